// Round 12
// baseline (1000.198 us; speedup 1.0000x reference)
//
#include <hip/hip_runtime.h>
#include <math.h>

#define HID 128
#define DEPTH 4
#define PSPLIT 16
#define SMAXB 40

typedef _Float16 half8 __attribute__((ext_vector_type(8)));
typedef float f4 __attribute__((ext_vector_type(4)));

// ---------------------------------------------------------------- node embed
__global__ void k_node_embed(const float* __restrict__ x, const float* __restrict__ nw,
                             const float* __restrict__ nb, float* __restrict__ h, int N) {
    int idx = blockIdx.x * blockDim.x + threadIdx.x;
    if (idx >= N * HID) return;
    int n = idx >> 7, c = idx & 127;
    float acc = nb[c];
#pragma unroll
    for (int d = 0; d < 4; ++d) acc += x[n * 4 + d] * nw[d * HID + c];
    h[idx] = acc;
}

// ---------------------------------------------------------------- W split+transpose (once per launch)
__global__ void k_wsplit(const float* __restrict__ fkw, _Float16* __restrict__ whi,
                         _Float16* __restrict__ wlo) {
    __shared__ float sh[64][65];
    int bid = blockIdx.x;           // 4 layers * 16 kblk * 2 nblk = 128 blocks
    int l = bid >> 5; int r = bid & 31; int kb = r >> 1; int nbk = r & 1;
    const float* W = fkw + (size_t)l * 131072;
    _Float16* Hl = whi + (size_t)l * 131072;
    _Float16* Ll = wlo + (size_t)l * 131072;
    int k0 = kb * 64, n0 = nbk * 64;
    for (int i = threadIdx.x; i < 4096; i += 256) {
        int kk = i >> 6, nn = i & 63;
        sh[kk][nn] = W[(k0 + kk) * HID + n0 + nn];
    }
    __syncthreads();
    for (int i = threadIdx.x; i < 4096; i += 256) {
        int nn = i >> 6, kk = i & 63;
        float w = sh[kk][nn];
        _Float16 hi = (_Float16)w;
        _Float16 lo = (_Float16)((w - (float)hi) * 2048.f);
        Hl[(n0 + nn) * 1024 + k0 + kk] = hi;
        Ll[(n0 + nn) * 1024 + k0 + kk] = lo;
    }
}

// ---------------------------------------------------------------- CSR build
__global__ void k_hist(const int* __restrict__ dst, int* __restrict__ deg, int E) {
    int e = blockIdx.x * 256 + threadIdx.x;
    if (e < E) atomicAdd(&deg[dst[e]], 1);
}

__global__ void k_scan_a(const int* __restrict__ deg, int* __restrict__ bsum, int N) {
    __shared__ int sh[256];
    int i = blockIdx.x * 256 + threadIdx.x;
    sh[threadIdx.x] = (i < N) ? deg[i] : 0;
    __syncthreads();
    for (int off = 128; off > 0; off >>= 1) {
        if (threadIdx.x < (unsigned)off) sh[threadIdx.x] += sh[threadIdx.x + off];
        __syncthreads();
    }
    if (threadIdx.x == 0) bsum[blockIdx.x] = sh[0];
}

__global__ void k_scan_b(int* __restrict__ bsum, int nb) {
    __shared__ int sh[256];
    int v = (threadIdx.x < (unsigned)nb) ? bsum[threadIdx.x] : 0;
    sh[threadIdx.x] = v;
    __syncthreads();
    for (int off = 1; off < 256; off <<= 1) {
        int add = (threadIdx.x >= (unsigned)off) ? sh[threadIdx.x - off] : 0;
        __syncthreads();
        sh[threadIdx.x] += add;
        __syncthreads();
    }
    if (threadIdx.x < (unsigned)nb) bsum[threadIdx.x] = sh[threadIdx.x] - v;
}

__global__ void k_scan_c(const int* __restrict__ deg, const int* __restrict__ bsum,
                         int* __restrict__ offs, int* __restrict__ cursor, int N) {
    __shared__ int sh[256];
    int i = blockIdx.x * 256 + threadIdx.x;
    int v = (i < N) ? deg[i] : 0;
    sh[threadIdx.x] = v;
    __syncthreads();
    for (int off = 1; off < 256; off <<= 1) {
        int add = (threadIdx.x >= (unsigned)off) ? sh[threadIdx.x - off] : 0;
        __syncthreads();
        sh[threadIdx.x] += add;
        __syncthreads();
    }
    int ex = bsum[blockIdx.x] + sh[threadIdx.x] - v;
    if (i < N) { offs[i] = ex; cursor[i] = ex; }
    if (i == N - 1) offs[N] = ex + v;
}

__global__ void k_scatter(const int* __restrict__ src, const int* __restrict__ dst,
                          int* cursor, int* __restrict__ eord,
                          int* __restrict__ srco, int E) {
    int e = blockIdx.x * 256 + threadIdx.x;
    if (e < E) {
        int d = dst[e];
        int p = atomicAdd(&cursor[d], 1);
        eord[p] = e;
        srco[p] = src[e];
    }
}

__global__ void k_eaord(const int* __restrict__ eord, const float* __restrict__ ea,
                        float4* __restrict__ ea3o, int E) {
    int idx = blockIdx.x * 256 + threadIdx.x;
    if (idx >= E) return;
    int e = eord[idx];
    float4 q;
    q.x = ea[e * 3 + 0]; q.y = ea[e * 3 + 1]; q.z = ea[e * 3 + 2]; q.w = 0.f;
    ea3o[idx] = q;
}

__global__ void k_bstart(const int* __restrict__ batch, int* __restrict__ boffs, int N, int B) {
    int n = blockIdx.x * 256 + threadIdx.x;
    if (n >= N) return;
    int b1 = batch[n];
    if (n == 0) for (int b = 0; b <= b1; ++b) boffs[b] = 0;
    int b2 = (n + 1 < N) ? batch[n + 1] : B;
    for (int b = b1 + 1; b <= b2; ++b) boffs[b] = n + 1;
}

// ---------------------------------------------------------------- per-node linear + attention dots (fused)
__global__ __launch_bounds__(256) void k_node_lin(const float* __restrict__ h,
                           const float* __restrict__ linw, const float* __restrict__ linb,
                           const float* __restrict__ attw, const float* __restrict__ attb,
                           float* __restrict__ A1, float* __restrict__ A2,
                           float* __restrict__ a1, float* __restrict__ a2, int N) {
    __shared__ float hT[HID][12];
    int nb = blockIdx.x * 8;
    int tid = threadIdx.x;
    for (int i = tid; i < 8 * HID; i += 256) {
        int n = i >> 7, c = i & 127;
        int gn = nb + n;
        hT[c][n] = (gn < N) ? h[gn * HID + c] : 0.f;
    }
    __syncthreads();
    {
        int node = tid >> 5, lane32 = tid & 31;
        float p1 = 0.f, p2 = 0.f;
#pragma unroll
        for (int j = 0; j < 4; ++j) {
            int k = lane32 * 4 + j;
            float hv = hT[k][node];
            p1 += hv * attw[k];
            p2 += hv * attw[128 + k];
        }
        for (int off = 16; off > 0; off >>= 1) {
            p1 += __shfl_down(p1, off, 32);
            p2 += __shfl_down(p2, off, 32);
        }
        int gn = nb + node;
        if (lane32 == 0 && gn < N) {
            a1[gn] = p1 + attb[0];
            a2[gn] = p2;
        }
    }
    int c = tid & 127, r = tid >> 7;
    const float* Wd = linw;
    const float* Ws = linw + 128 * HID;
    float acc1[4] = {0, 0, 0, 0}, acc2[4] = {0, 0, 0, 0};
#pragma unroll 4
    for (int k = 0; k < HID; ++k) {
        float wd = Wd[k * HID + c];
        float ws = Ws[k * HID + c];
        float4 hv = *(const float4*)&hT[k][r * 4];
        acc1[0] += hv.x * wd; acc2[0] += hv.x * ws;
        acc1[1] += hv.y * wd; acc2[1] += hv.y * ws;
        acc1[2] += hv.z * wd; acc2[2] += hv.z * ws;
        acc1[3] += hv.w * wd; acc2[3] += hv.w * ws;
    }
#pragma unroll
    for (int j = 0; j < 4; ++j) {
        int gn = nb + r * 4 + j;
        if (gn < N) {
            A1[gn * HID + c] = acc1[j] + linb[c];
            A2[gn * HID + c] = acc2[j];
        }
    }
}

// ---------------------------------------------------------------- edge conv (CSR, 8 slots, float4, alpha fused)
// also zeroes the bn stats buffer (block 0)
__global__ __launch_bounds__(256) void k_edge(const float* __restrict__ A1,
        const float* __restrict__ A2, const float* __restrict__ a1,
        const float* __restrict__ a2, const int* __restrict__ srco,
        const float4* __restrict__ ea3o, const int* __restrict__ offs,
        const float* __restrict__ linw3, const float* __restrict__ attw3,
        float* __restrict__ hconv, double* __restrict__ stats, int N) {
    __shared__ float w3s[3 * HID];
    __shared__ float aw3s[3];
    __shared__ float part[8][HID];
    int n = blockIdx.x;
    int tid = threadIdx.x;
    if (n == 0) stats[tid] = 0.0;
    int lane32 = tid & 31, slot = tid >> 5;
    int c4 = lane32 * 4;
    for (int i = tid; i < 3 * HID; i += 256) w3s[i] = linw3[i];
    if (tid < 3) aw3s[tid] = attw3[tid];
    __syncthreads();
    float4 w0v = *(const float4*)&w3s[c4];
    float4 w1v = *(const float4*)&w3s[HID + c4];
    float4 w2v = *(const float4*)&w3s[2 * HID + c4];
    float aw0 = aw3s[0], aw1 = aw3s[1], aw2 = aw3s[2];
    float a1n = a1[n];
    float4 A1v = *(const float4*)&A1[(size_t)n * HID + c4];
    float4 acc; acc.x = acc.y = acc.z = acc.w = 0.f;
    int s0 = offs[n], s1 = offs[n + 1];
    for (int idx = s0 + slot; idx < s1; idx += 8) {
        int s = srco[idx];
        float4 q = ea3o[idx];
        float logit = a1n + a2[s] + q.x * aw0 + q.y * aw1 + q.z * aw2;
        float al = 1.f / (1.f + __expf(-logit));
        float4 a2v = *(const float4*)&A2[(size_t)s * HID + c4];
        float4 pre;
        pre.x = A1v.x + a2v.x + q.x * w0v.x + q.y * w1v.x + q.z * w2v.x;
        pre.y = A1v.y + a2v.y + q.x * w0v.y + q.y * w1v.y + q.z * w2v.y;
        pre.z = A1v.z + a2v.z + q.x * w0v.z + q.y * w1v.z + q.z * w2v.z;
        pre.w = A1v.w + a2v.w + q.x * w0v.w + q.y * w1v.w + q.z * w2v.w;
        acc.x += al * pre.x; acc.y += al * pre.y;
        acc.z += al * pre.z; acc.w += al * pre.w;
    }
    *(float4*)&part[slot][c4] = acc;
    __syncthreads();
    for (int st = 4; st >= 1; st >>= 1) {
        if (slot < st) {
            float4 p = *(const float4*)&part[slot][c4];
            float4 r = *(const float4*)&part[slot + st][c4];
            p.x += r.x; p.y += r.y; p.z += r.z; p.w += r.w;
            *(float4*)&part[slot][c4] = p;
        }
        __syncthreads();
    }
    if (slot == 0) *(float4*)&hconv[(size_t)n * HID + c4] = *(const float4*)&part[0][c4];
}

// ---------------------------------------------------------------- Fourier-Kolmogorov GEMM (transposed MFMA)
// D = W·T^T: A-operand = W (lane = channel row), B-operand = trig (lane = node col).
// Each lane computes its OWN B-fragment trig in registers: no LDS, no barriers,
// no cross-lane trig hand-off. Wave = 16 nodes x 64 ch; block = 32 nodes x 128 ch
// x 512 K (K-split 2). Output written transposed pT[ch][node].
__global__ __launch_bounds__(256) void k_fk(const float* __restrict__ h,
        const _Float16* __restrict__ whi, const _Float16* __restrict__ wlo,
        float* __restrict__ pT0, float* __restrict__ pT1, int N) {
    int bx = blockIdx.x;
    int nb = (bx >> 1) * 32;
    int ks = bx & 1;
    int kbase = ks * 512;
    int fr0 = ks * 4;
    int tid = threadIdx.x, lane = tid & 63, wv = tid >> 6;
    int l16 = lane & 15, quad = lane >> 4;
    int node = nb + (wv & 1) * 16 + l16;
    int c0 = (wv >> 1) * 64;
    int rc = (node < N) ? node : (N - 1);
    // preload this lane's 32 h floats: octets quad*8 + g*32, g=0..3
    float4 hreg[4][2];
    {
        const float* hp = h + (size_t)rc * HID + quad * 8;
#pragma unroll
        for (int g = 0; g < 4; ++g) {
            hreg[g][0] = *(const float4*)(hp + g * 32);
            hreg[g][1] = *(const float4*)(hp + g * 32 + 4);
        }
    }
    f4 acc0[4], accL[4];
#pragma unroll
    for (int t = 0; t < 4; ++t) { acc0[t] = (f4)(0.f); accL[t] = (f4)(0.f); }
    const _Float16* wh[4]; const _Float16* wl[4];
#pragma unroll
    for (int t = 0; t < 4; ++t) {
        size_t off = (size_t)(c0 + t * 16 + l16) * 1024 + kbase + quad * 8;
        wh[t] = whi + off;
        wl[t] = wlo + off;
    }
#pragma unroll 2
    for (int s = 0; s < 16; ++s) {
        int g = s & 3;
        float freqf = 6.2831853f * (float)(fr0 + (s >> 2) + 1);
        float hv[8] = {hreg[g][0].x, hreg[g][0].y, hreg[g][0].z, hreg[g][0].w,
                       hreg[g][1].x, hreg[g][1].y, hreg[g][1].z, hreg[g][1].w};
        half8 bh, bl;
#pragma unroll
        for (int j = 0; j < 8; ++j) {
            float ang = freqf * hv[j] + 0.78539816f;
            float a = 1.41421356f * __sinf(ang);   // sin + cos
            _Float16 hi = (_Float16)a;
            bh[j] = hi;
            bl[j] = (_Float16)((a - (float)hi) * 2048.f);
        }
        int ko = s * 32;
#pragma unroll
        for (int t = 0; t < 4; ++t) {
            half8 ah = *(const half8*)(wh[t] + ko);
            half8 al = *(const half8*)(wl[t] + ko);
            acc0[t] = __builtin_amdgcn_mfma_f32_16x16x32_f16(ah, bh, acc0[t], 0, 0, 0);
            accL[t] = __builtin_amdgcn_mfma_f32_16x16x32_f16(ah, bl, accL[t], 0, 0, 0);
            accL[t] = __builtin_amdgcn_mfma_f32_16x16x32_f16(al, bh, accL[t], 0, 0, 0);
        }
    }
    float* pT = ks ? pT1 : pT0;
    const float inv = 1.0f / 2048.0f;
    if (node < N) {
#pragma unroll
        for (int t = 0; t < 4; ++t)
#pragma unroll
            for (int r = 0; r < 4; ++r) {
                int ch = c0 + t * 16 + quad * 4 + r;
                pT[(size_t)ch * N + node] = acc0[t][r] + accL[t][r] * inv;
            }
    }
}

// ---------------------------------------------------------------- BN stats + transpose-combine
// v[n][c] = hconv[n][c] + pT0[c][n] + pT1[c][n] + fkb[c]; writes hconv in place,
// accumulates per-channel (sum, sumsq) via atomics. 32-node tiles, 17.4 KB LDS.
#define SN 32
__global__ __launch_bounds__(256) void k_bn_statsT(float* __restrict__ hconv,
        const float* __restrict__ pT0, const float* __restrict__ pT1,
        const float* __restrict__ fkb, double* __restrict__ stats, int N) {
    __shared__ float v[128][SN + 2];
    int nb = blockIdx.x * SN;
    int tid = threadIdx.x;
    int nvalid = (N - nb < SN) ? (N - nb) : SN;
    {   // phase 1: sum the two transposed partials into LDS
        int c = tid >> 1, hf = tid & 1;
        size_t ro = (size_t)c * N + nb + hf * 16;
        if (nvalid == SN) {
#pragma unroll
            for (int i = 0; i < 4; ++i) {
                float4 a = *(const float4*)(pT0 + ro + i * 4);
                float4 b = *(const float4*)(pT1 + ro + i * 4);
                float4 sm; sm.x = a.x + b.x; sm.y = a.y + b.y; sm.z = a.z + b.z; sm.w = a.w + b.w;
                *(float4*)&v[c][hf * 16 + i * 4] = sm;
            }
        } else {
            for (int j = 0; j < 16; ++j) {
                int node = hf * 16 + j;
                v[c][node] = (node < nvalid)
                    ? pT0[(size_t)c * N + nb + node] + pT1[(size_t)c * N + nb + node] : 0.f;
            }
        }
    }
    __syncthreads();
    {   // phase 2a: add hconv + bias, write hconv (node-major, coalesced), update LDS
        int node = tid >> 3, cq = tid & 7;
        if (node < nvalid) {
#pragma unroll
            for (int i = 0; i < 4; ++i) {
                int ch = cq * 16 + i * 4;
                float4 hc = *(const float4*)&hconv[(size_t)(nb + node) * HID + ch];
                float4 bb = *(const float4*)&fkb[ch];
                float4 vv;
                vv.x = v[ch + 0][node] + hc.x + bb.x;
                vv.y = v[ch + 1][node] + hc.y + bb.y;
                vv.z = v[ch + 2][node] + hc.z + bb.z;
                vv.w = v[ch + 3][node] + hc.w + bb.w;
                *(float4*)&hconv[(size_t)(nb + node) * HID + ch] = vv;
                v[ch + 0][node] = vv.x; v[ch + 1][node] = vv.y;
                v[ch + 2][node] = vv.z; v[ch + 3][node] = vv.w;
            }
        }
    }
    __syncthreads();
    if (tid < 128) {   // phase 2b: per-channel partial stats
        float s1 = 0.f, s2 = 0.f;
        for (int n = 0; n < nvalid; ++n) { float x = v[tid][n]; s1 += x; s2 += x * x; }
        atomicAdd(&stats[tid], (double)s1);
        atomicAdd(&stats[128 + tid], (double)s2);
    }
}

// bn_final folded in; optionally computes pool scores (last layer)
__global__ void k_bn_apply(const float* __restrict__ hsum, const double* __restrict__ stats,
                           const float* __restrict__ g, const float* __restrict__ b,
                           const float* __restrict__ pw, const float* __restrict__ pb,
                           float* __restrict__ h, float* __restrict__ s,
                           int do_score, int N) {
    __shared__ float red[4];
    int idx = blockIdx.x * 256 + threadIdx.x;
    int valid = idx < N * HID;
    int c = idx & 127;
    double invN = 1.0 / (double)N;
    float mu = (float)(stats[c] * invN);
    float var = (float)(stats[128 + c] * invN) - mu * mu;
    float inv = 1.f / sqrtf(var + 1e-5f);
    float sc = g[c] * inv;
    float sh = b[c] - mu * sc;
    float o = 0.f;
    if (valid) {
        o = fmaxf(hsum[idx] * sc + sh, 0.f);
        h[idx] = o;
    }
    if (do_score) {
        float p = valid ? o * pw[c] : 0.f;
        for (int off = 32; off > 0; off >>= 1) p += __shfl_down(p, off);
        int wid = threadIdx.x >> 6;
        if ((threadIdx.x & 63) == 0) red[wid] = p;
        __syncthreads();
        int row = idx >> 7;
        int half = threadIdx.x >> 7;
        if ((threadIdx.x & 127) == 0 && row < N)
            s[row] = red[half * 2] + red[half * 2 + 1] + pb[0];
    }
}

// ---------------------------------------------------------------- softmax partials
__global__ void k_smax1(const float* __restrict__ s, float* __restrict__ mzp, int N) {
    __shared__ float red[256];
    float m = -INFINITY;
    for (int n = blockIdx.x * 256 + threadIdx.x; n < N; n += SMAXB * 256)
        m = fmaxf(m, s[n]);
    red[threadIdx.x] = m;
    __syncthreads();
    for (int off = 128; off > 0; off >>= 1) {
        if (threadIdx.x < (unsigned)off)
            red[threadIdx.x] = fmaxf(red[threadIdx.x], red[threadIdx.x + off]);
        __syncthreads();
    }
    m = red[0];
    __syncthreads();
    float z = 0.f;
    for (int n = blockIdx.x * 256 + threadIdx.x; n < N; n += SMAXB * 256)
        z += __expf(s[n] - m);
    red[threadIdx.x] = z;
    __syncthreads();
    for (int off = 128; off > 0; off >>= 1) {
        if (threadIdx.x < (unsigned)off) red[threadIdx.x] += red[threadIdx.x + off];
        __syncthreads();
    }
    if (threadIdx.x == 0) { mzp[blockIdx.x * 2] = m; mzp[blockIdx.x * 2 + 1] = red[0]; }
}

__device__ __forceinline__ void combine_mz(const float* mzp, float& m, float& Z) {
    m = -INFINITY;
#pragma unroll 8
    for (int i = 0; i < SMAXB; ++i) m = fmaxf(m, mzp[i * 2]);
    Z = 0.f;
#pragma unroll 8
    for (int i = 0; i < SMAXB; ++i) Z += mzp[i * 2 + 1] * __expf(mzp[i * 2] - m);
}

// ---------------------------------------------------------------- attention pool (split)
__global__ void k_pool_part(const float* __restrict__ h, const float* __restrict__ s,
                            const float* __restrict__ mzp, const int* __restrict__ boffs,
                            float* __restrict__ part) {
    int b = blockIdx.x >> 4, split = blockIdx.x & (PSPLIT - 1);
    int c = threadIdx.x & 127, half = threadIdx.x >> 7;
    float m, Z;
    combine_mz(mzp, m, Z);
    (void)Z;
    int n0 = boffs[b], n1 = boffs[b + 1];
    float acc = 0.f;
    for (int n = n0 + split * 2 + half; n < n1; n += PSPLIT * 2)
        acc += __expf(s[n] - m) * h[n * HID + c];
    __shared__ float prt[2][HID];
    prt[half][c] = acc;
    __syncthreads();
    if (half == 0) part[(size_t)(b * PSPLIT + split) * HID + c] = prt[0][c] + prt[1][c];
}

__global__ void k_pool_sum(const float* __restrict__ part, const float* __restrict__ mzp,
                           float* __restrict__ pooled) {
    int b = blockIdx.x, c = threadIdx.x;
    float m, Z;
    combine_mz(mzp, m, Z);
    float acc = 0.f;
#pragma unroll
    for (int i = 0; i < PSPLIT; ++i) acc += part[(size_t)(b * PSPLIT + i) * HID + c];
    pooled[b * HID + c] = acc / Z;
}

// ---------------------------------------------------------------- heads (grid = B*4)
__global__ __launch_bounds__(256) void k_head(const float* __restrict__ pooled,
                       const float* __restrict__ sg_table,
                       const int* __restrict__ space_group,
                       const float* __restrict__ hw1, const float* __restrict__ hb1,
                       const float* __restrict__ ew2, const float* __restrict__ eb2,
                       const float* __restrict__ sw2, const float* __restrict__ sb2,
                       const float* __restrict__ cw2, const float* __restrict__ cb2,
                       const float* __restrict__ mw2, const float* __restrict__ mb2,
                       float* __restrict__ out, int B) {
    __shared__ float comb[256];
    __shared__ float zred[2][128];
    __shared__ float zsh[128];
    int b = blockIdx.x >> 2, i = blockIdx.x & 3;
    int t = threadIdx.x;
    comb[t] = (t < 128) ? pooled[b * HID + t] : sg_table[space_group[b] * HID + (t - 128)];
    __syncthreads();
    int half = t >> 7, tt = t & 127;
    const float* W = hw1 + ((size_t)i * 256 + half * 128) * HID;
    const float* cb = &comb[half * 128];
    float z = 0.f;
#pragma unroll 8
    for (int k = 0; k < 128; ++k) z += cb[k] * W[k * HID + tt];
    zred[half][tt] = z;
    __syncthreads();
    if (t < 128) zsh[t] = fmaxf(zred[0][t] + zred[1][t] + hb1[i * HID + t], 0.f);
    __syncthreads();
    const int od[4] = {1, 3, 7, 3};
    const int base[4] = {0, 64, 256, 704};
    const float* w2 = (i == 0) ? ew2 : (i == 1) ? sw2 : (i == 2) ? cw2 : mw2;
    const float* b2 = (i == 0) ? eb2 : (i == 1) ? sb2 : (i == 2) ? cb2 : mb2;
    int odi = od[i];
    if (t < odi) {
        float o = b2[t];
        for (int c = 0; c < HID; ++c) o += zsh[c] * w2[c * odi + t];
        out[base[i] + b * odi + t] = o;
    }
}

// ---------------------------------------------------------------- launch
extern "C" void kernel_launch(void* const* d_in, const int* in_sizes, int n_in,
                              void* d_out, int out_size, void* d_ws, size_t ws_size,
                              hipStream_t stream) {
    const float* x          = (const float*)d_in[0];
    const int*   edge_index = (const int*)d_in[1];
    const float* edge_attr  = (const float*)d_in[2];
    const int*   batch      = (const int*)d_in[3];
    const int*   space_group= (const int*)d_in[4];
    const float* node_w     = (const float*)d_in[5];
    const float* node_b     = (const float*)d_in[6];
    const float* sg_table   = (const float*)d_in[7];
    const float* lin_w      = (const float*)d_in[8];
    const float* lin_b      = (const float*)d_in[9];
    const float* att_w      = (const float*)d_in[10];
    const float* att_b      = (const float*)d_in[11];
    const float* fk_w       = (const float*)d_in[12];
    const float* fk_b       = (const float*)d_in[13];
    const float* bn_g       = (const float*)d_in[14];
    const float* bn_b       = (const float*)d_in[15];
    const float* pool_w     = (const float*)d_in[16];
    const float* pool_b     = (const float*)d_in[17];
    const float* head_w1    = (const float*)d_in[18];
    const float* head_b1    = (const float*)d_in[19];
    const float* ew2 = (const float*)d_in[20]; const float* eb2 = (const float*)d_in[21];
    const float* sw2 = (const float*)d_in[22]; const float* sb2 = (const float*)d_in[23];
    const float* cw2 = (const float*)d_in[24]; const float* cb2 = (const float*)d_in[25];
    const float* mw2 = (const float*)d_in[26]; const float* mb2 = (const float*)d_in[27];
    float* out = (float*)d_out;

    const int N = in_sizes[3];
    const int E = in_sizes[1] / 2;
    const int B = in_sizes[4];
    const int* src = edge_index;
    const int* dst = edge_index + E;

    char* w = (char*)d_ws;
    auto alloc = [&](size_t bytes) { char* p = w; w += (bytes + 255) & ~(size_t)255; return p; };
    float*  h      = (float*)alloc((size_t)N * HID * 4);
    float*  A1     = (float*)alloc((size_t)N * HID * 4);  // reused as FK transposed partial 0
    float*  A2     = (float*)alloc((size_t)N * HID * 4);  // reused as FK transposed partial 1
    float*  hconv  = (float*)alloc((size_t)N * HID * 4);  // becomes pre-BN sum in place
    float*  a1     = (float*)alloc((size_t)N * 4);
    float*  a2     = (float*)alloc((size_t)N * 4);
    float*  sbuf   = (float*)alloc((size_t)N * 4);
    int*    deg    = (int*)alloc((size_t)N * 4);
    int*    cursor = (int*)alloc((size_t)N * 4);
    int*    offs   = (int*)alloc((size_t)(N + 1) * 4);
    int*    eord   = (int*)alloc((size_t)E * 4);
    int*    srco   = (int*)alloc((size_t)E * 4);
    float4* ea3o   = (float4*)alloc((size_t)E * 16);
    _Float16* whi  = (_Float16*)alloc((size_t)DEPTH * 1024 * HID * 2);
    _Float16* wlo  = (_Float16*)alloc((size_t)DEPTH * 1024 * HID * 2);
    int*    bsum   = (int*)alloc(256 * 4);
    int*    boffs  = (int*)alloc((size_t)(B + 1) * 4);
    double* stats  = (double*)alloc(256 * 8);
    float*  mzp    = (float*)alloc(SMAXB * 2 * 4);
    float*  part   = (float*)alloc((size_t)B * PSPLIT * HID * 4);
    float*  pooled = (float*)alloc((size_t)B * HID * 4);

    const int nchunk = (N + 255) / 256;
    const int echunk = (E + 255) / 256;
    const int ntile  = (N + 31) / 32;

    // one-time per launch: W split + CSR build
    k_wsplit<<<128, 256, 0, stream>>>(fk_w, whi, wlo);
    hipMemsetAsync(deg, 0, (size_t)N * 4, stream);
    k_hist<<<echunk, 256, 0, stream>>>(dst, deg, E);
    k_scan_a<<<nchunk, 256, 0, stream>>>(deg, bsum, N);
    k_scan_b<<<1, 256, 0, stream>>>(bsum, nchunk);
    k_scan_c<<<nchunk, 256, 0, stream>>>(deg, bsum, offs, cursor, N);
    k_scatter<<<echunk, 256, 0, stream>>>(src, dst, cursor, eord, srco, E);
    k_eaord<<<echunk, 256, 0, stream>>>(eord, edge_attr, ea3o, E);
    k_bstart<<<nchunk, 256, 0, stream>>>(batch, boffs, N, B);

    k_node_embed<<<(N * HID + 255) / 256, 256, 0, stream>>>(x, node_w, node_b, h, N);

    for (int l = 0; l < DEPTH; ++l) {
        const float* linw_l = lin_w + (size_t)l * 259 * HID;
        k_node_lin<<<(N + 7) / 8, 256, 0, stream>>>(
            h, linw_l, lin_b + l * HID, att_w + (size_t)l * 259, att_b + l,
            A1, A2, a1, a2, N);
        k_edge<<<N, 256, 0, stream>>>(A1, A2, a1, a2, srco, ea3o, offs,
                                      linw_l + 256 * HID, att_w + (size_t)l * 259 + 256,
                                      hconv, stats, N);
        k_fk<<<ntile * 2, 256, 0, stream>>>(
            h, whi + (size_t)l * 131072, wlo + (size_t)l * 131072, A1, A2, N);
        k_bn_statsT<<<ntile, 256, 0, stream>>>(hconv, A1, A2, fk_b + l * HID, stats, N);
        k_bn_apply<<<(N * HID + 255) / 256, 256, 0, stream>>>(
            hconv, stats, bn_g + l * HID, bn_b + l * HID, pool_w, pool_b,
            h, sbuf, (l == DEPTH - 1) ? 1 : 0, N);
    }

    k_smax1<<<SMAXB, 256, 0, stream>>>(sbuf, mzp, N);
    k_pool_part<<<B * PSPLIT, 256, 0, stream>>>(h, sbuf, mzp, boffs, part);
    k_pool_sum<<<B, 128, 0, stream>>>(part, mzp, pooled);
    k_head<<<B * 4, 256, 0, stream>>>(pooled, sg_table, space_group, head_w1, head_b1,
                                      ew2, eb2, sw2, sb2, cw2, cb2, mw2, mb2, out, B);
}

// Round 14
// 897.624 us; speedup vs baseline: 1.1143x; 1.1143x over previous
//
#include <hip/hip_runtime.h>
#include <math.h>

#define HID 128
#define DEPTH 4
#define PSPLIT 16
#define SMAXB 40

typedef _Float16 half8 __attribute__((ext_vector_type(8)));
typedef float f4 __attribute__((ext_vector_type(4)));

// ---------------------------------------------------------------- node embed
__global__ void k_node_embed(const float* __restrict__ x, const float* __restrict__ nw,
                             const float* __restrict__ nb, float* __restrict__ h, int N) {
    int idx = blockIdx.x * blockDim.x + threadIdx.x;
    if (idx >= N * HID) return;
    int n = idx >> 7, c = idx & 127;
    float acc = nb[c];
#pragma unroll
    for (int d = 0; d < 4; ++d) acc += x[n * 4 + d] * nw[d * HID + c];
    h[idx] = acc;
}

// ---------------------------------------------------------------- W split+transpose (once per launch)
__global__ void k_wsplit(const float* __restrict__ fkw, _Float16* __restrict__ whi,
                         _Float16* __restrict__ wlo) {
    __shared__ float sh[64][65];
    int bid = blockIdx.x;           // 4 layers * 16 kblk * 2 nblk = 128 blocks
    int l = bid >> 5; int r = bid & 31; int kb = r >> 1; int nbk = r & 1;
    const float* W = fkw + (size_t)l * 131072;
    _Float16* Hl = whi + (size_t)l * 131072;
    _Float16* Ll = wlo + (size_t)l * 131072;
    int k0 = kb * 64, n0 = nbk * 64;
    for (int i = threadIdx.x; i < 4096; i += 256) {
        int kk = i >> 6, nn = i & 63;
        sh[kk][nn] = W[(k0 + kk) * HID + n0 + nn];
    }
    __syncthreads();
    for (int i = threadIdx.x; i < 4096; i += 256) {
        int nn = i >> 6, kk = i & 63;
        float w = sh[kk][nn];
        _Float16 hi = (_Float16)w;
        _Float16 lo = (_Float16)((w - (float)hi) * 2048.f);
        Hl[(n0 + nn) * 1024 + k0 + kk] = hi;
        Ll[(n0 + nn) * 1024 + k0 + kk] = lo;
    }
}

// ---------------------------------------------------------------- CSR build
__global__ void k_hist(const int* __restrict__ dst, int* __restrict__ deg, int E) {
    int e = blockIdx.x * 256 + threadIdx.x;
    if (e < E) atomicAdd(&deg[dst[e]], 1);
}

__global__ void k_scan_a(const int* __restrict__ deg, int* __restrict__ bsum, int N) {
    __shared__ int sh[256];
    int i = blockIdx.x * 256 + threadIdx.x;
    sh[threadIdx.x] = (i < N) ? deg[i] : 0;
    __syncthreads();
    for (int off = 128; off > 0; off >>= 1) {
        if (threadIdx.x < (unsigned)off) sh[threadIdx.x] += sh[threadIdx.x + off];
        __syncthreads();
    }
    if (threadIdx.x == 0) bsum[blockIdx.x] = sh[0];
}

__global__ void k_scan_b(int* __restrict__ bsum, int nb) {
    __shared__ int sh[256];
    int v = (threadIdx.x < (unsigned)nb) ? bsum[threadIdx.x] : 0;
    sh[threadIdx.x] = v;
    __syncthreads();
    for (int off = 1; off < 256; off <<= 1) {
        int add = (threadIdx.x >= (unsigned)off) ? sh[threadIdx.x - off] : 0;
        __syncthreads();
        sh[threadIdx.x] += add;
        __syncthreads();
    }
    if (threadIdx.x < (unsigned)nb) bsum[threadIdx.x] = sh[threadIdx.x] - v;
}

__global__ void k_scan_c(const int* __restrict__ deg, const int* __restrict__ bsum,
                         int* __restrict__ offs, int* __restrict__ cursor, int N) {
    __shared__ int sh[256];
    int i = blockIdx.x * 256 + threadIdx.x;
    int v = (i < N) ? deg[i] : 0;
    sh[threadIdx.x] = v;
    __syncthreads();
    for (int off = 1; off < 256; off <<= 1) {
        int add = (threadIdx.x >= (unsigned)off) ? sh[threadIdx.x - off] : 0;
        __syncthreads();
        sh[threadIdx.x] += add;
        __syncthreads();
    }
    int ex = bsum[blockIdx.x] + sh[threadIdx.x] - v;
    if (i < N) { offs[i] = ex; cursor[i] = ex; }
    if (i == N - 1) offs[N] = ex + v;
}

__global__ void k_scatter(const int* __restrict__ src, const int* __restrict__ dst,
                          int* cursor, int* __restrict__ eord,
                          int* __restrict__ srco, int E) {
    int e = blockIdx.x * 256 + threadIdx.x;
    if (e < E) {
        int d = dst[e];
        int p = atomicAdd(&cursor[d], 1);
        eord[p] = e;
        srco[p] = src[e];
    }
}

__global__ void k_eaord(const int* __restrict__ eord, const float* __restrict__ ea,
                        float4* __restrict__ ea3o, int E) {
    int idx = blockIdx.x * 256 + threadIdx.x;
    if (idx >= E) return;
    int e = eord[idx];
    float4 q;
    q.x = ea[e * 3 + 0]; q.y = ea[e * 3 + 1]; q.z = ea[e * 3 + 2]; q.w = 0.f;
    ea3o[idx] = q;
}

__global__ void k_bstart(const int* __restrict__ batch, int* __restrict__ boffs, int N, int B) {
    int n = blockIdx.x * 256 + threadIdx.x;
    if (n >= N) return;
    int b1 = batch[n];
    if (n == 0) for (int b = 0; b <= b1; ++b) boffs[b] = 0;
    int b2 = (n + 1 < N) ? batch[n + 1] : B;
    for (int b = b1 + 1; b <= b2; ++b) boffs[b] = n + 1;
}

// ---------------------------------------------------------------- per-node linear + attention dots (fused, fp32)
__global__ __launch_bounds__(256) void k_node_lin(const float* __restrict__ h,
                           const float* __restrict__ linw, const float* __restrict__ linb,
                           const float* __restrict__ attw, const float* __restrict__ attb,
                           float* __restrict__ A1, float* __restrict__ A2,
                           float* __restrict__ a1, float* __restrict__ a2, int N) {
    __shared__ float hT[HID][12];
    int nb = blockIdx.x * 8;
    int tid = threadIdx.x;
    for (int i = tid; i < 8 * HID; i += 256) {
        int n = i >> 7, c = i & 127;
        int gn = nb + n;
        hT[c][n] = (gn < N) ? h[gn * HID + c] : 0.f;
    }
    __syncthreads();
    {
        int node = tid >> 5, lane32 = tid & 31;
        float p1 = 0.f, p2 = 0.f;
#pragma unroll
        for (int j = 0; j < 4; ++j) {
            int k = lane32 * 4 + j;
            float hv = hT[k][node];
            p1 += hv * attw[k];
            p2 += hv * attw[128 + k];
        }
        for (int off = 16; off > 0; off >>= 1) {
            p1 += __shfl_down(p1, off, 32);
            p2 += __shfl_down(p2, off, 32);
        }
        int gn = nb + node;
        if (lane32 == 0 && gn < N) {
            a1[gn] = p1 + attb[0];
            a2[gn] = p2;
        }
    }
    int c = tid & 127, r = tid >> 7;
    const float* Wd = linw;
    const float* Ws = linw + 128 * HID;
    float acc1[4] = {0, 0, 0, 0}, acc2[4] = {0, 0, 0, 0};
#pragma unroll 4
    for (int k = 0; k < HID; ++k) {
        float wd = Wd[k * HID + c];
        float ws = Ws[k * HID + c];
        float4 hv = *(const float4*)&hT[k][r * 4];
        acc1[0] += hv.x * wd; acc2[0] += hv.x * ws;
        acc1[1] += hv.y * wd; acc2[1] += hv.y * ws;
        acc1[2] += hv.z * wd; acc2[2] += hv.z * ws;
        acc1[3] += hv.w * wd; acc2[3] += hv.w * ws;
    }
#pragma unroll
    for (int j = 0; j < 4; ++j) {
        int gn = nb + r * 4 + j;
        if (gn < N) {
            A1[gn * HID + c] = acc1[j] + linb[c];
            A2[gn * HID + c] = acc2[j];
        }
    }
}

// ---------------------------------------------------------------- edge conv (CSR, 8 slots, float4, alpha fused)
// also zeroes the bn stats buffer (block 0)
__global__ __launch_bounds__(256) void k_edge(const float* __restrict__ A1,
        const float* __restrict__ A2, const float* __restrict__ a1,
        const float* __restrict__ a2, const int* __restrict__ srco,
        const float4* __restrict__ ea3o, const int* __restrict__ offs,
        const float* __restrict__ linw3, const float* __restrict__ attw3,
        float* __restrict__ hconv, double* __restrict__ stats, int N) {
    __shared__ float w3s[3 * HID];
    __shared__ float aw3s[3];
    __shared__ float part[8][HID];
    int n = blockIdx.x;
    int tid = threadIdx.x;
    if (n == 0) stats[tid] = 0.0;
    int lane32 = tid & 31, slot = tid >> 5;
    int c4 = lane32 * 4;
    for (int i = tid; i < 3 * HID; i += 256) w3s[i] = linw3[i];
    if (tid < 3) aw3s[tid] = attw3[tid];
    __syncthreads();
    float4 w0v = *(const float4*)&w3s[c4];
    float4 w1v = *(const float4*)&w3s[HID + c4];
    float4 w2v = *(const float4*)&w3s[2 * HID + c4];
    float aw0 = aw3s[0], aw1 = aw3s[1], aw2 = aw3s[2];
    float a1n = a1[n];
    float4 A1v = *(const float4*)&A1[(size_t)n * HID + c4];
    float4 acc; acc.x = acc.y = acc.z = acc.w = 0.f;
    int s0 = offs[n], s1 = offs[n + 1];
    for (int idx = s0 + slot; idx < s1; idx += 8) {
        int s = srco[idx];
        float4 q = ea3o[idx];
        float logit = a1n + a2[s] + q.x * aw0 + q.y * aw1 + q.z * aw2;
        float al = 1.f / (1.f + __expf(-logit));
        float4 a2v = *(const float4*)&A2[(size_t)s * HID + c4];
        float4 pre;
        pre.x = A1v.x + a2v.x + q.x * w0v.x + q.y * w1v.x + q.z * w2v.x;
        pre.y = A1v.y + a2v.y + q.x * w0v.y + q.y * w1v.y + q.z * w2v.y;
        pre.z = A1v.z + a2v.z + q.x * w0v.z + q.y * w1v.z + q.z * w2v.z;
        pre.w = A1v.w + a2v.w + q.x * w0v.w + q.y * w1v.w + q.z * w2v.w;
        acc.x += al * pre.x; acc.y += al * pre.y;
        acc.z += al * pre.z; acc.w += al * pre.w;
    }
    *(float4*)&part[slot][c4] = acc;
    __syncthreads();
    for (int st = 4; st >= 1; st >>= 1) {
        if (slot < st) {
            float4 p = *(const float4*)&part[slot][c4];
            float4 r = *(const float4*)&part[slot + st][c4];
            p.x += r.x; p.y += r.y; p.z += r.z; p.w += r.w;
            *(float4*)&part[slot][c4] = p;
        }
        __syncthreads();
    }
    if (slot == 0) *(float4*)&hconv[(size_t)n * HID + c4] = *(const float4*)&part[0][c4];
}

// ---------------------------------------------------------------- Fourier-Kolmogorov GEMM (split-f16 MFMA)
// Block = 32 nodes x 64 cols (col-half via grid). 4 waves own (row-group 16 x
// K-half 512) tiles -> 1x trig total, in-register A-fragments (read from the
// hsh tile), NO staging LDS, NO in-loop barriers. Epilogue: K-half pairs reduce
// through reused LDS (2 barriers) and write ONE final plane.
__global__ __launch_bounds__(256) void k_fk(const float* __restrict__ h,
        const _Float16* __restrict__ whi, const _Float16* __restrict__ wlo,
        float* __restrict__ p0, int N) {
    __shared__ float smem[32 * 132];            // hsh tile, reused for reduction
    int tid = threadIdx.x;
    int bx = blockIdx.x;
    int nb = (bx >> 1) * 32;
    int c0 = (bx & 1) * 64;
    for (int i = tid; i < 32 * 32; i += 256) {
        int nn = i >> 5, c4 = (i & 31) * 4;
        int gn = nb + nn;
        float4 v = (gn < N) ? *(const float4*)&h[gn * HID + c4] : make_float4(0.f, 0.f, 0.f, 0.f);
        *(float4*)&smem[nn * 132 + c4] = v;
    }
    __syncthreads();
    int lane = tid & 63, wv = tid >> 6;
    int quad = lane >> 4, l16 = lane & 15;
    int rg = wv >> 1;                 // row group: rows nb + rg*16 ..
    int kh = wv & 1;                  // K half: [kh*512, kh*512+512)
    int kbase = kh * 512;
    int fr0 = kh * 4;
    f4 acc0[4], accL[4];
#pragma unroll
    for (int ni = 0; ni < 4; ++ni) { acc0[ni] = (f4)(0.f); accL[ni] = (f4)(0.f); }
    const _Float16* bh[4]; const _Float16* bl[4];
#pragma unroll
    for (int ni = 0; ni < 4; ++ni) {
        size_t off = (size_t)(c0 + ni * 16 + l16) * 1024 + kbase + quad * 8;
        bh[ni] = whi + off;
        bl[ni] = wlo + off;
    }
    const float* hrow = &smem[(rg * 16 + l16) * 132];
#pragma unroll 2
    for (int step = 0; step < 16; ++step) {
        int kg0 = kbase + step * 32 + quad * 8;
        int fr = kg0 >> 7;
        int ii = kg0 & 127;
        float freqf = 6.2831853f * (float)(fr + 1);
        float4 h0 = *(const float4*)&hrow[ii];
        float4 h1 = *(const float4*)&hrow[ii + 4];
        float hv[8] = {h0.x, h0.y, h0.z, h0.w, h1.x, h1.y, h1.z, h1.w};
        half8 ah, al;
#pragma unroll
        for (int j = 0; j < 8; ++j) {
            float ang = freqf * hv[j] + 0.78539816f;
            float a = 1.41421356f * __sinf(ang);   // sin + cos
            _Float16 hi = (_Float16)a;
            ah[j] = hi;
            al[j] = (_Float16)((a - (float)hi) * 2048.f);
        }
        int ko = step * 32;
#pragma unroll
        for (int ni = 0; ni < 4; ++ni) {
            half8 wh_ = *(const half8*)(bh[ni] + ko);
            half8 wl_ = *(const half8*)(bl[ni] + ko);
            acc0[ni] = __builtin_amdgcn_mfma_f32_16x16x32_f16(ah, wh_, acc0[ni], 0, 0, 0);
            accL[ni] = __builtin_amdgcn_mfma_f32_16x16x32_f16(ah, wl_, accL[ni], 0, 0, 0);
            accL[ni] = __builtin_amdgcn_mfma_f32_16x16x32_f16(al, wh_, accL[ni], 0, 0, 0);
        }
    }
    // fold low-part
    const float inv = 1.0f / 2048.0f;
    float vals[16];
#pragma unroll
    for (int ni = 0; ni < 4; ++ni)
#pragma unroll
        for (int r = 0; r < 4; ++r)
            vals[ni * 4 + r] = acc0[ni][r] + accL[ni][r] * inv;
    __syncthreads();                  // hsh dead; reuse smem for reduction
    float* red = smem + rg * 1088;    // 16 x (64+4) floats per row-group
    if (kh == 1) {
#pragma unroll
        for (int j = 0; j < 16; ++j) red[j * 68 + lane] = vals[j];
    }
    __syncthreads();
    if (kh == 0) {
#pragma unroll
        for (int j = 0; j < 16; ++j) vals[j] += red[j * 68 + lane];
#pragma unroll
        for (int ni = 0; ni < 4; ++ni)
#pragma unroll
            for (int r = 0; r < 4; ++r) {
                int gn = nb + rg * 16 + quad * 4 + r;
                if (gn < N)
                    p0[(size_t)gn * HID + c0 + ni * 16 + l16] = vals[ni * 4 + r];
            }
    }
}

// ---------------------------------------------------------------- batchnorm stats (single FK plane)
__global__ void k_bn_stats(float* __restrict__ hconv, const float* __restrict__ p0,
                           const float* __restrict__ fkb,
                           double* __restrict__ stats, int N) {
    int c = threadIdx.x & 127, half = threadIdx.x >> 7;
    float bias = fkb[c];
    float s = 0.f, s2 = 0.f;
    for (int n = blockIdx.x * 2 + half; n < N; n += gridDim.x * 2) {
        int idx = n * HID + c;
        float v = hconv[idx] + p0[idx] + bias;
        hconv[idx] = v;
        s += v; s2 += v * v;
    }
    __shared__ float sh[256], sh2[256];
    sh[threadIdx.x] = s; sh2[threadIdx.x] = s2;
    __syncthreads();
    if (half == 0) {
        s = sh[c] + sh[128 + c];
        s2 = sh2[c] + sh2[128 + c];
        atomicAdd(&stats[c], (double)s);
        atomicAdd(&stats[128 + c], (double)s2);
    }
}

// bn_final folded in; optionally computes pool scores (last layer)
__global__ void k_bn_apply(const float* __restrict__ hsum, const double* __restrict__ stats,
                           const float* __restrict__ g, const float* __restrict__ b,
                           const float* __restrict__ pw, const float* __restrict__ pb,
                           float* __restrict__ h, float* __restrict__ s,
                           int do_score, int N) {
    __shared__ float red[4];
    int idx = blockIdx.x * 256 + threadIdx.x;
    int valid = idx < N * HID;
    int c = idx & 127;
    double invN = 1.0 / (double)N;
    float mu = (float)(stats[c] * invN);
    float var = (float)(stats[128 + c] * invN) - mu * mu;
    float inv = 1.f / sqrtf(var + 1e-5f);
    float sc = g[c] * inv;
    float sh = b[c] - mu * sc;
    float o = 0.f;
    if (valid) {
        o = fmaxf(hsum[idx] * sc + sh, 0.f);
        h[idx] = o;
    }
    if (do_score) {
        float p = valid ? o * pw[c] : 0.f;
        for (int off = 32; off > 0; off >>= 1) p += __shfl_down(p, off);
        int wid = threadIdx.x >> 6;
        if ((threadIdx.x & 63) == 0) red[wid] = p;
        __syncthreads();
        int row = idx >> 7;
        int half = threadIdx.x >> 7;
        if ((threadIdx.x & 127) == 0 && row < N)
            s[row] = red[half * 2] + red[half * 2 + 1] + pb[0];
    }
}

// ---------------------------------------------------------------- softmax partials
__global__ void k_smax1(const float* __restrict__ s, float* __restrict__ mzp, int N) {
    __shared__ float red[256];
    float m = -INFINITY;
    for (int n = blockIdx.x * 256 + threadIdx.x; n < N; n += SMAXB * 256)
        m = fmaxf(m, s[n]);
    red[threadIdx.x] = m;
    __syncthreads();
    for (int off = 128; off > 0; off >>= 1) {
        if (threadIdx.x < (unsigned)off)
            red[threadIdx.x] = fmaxf(red[threadIdx.x], red[threadIdx.x + off]);
        __syncthreads();
    }
    m = red[0];
    __syncthreads();
    float z = 0.f;
    for (int n = blockIdx.x * 256 + threadIdx.x; n < N; n += SMAXB * 256)
        z += __expf(s[n] - m);
    red[threadIdx.x] = z;
    __syncthreads();
    for (int off = 128; off > 0; off >>= 1) {
        if (threadIdx.x < (unsigned)off) red[threadIdx.x] += red[threadIdx.x + off];
        __syncthreads();
    }
    if (threadIdx.x == 0) { mzp[blockIdx.x * 2] = m; mzp[blockIdx.x * 2 + 1] = red[0]; }
}

__device__ __forceinline__ void combine_mz(const float* mzp, float& m, float& Z) {
    m = -INFINITY;
#pragma unroll 8
    for (int i = 0; i < SMAXB; ++i) m = fmaxf(m, mzp[i * 2]);
    Z = 0.f;
#pragma unroll 8
    for (int i = 0; i < SMAXB; ++i) Z += mzp[i * 2 + 1] * __expf(mzp[i * 2] - m);
}

// ---------------------------------------------------------------- attention pool (split)
__global__ void k_pool_part(const float* __restrict__ h, const float* __restrict__ s,
                            const float* __restrict__ mzp, const int* __restrict__ boffs,
                            float* __restrict__ part) {
    int b = blockIdx.x >> 4, split = blockIdx.x & (PSPLIT - 1);
    int c = threadIdx.x & 127, half = threadIdx.x >> 7;
    float m, Z;
    combine_mz(mzp, m, Z);
    (void)Z;
    int n0 = boffs[b], n1 = boffs[b + 1];
    float acc = 0.f;
    for (int n = n0 + split * 2 + half; n < n1; n += PSPLIT * 2)
        acc += __expf(s[n] - m) * h[n * HID + c];
    __shared__ float prt[2][HID];
    prt[half][c] = acc;
    __syncthreads();
    if (half == 0) part[(size_t)(b * PSPLIT + split) * HID + c] = prt[0][c] + prt[1][c];
}

__global__ void k_pool_sum(const float* __restrict__ part, const float* __restrict__ mzp,
                           float* __restrict__ pooled) {
    int b = blockIdx.x, c = threadIdx.x;
    float m, Z;
    combine_mz(mzp, m, Z);
    float acc = 0.f;
#pragma unroll
    for (int i = 0; i < PSPLIT; ++i) acc += part[(size_t)(b * PSPLIT + i) * HID + c];
    pooled[b * HID + c] = acc / Z;
}

// ---------------------------------------------------------------- heads (grid = B*4)
__global__ __launch_bounds__(256) void k_head(const float* __restrict__ pooled,
                       const float* __restrict__ sg_table,
                       const int* __restrict__ space_group,
                       const float* __restrict__ hw1, const float* __restrict__ hb1,
                       const float* __restrict__ ew2, const float* __restrict__ eb2,
                       const float* __restrict__ sw2, const float* __restrict__ sb2,
                       const float* __restrict__ cw2, const float* __restrict__ cb2,
                       const float* __restrict__ mw2, const float* __restrict__ mb2,
                       float* __restrict__ out, int B) {
    __shared__ float comb[256];
    __shared__ float zred[2][128];
    __shared__ float zsh[128];
    int b = blockIdx.x >> 2, i = blockIdx.x & 3;
    int t = threadIdx.x;
    comb[t] = (t < 128) ? pooled[b * HID + t] : sg_table[space_group[b] * HID + (t - 128)];
    __syncthreads();
    int half = t >> 7, tt = t & 127;
    const float* W = hw1 + ((size_t)i * 256 + half * 128) * HID;
    const float* cb = &comb[half * 128];
    float z = 0.f;
#pragma unroll 8
    for (int k = 0; k < 128; ++k) z += cb[k] * W[k * HID + tt];
    zred[half][tt] = z;
    __syncthreads();
    if (t < 128) zsh[t] = fmaxf(zred[0][t] + zred[1][t] + hb1[i * HID + t], 0.f);
    __syncthreads();
    const int od[4] = {1, 3, 7, 3};
    const int base[4] = {0, 64, 256, 704};
    const float* w2 = (i == 0) ? ew2 : (i == 1) ? sw2 : (i == 2) ? cw2 : mw2;
    const float* b2 = (i == 0) ? eb2 : (i == 1) ? sb2 : (i == 2) ? cb2 : mb2;
    int odi = od[i];
    if (t < odi) {
        float o = b2[t];
        for (int c = 0; c < HID; ++c) o += zsh[c] * w2[c * odi + t];
        out[base[i] + b * odi + t] = o;
    }
}

// ---------------------------------------------------------------- launch
extern "C" void kernel_launch(void* const* d_in, const int* in_sizes, int n_in,
                              void* d_out, int out_size, void* d_ws, size_t ws_size,
                              hipStream_t stream) {
    const float* x          = (const float*)d_in[0];
    const int*   edge_index = (const int*)d_in[1];
    const float* edge_attr  = (const float*)d_in[2];
    const int*   batch      = (const int*)d_in[3];
    const int*   space_group= (const int*)d_in[4];
    const float* node_w     = (const float*)d_in[5];
    const float* node_b     = (const float*)d_in[6];
    const float* sg_table   = (const float*)d_in[7];
    const float* lin_w      = (const float*)d_in[8];
    const float* lin_b      = (const float*)d_in[9];
    const float* att_w      = (const float*)d_in[10];
    const float* att_b      = (const float*)d_in[11];
    const float* fk_w       = (const float*)d_in[12];
    const float* fk_b       = (const float*)d_in[13];
    const float* bn_g       = (const float*)d_in[14];
    const float* bn_b       = (const float*)d_in[15];
    const float* pool_w     = (const float*)d_in[16];
    const float* pool_b     = (const float*)d_in[17];
    const float* head_w1    = (const float*)d_in[18];
    const float* head_b1    = (const float*)d_in[19];
    const float* ew2 = (const float*)d_in[20]; const float* eb2 = (const float*)d_in[21];
    const float* sw2 = (const float*)d_in[22]; const float* sb2 = (const float*)d_in[23];
    const float* cw2 = (const float*)d_in[24]; const float* cb2 = (const float*)d_in[25];
    const float* mw2 = (const float*)d_in[26]; const float* mb2 = (const float*)d_in[27];
    float* out = (float*)d_out;

    const int N = in_sizes[3];
    const int E = in_sizes[1] / 2;
    const int B = in_sizes[4];
    const int* src = edge_index;
    const int* dst = edge_index + E;

    char* w = (char*)d_ws;
    auto alloc = [&](size_t bytes) { char* p = w; w += (bytes + 255) & ~(size_t)255; return p; };
    float*  h      = (float*)alloc((size_t)N * HID * 4);
    float*  A1     = (float*)alloc((size_t)N * HID * 4);  // reused as FK output plane
    float*  A2     = (float*)alloc((size_t)N * HID * 4);
    float*  hconv  = (float*)alloc((size_t)N * HID * 4);  // becomes pre-BN sum in place
    float*  a1     = (float*)alloc((size_t)N * 4);
    float*  a2     = (float*)alloc((size_t)N * 4);
    float*  sbuf   = (float*)alloc((size_t)N * 4);
    int*    deg    = (int*)alloc((size_t)N * 4);
    int*    cursor = (int*)alloc((size_t)N * 4);
    int*    offs   = (int*)alloc((size_t)(N + 1) * 4);
    int*    eord   = (int*)alloc((size_t)E * 4);
    int*    srco   = (int*)alloc((size_t)E * 4);
    float4* ea3o   = (float4*)alloc((size_t)E * 16);
    _Float16* whi  = (_Float16*)alloc((size_t)DEPTH * 1024 * HID * 2);
    _Float16* wlo  = (_Float16*)alloc((size_t)DEPTH * 1024 * HID * 2);
    int*    bsum   = (int*)alloc(256 * 4);
    int*    boffs  = (int*)alloc((size_t)(B + 1) * 4);
    double* stats  = (double*)alloc(256 * 8);
    float*  mzp    = (float*)alloc(SMAXB * 2 * 4);
    float*  part   = (float*)alloc((size_t)B * PSPLIT * HID * 4);
    float*  pooled = (float*)alloc((size_t)B * HID * 4);

    const int nchunk = (N + 255) / 256;
    const int echunk = (E + 255) / 256;
    const int ntile  = (N + 31) / 32;

    // one-time per launch: W split + CSR build
    k_wsplit<<<128, 256, 0, stream>>>(fk_w, whi, wlo);
    hipMemsetAsync(deg, 0, (size_t)N * 4, stream);
    k_hist<<<echunk, 256, 0, stream>>>(dst, deg, E);
    k_scan_a<<<nchunk, 256, 0, stream>>>(deg, bsum, N);
    k_scan_b<<<1, 256, 0, stream>>>(bsum, nchunk);
    k_scan_c<<<nchunk, 256, 0, stream>>>(deg, bsum, offs, cursor, N);
    k_scatter<<<echunk, 256, 0, stream>>>(src, dst, cursor, eord, srco, E);
    k_eaord<<<echunk, 256, 0, stream>>>(eord, edge_attr, ea3o, E);
    k_bstart<<<nchunk, 256, 0, stream>>>(batch, boffs, N, B);

    k_node_embed<<<(N * HID + 255) / 256, 256, 0, stream>>>(x, node_w, node_b, h, N);

    for (int l = 0; l < DEPTH; ++l) {
        const float* linw_l = lin_w + (size_t)l * 259 * HID;
        k_node_lin<<<(N + 7) / 8, 256, 0, stream>>>(
            h, linw_l, lin_b + l * HID, att_w + (size_t)l * 259, att_b + l,
            A1, A2, a1, a2, N);
        k_edge<<<N, 256, 0, stream>>>(A1, A2, a1, a2, srco, ea3o, offs,
                                      linw_l + 256 * HID, att_w + (size_t)l * 259 + 256,
                                      hconv, stats, N);
        // A1 now dead -> reuse as the single FK output plane
        k_fk<<<ntile * 2, 256, 0, stream>>>(
            h, whi + (size_t)l * 131072, wlo + (size_t)l * 131072, A1, N);
        k_bn_stats<<<320, 256, 0, stream>>>(hconv, A1, fk_b + l * HID, stats, N);
        k_bn_apply<<<(N * HID + 255) / 256, 256, 0, stream>>>(
            hconv, stats, bn_g + l * HID, bn_b + l * HID, pool_w, pool_b,
            h, sbuf, (l == DEPTH - 1) ? 1 : 0, N);
    }

    k_smax1<<<SMAXB, 256, 0, stream>>>(sbuf, mzp, N);
    k_pool_part<<<B * PSPLIT, 256, 0, stream>>>(h, sbuf, mzp, boffs, part);
    k_pool_sum<<<B, 128, 0, stream>>>(part, mzp, pooled);
    k_head<<<B * 4, 256, 0, stream>>>(pooled, sg_table, space_group, head_w1, head_b1,
                                      ew2, eb2, sw2, sb2, cw2, cb2, mw2, mb2, out, B);
}

// Round 15
// 813.418 us; speedup vs baseline: 1.2296x; 1.1035x over previous
//
#include <hip/hip_runtime.h>
#include <math.h>

#define HID 128
#define DEPTH 4
#define PSPLIT 16
#define SMAXB 40

typedef _Float16 half8 __attribute__((ext_vector_type(8)));
typedef float f4 __attribute__((ext_vector_type(4)));

// ---------------------------------------------------------------- node embed
__global__ void k_node_embed(const float* __restrict__ x, const float* __restrict__ nw,
                             const float* __restrict__ nb, float* __restrict__ h, int N) {
    int idx = blockIdx.x * blockDim.x + threadIdx.x;
    if (idx >= N * HID) return;
    int n = idx >> 7, c = idx & 127;
    float acc = nb[c];
#pragma unroll
    for (int d = 0; d < 4; ++d) acc += x[n * 4 + d] * nw[d * HID + c];
    h[idx] = acc;
}

// ---------------------------------------------------------------- W split+transpose (once per launch)
__global__ void k_wsplit(const float* __restrict__ fkw, _Float16* __restrict__ whi,
                         _Float16* __restrict__ wlo) {
    __shared__ float sh[64][65];
    int bid = blockIdx.x;           // 4 layers * 16 kblk * 2 nblk = 128 blocks
    int l = bid >> 5; int r = bid & 31; int kb = r >> 1; int nbk = r & 1;
    const float* W = fkw + (size_t)l * 131072;
    _Float16* Hl = whi + (size_t)l * 131072;
    _Float16* Ll = wlo + (size_t)l * 131072;
    int k0 = kb * 64, n0 = nbk * 64;
    for (int i = threadIdx.x; i < 4096; i += 256) {
        int kk = i >> 6, nn = i & 63;
        sh[kk][nn] = W[(k0 + kk) * HID + n0 + nn];
    }
    __syncthreads();
    for (int i = threadIdx.x; i < 4096; i += 256) {
        int nn = i >> 6, kk = i & 63;
        float w = sh[kk][nn];
        _Float16 hi = (_Float16)w;
        _Float16 lo = (_Float16)((w - (float)hi) * 2048.f);
        Hl[(n0 + nn) * 1024 + k0 + kk] = hi;
        Ll[(n0 + nn) * 1024 + k0 + kk] = lo;
    }
}

// ---------------------------------------------------------------- CSR build
__global__ void k_hist(const int* __restrict__ dst, int* __restrict__ deg, int E) {
    int e = blockIdx.x * 256 + threadIdx.x;
    if (e < E) atomicAdd(&deg[dst[e]], 1);
}

__global__ void k_scan_a(const int* __restrict__ deg, int* __restrict__ bsum, int N) {
    __shared__ int sh[256];
    int i = blockIdx.x * 256 + threadIdx.x;
    sh[threadIdx.x] = (i < N) ? deg[i] : 0;
    __syncthreads();
    for (int off = 128; off > 0; off >>= 1) {
        if (threadIdx.x < (unsigned)off) sh[threadIdx.x] += sh[threadIdx.x + off];
        __syncthreads();
    }
    if (threadIdx.x == 0) bsum[blockIdx.x] = sh[0];
}

__global__ void k_scan_b(int* __restrict__ bsum, int nb) {
    __shared__ int sh[256];
    int v = (threadIdx.x < (unsigned)nb) ? bsum[threadIdx.x] : 0;
    sh[threadIdx.x] = v;
    __syncthreads();
    for (int off = 1; off < 256; off <<= 1) {
        int add = (threadIdx.x >= (unsigned)off) ? sh[threadIdx.x - off] : 0;
        __syncthreads();
        sh[threadIdx.x] += add;
        __syncthreads();
    }
    if (threadIdx.x < (unsigned)nb) bsum[threadIdx.x] = sh[threadIdx.x] - v;
}

__global__ void k_scan_c(const int* __restrict__ deg, const int* __restrict__ bsum,
                         int* __restrict__ offs, int* __restrict__ cursor, int N) {
    __shared__ int sh[256];
    int i = blockIdx.x * 256 + threadIdx.x;
    int v = (i < N) ? deg[i] : 0;
    sh[threadIdx.x] = v;
    __syncthreads();
    for (int off = 1; off < 256; off <<= 1) {
        int add = (threadIdx.x >= (unsigned)off) ? sh[threadIdx.x - off] : 0;
        __syncthreads();
        sh[threadIdx.x] += add;
        __syncthreads();
    }
    int ex = bsum[blockIdx.x] + sh[threadIdx.x] - v;
    if (i < N) { offs[i] = ex; cursor[i] = ex; }
    if (i == N - 1) offs[N] = ex + v;
}

__global__ void k_scatter(const int* __restrict__ src, const int* __restrict__ dst,
                          int* cursor, int* __restrict__ eord,
                          int* __restrict__ srco, int E) {
    int e = blockIdx.x * 256 + threadIdx.x;
    if (e < E) {
        int d = dst[e];
        int p = atomicAdd(&cursor[d], 1);
        eord[p] = e;
        srco[p] = src[e];
    }
}

__global__ void k_eaord(const int* __restrict__ eord, const float* __restrict__ ea,
                        float4* __restrict__ ea3o, int E) {
    int idx = blockIdx.x * 256 + threadIdx.x;
    if (idx >= E) return;
    int e = eord[idx];
    float4 q;
    q.x = ea[e * 3 + 0]; q.y = ea[e * 3 + 1]; q.z = ea[e * 3 + 2]; q.w = 0.f;
    ea3o[idx] = q;
}

__global__ void k_bstart(const int* __restrict__ batch, int* __restrict__ boffs, int N, int B) {
    int n = blockIdx.x * 256 + threadIdx.x;
    if (n >= N) return;
    int b1 = batch[n];
    if (n == 0) for (int b = 0; b <= b1; ++b) boffs[b] = 0;
    int b2 = (n + 1 < N) ? batch[n + 1] : B;
    for (int b = b1 + 1; b <= b2; ++b) boffs[b] = n + 1;
}

// ---------------------------------------------------------------- per-node linear + attention dots (fused, fp32)
__global__ __launch_bounds__(256) void k_node_lin(const float* __restrict__ h,
                           const float* __restrict__ linw, const float* __restrict__ linb,
                           const float* __restrict__ attw, const float* __restrict__ attb,
                           float* __restrict__ A1, float* __restrict__ A2,
                           float* __restrict__ a1, float* __restrict__ a2, int N) {
    __shared__ float hT[HID][12];
    int nb = blockIdx.x * 8;
    int tid = threadIdx.x;
    for (int i = tid; i < 8 * HID; i += 256) {
        int n = i >> 7, c = i & 127;
        int gn = nb + n;
        hT[c][n] = (gn < N) ? h[gn * HID + c] : 0.f;
    }
    __syncthreads();
    {
        int node = tid >> 5, lane32 = tid & 31;
        float p1 = 0.f, p2 = 0.f;
#pragma unroll
        for (int j = 0; j < 4; ++j) {
            int k = lane32 * 4 + j;
            float hv = hT[k][node];
            p1 += hv * attw[k];
            p2 += hv * attw[128 + k];
        }
        for (int off = 16; off > 0; off >>= 1) {
            p1 += __shfl_down(p1, off, 32);
            p2 += __shfl_down(p2, off, 32);
        }
        int gn = nb + node;
        if (lane32 == 0 && gn < N) {
            a1[gn] = p1 + attb[0];
            a2[gn] = p2;
        }
    }
    int c = tid & 127, r = tid >> 7;
    const float* Wd = linw;
    const float* Ws = linw + 128 * HID;
    float acc1[4] = {0, 0, 0, 0}, acc2[4] = {0, 0, 0, 0};
#pragma unroll 4
    for (int k = 0; k < HID; ++k) {
        float wd = Wd[k * HID + c];
        float ws = Ws[k * HID + c];
        float4 hv = *(const float4*)&hT[k][r * 4];
        acc1[0] += hv.x * wd; acc2[0] += hv.x * ws;
        acc1[1] += hv.y * wd; acc2[1] += hv.y * ws;
        acc1[2] += hv.z * wd; acc2[2] += hv.z * ws;
        acc1[3] += hv.w * wd; acc2[3] += hv.w * ws;
    }
#pragma unroll
    for (int j = 0; j < 4; ++j) {
        int gn = nb + r * 4 + j;
        if (gn < N) {
            A1[gn * HID + c] = acc1[j] + linb[c];
            A2[gn * HID + c] = acc2[j];
        }
    }
}

// ---------------------------------------------------------------- FUSED edge-conv + FK-GEMM dispatch
// blocks [0, nfkb): FK GEMM (R6 register-trig body, hsh LDS only, no K-loop
// barriers, K-split 2, writes dedicated planes pf0/pf1).
// blocks [nfkb, nfkb+N): edge conv (CSR, 8 slots, float4, alpha fused).
// Both are latency-bound with idle pipes -> co-residency overlaps them.
__global__ __launch_bounds__(256) void k_edge_fk(
        const float* __restrict__ h,
        const _Float16* __restrict__ whi, const _Float16* __restrict__ wlo,
        float* __restrict__ pf0, float* __restrict__ pf1,
        const float* __restrict__ A1, const float* __restrict__ A2,
        const float* __restrict__ a1, const float* __restrict__ a2,
        const int* __restrict__ srco, const float4* __restrict__ ea3o,
        const int* __restrict__ offs, const float* __restrict__ linw3,
        const float* __restrict__ attw3, float* __restrict__ hconv,
        double* __restrict__ stats, int nfkb, int N) {
    __shared__ float smem[32 * 132];   // 16896 B: fk hsh tile / edge scratch
    int bx = blockIdx.x;
    int tid = threadIdx.x;
    if (bx < nfkb) {
        // ---------------- FK branch (R6 body) ----------------
        int nb = (bx >> 1) * 32;
        int ks = bx & 1;
        int kbase = ks * 512;
        for (int i = tid; i < 32 * 32; i += 256) {
            int nn = i >> 5, c4 = (i & 31) * 4;
            int gn = nb + nn;
            float4 v = (gn < N) ? *(const float4*)&h[gn * HID + c4]
                                : make_float4(0.f, 0.f, 0.f, 0.f);
            *(float4*)&smem[nn * 132 + c4] = v;
        }
        __syncthreads();
        int lane = tid & 63, wv = tid >> 6;
        int quad = lane >> 4, l16 = lane & 15;
        int n0w = wv * 32;
        f4 acc0[2][2], accL[2][2];
#pragma unroll
        for (int mi = 0; mi < 2; ++mi)
#pragma unroll
            for (int ni = 0; ni < 2; ++ni) { acc0[mi][ni] = (f4)(0.f); accL[mi][ni] = (f4)(0.f); }
        const _Float16* bhp0 = whi + (size_t)(n0w + l16) * 1024 + kbase + quad * 8;
        const _Float16* bhp1 = whi + (size_t)(n0w + 16 + l16) * 1024 + kbase + quad * 8;
        const _Float16* blp0 = wlo + (size_t)(n0w + l16) * 1024 + kbase + quad * 8;
        const _Float16* blp1 = wlo + (size_t)(n0w + 16 + l16) * 1024 + kbase + quad * 8;
#pragma unroll 2
        for (int step = 0; step < 16; ++step) {
            int kg0 = kbase + step * 32 + quad * 8;
            int fr = kg0 >> 7;
            int ii = kg0 & 127;
            float freqf = 6.2831853f * (float)(fr + 1);
            half8 ah[2], al[2];
#pragma unroll
            for (int mi = 0; mi < 2; ++mi) {
                const float* hp = &smem[(mi * 16 + l16) * 132 + ii];
                float4 h0 = *(const float4*)hp;
                float4 h1 = *(const float4*)(hp + 4);
                float hv[8] = {h0.x, h0.y, h0.z, h0.w, h1.x, h1.y, h1.z, h1.w};
#pragma unroll
                for (int j = 0; j < 8; ++j) {
                    float ang = freqf * hv[j] + 0.78539816f;
                    float a = 1.41421356f * __sinf(ang);   // sin + cos
                    _Float16 hi = (_Float16)a;
                    ah[mi][j] = hi;
                    al[mi][j] = (_Float16)((a - (float)hi) * 2048.f);
                }
            }
            int ko = step * 32;
            half8 bh0 = *(const half8*)(bhp0 + ko);
            half8 bh1 = *(const half8*)(bhp1 + ko);
            half8 bl0 = *(const half8*)(blp0 + ko);
            half8 bl1 = *(const half8*)(blp1 + ko);
            acc0[0][0] = __builtin_amdgcn_mfma_f32_16x16x32_f16(ah[0], bh0, acc0[0][0], 0, 0, 0);
            acc0[0][1] = __builtin_amdgcn_mfma_f32_16x16x32_f16(ah[0], bh1, acc0[0][1], 0, 0, 0);
            acc0[1][0] = __builtin_amdgcn_mfma_f32_16x16x32_f16(ah[1], bh0, acc0[1][0], 0, 0, 0);
            acc0[1][1] = __builtin_amdgcn_mfma_f32_16x16x32_f16(ah[1], bh1, acc0[1][1], 0, 0, 0);
            accL[0][0] = __builtin_amdgcn_mfma_f32_16x16x32_f16(ah[0], bl0, accL[0][0], 0, 0, 0);
            accL[0][1] = __builtin_amdgcn_mfma_f32_16x16x32_f16(ah[0], bl1, accL[0][1], 0, 0, 0);
            accL[1][0] = __builtin_amdgcn_mfma_f32_16x16x32_f16(ah[1], bl0, accL[1][0], 0, 0, 0);
            accL[1][1] = __builtin_amdgcn_mfma_f32_16x16x32_f16(ah[1], bl1, accL[1][1], 0, 0, 0);
            accL[0][0] = __builtin_amdgcn_mfma_f32_16x16x32_f16(al[0], bh0, accL[0][0], 0, 0, 0);
            accL[0][1] = __builtin_amdgcn_mfma_f32_16x16x32_f16(al[0], bh1, accL[0][1], 0, 0, 0);
            accL[1][0] = __builtin_amdgcn_mfma_f32_16x16x32_f16(al[1], bh0, accL[1][0], 0, 0, 0);
            accL[1][1] = __builtin_amdgcn_mfma_f32_16x16x32_f16(al[1], bh1, accL[1][1], 0, 0, 0);
        }
        float* p = ks ? pf1 : pf0;
        const float inv = 1.0f / 2048.0f;
#pragma unroll
        for (int mi = 0; mi < 2; ++mi)
#pragma unroll
            for (int ni = 0; ni < 2; ++ni)
#pragma unroll
                for (int r = 0; r < 4; ++r) {
                    int gn = nb + mi * 16 + quad * 4 + r;
                    if (gn < N)
                        p[gn * HID + n0w + ni * 16 + l16] = acc0[mi][ni][r] + accL[mi][ni][r] * inv;
                }
    } else {
        // ---------------- edge branch ----------------
        int n = bx - nfkb;
        if (n == 0) stats[tid] = 0.0;
        float* w3s  = smem;            // 384 floats
        float* aw3s = smem + 384;      // 3 floats
        float* partf = smem + 388;     // 8*128 floats (16B-aligned: 388*4=1552)
        int lane32 = tid & 31, slot = tid >> 5;
        int c4 = lane32 * 4;
        for (int i = tid; i < 3 * HID; i += 256) w3s[i] = linw3[i];
        if (tid < 3) aw3s[tid] = attw3[tid];
        __syncthreads();
        float4 w0v = *(const float4*)&w3s[c4];
        float4 w1v = *(const float4*)&w3s[HID + c4];
        float4 w2v = *(const float4*)&w3s[2 * HID + c4];
        float aw0 = aw3s[0], aw1 = aw3s[1], aw2 = aw3s[2];
        float a1n = a1[n];
        float4 A1v = *(const float4*)&A1[(size_t)n * HID + c4];
        float4 acc; acc.x = acc.y = acc.z = acc.w = 0.f;
        int s0 = offs[n], s1 = offs[n + 1];
        for (int idx = s0 + slot; idx < s1; idx += 8) {
            int s = srco[idx];
            float4 q = ea3o[idx];
            float logit = a1n + a2[s] + q.x * aw0 + q.y * aw1 + q.z * aw2;
            float al = 1.f / (1.f + __expf(-logit));
            float4 a2v = *(const float4*)&A2[(size_t)s * HID + c4];
            float4 pre;
            pre.x = A1v.x + a2v.x + q.x * w0v.x + q.y * w1v.x + q.z * w2v.x;
            pre.y = A1v.y + a2v.y + q.x * w0v.y + q.y * w1v.y + q.z * w2v.y;
            pre.z = A1v.z + a2v.z + q.x * w0v.z + q.y * w1v.z + q.z * w2v.z;
            pre.w = A1v.w + a2v.w + q.x * w0v.w + q.y * w1v.w + q.z * w2v.w;
            acc.x += al * pre.x; acc.y += al * pre.y;
            acc.z += al * pre.z; acc.w += al * pre.w;
        }
        *(float4*)&partf[slot * HID + c4] = acc;
        __syncthreads();
        for (int st = 4; st >= 1; st >>= 1) {
            if (slot < st) {
                float4 p = *(const float4*)&partf[slot * HID + c4];
                float4 r = *(const float4*)&partf[(slot + st) * HID + c4];
                p.x += r.x; p.y += r.y; p.z += r.z; p.w += r.w;
                *(float4*)&partf[slot * HID + c4] = p;
            }
            __syncthreads();
        }
        if (slot == 0) *(float4*)&hconv[(size_t)n * HID + c4] = *(const float4*)&partf[c4];
    }
}

// ---------------------------------------------------------------- batchnorm stats (3 streams)
__global__ void k_bn_stats(float* __restrict__ hconv,
                           const float* __restrict__ p0, const float* __restrict__ p1,
                           const float* __restrict__ fkb,
                           double* __restrict__ stats, int N) {
    int c = threadIdx.x & 127, half = threadIdx.x >> 7;
    float bias = fkb[c];
    float s = 0.f, s2 = 0.f;
    for (int n = blockIdx.x * 2 + half; n < N; n += gridDim.x * 2) {
        int idx = n * HID + c;
        float v = hconv[idx] + p0[idx] + p1[idx] + bias;
        hconv[idx] = v;
        s += v; s2 += v * v;
    }
    __shared__ float sh[256], sh2[256];
    sh[threadIdx.x] = s; sh2[threadIdx.x] = s2;
    __syncthreads();
    if (half == 0) {
        s = sh[c] + sh[128 + c];
        s2 = sh2[c] + sh2[128 + c];
        atomicAdd(&stats[c], (double)s);
        atomicAdd(&stats[128 + c], (double)s2);
    }
}

// bn_final folded in; optionally computes pool scores (last layer)
__global__ void k_bn_apply(const float* __restrict__ hsum, const double* __restrict__ stats,
                           const float* __restrict__ g, const float* __restrict__ b,
                           const float* __restrict__ pw, const float* __restrict__ pb,
                           float* __restrict__ h, float* __restrict__ s,
                           int do_score, int N) {
    __shared__ float red[4];
    int idx = blockIdx.x * 256 + threadIdx.x;
    int valid = idx < N * HID;
    int c = idx & 127;
    double invN = 1.0 / (double)N;
    float mu = (float)(stats[c] * invN);
    float var = (float)(stats[128 + c] * invN) - mu * mu;
    float inv = 1.f / sqrtf(var + 1e-5f);
    float sc = g[c] * inv;
    float sh = b[c] - mu * sc;
    float o = 0.f;
    if (valid) {
        o = fmaxf(hsum[idx] * sc + sh, 0.f);
        h[idx] = o;
    }
    if (do_score) {
        float p = valid ? o * pw[c] : 0.f;
        for (int off = 32; off > 0; off >>= 1) p += __shfl_down(p, off);
        int wid = threadIdx.x >> 6;
        if ((threadIdx.x & 63) == 0) red[wid] = p;
        __syncthreads();
        int row = idx >> 7;
        int half = threadIdx.x >> 7;
        if ((threadIdx.x & 127) == 0 && row < N)
            s[row] = red[half * 2] + red[half * 2 + 1] + pb[0];
    }
}

// ---------------------------------------------------------------- softmax partials
__global__ void k_smax1(const float* __restrict__ s, float* __restrict__ mzp, int N) {
    __shared__ float red[256];
    float m = -INFINITY;
    for (int n = blockIdx.x * 256 + threadIdx.x; n < N; n += SMAXB * 256)
        m = fmaxf(m, s[n]);
    red[threadIdx.x] = m;
    __syncthreads();
    for (int off = 128; off > 0; off >>= 1) {
        if (threadIdx.x < (unsigned)off)
            red[threadIdx.x] = fmaxf(red[threadIdx.x], red[threadIdx.x + off]);
        __syncthreads();
    }
    m = red[0];
    __syncthreads();
    float z = 0.f;
    for (int n = blockIdx.x * 256 + threadIdx.x; n < N; n += SMAXB * 256)
        z += __expf(s[n] - m);
    red[threadIdx.x] = z;
    __syncthreads();
    for (int off = 128; off > 0; off >>= 1) {
        if (threadIdx.x < (unsigned)off) red[threadIdx.x] += red[threadIdx.x + off];
        __syncthreads();
    }
    if (threadIdx.x == 0) { mzp[blockIdx.x * 2] = m; mzp[blockIdx.x * 2 + 1] = red[0]; }
}

__device__ __forceinline__ void combine_mz(const float* mzp, float& m, float& Z) {
    m = -INFINITY;
#pragma unroll 8
    for (int i = 0; i < SMAXB; ++i) m = fmaxf(m, mzp[i * 2]);
    Z = 0.f;
#pragma unroll 8
    for (int i = 0; i < SMAXB; ++i) Z += mzp[i * 2 + 1] * __expf(mzp[i * 2] - m);
}

// ---------------------------------------------------------------- attention pool (split)
__global__ void k_pool_part(const float* __restrict__ h, const float* __restrict__ s,
                            const float* __restrict__ mzp, const int* __restrict__ boffs,
                            float* __restrict__ part) {
    int b = blockIdx.x >> 4, split = blockIdx.x & (PSPLIT - 1);
    int c = threadIdx.x & 127, half = threadIdx.x >> 7;
    float m, Z;
    combine_mz(mzp, m, Z);
    (void)Z;
    int n0 = boffs[b], n1 = boffs[b + 1];
    float acc = 0.f;
    for (int n = n0 + split * 2 + half; n < n1; n += PSPLIT * 2)
        acc += __expf(s[n] - m) * h[n * HID + c];
    __shared__ float prt[2][HID];
    prt[half][c] = acc;
    __syncthreads();
    if (half == 0) part[(size_t)(b * PSPLIT + split) * HID + c] = prt[0][c] + prt[1][c];
}

__global__ void k_pool_sum(const float* __restrict__ part, const float* __restrict__ mzp,
                           float* __restrict__ pooled) {
    int b = blockIdx.x, c = threadIdx.x;
    float m, Z;
    combine_mz(mzp, m, Z);
    float acc = 0.f;
#pragma unroll
    for (int i = 0; i < PSPLIT; ++i) acc += part[(size_t)(b * PSPLIT + i) * HID + c];
    pooled[b * HID + c] = acc / Z;
}

// ---------------------------------------------------------------- heads (grid = B*4)
__global__ __launch_bounds__(256) void k_head(const float* __restrict__ pooled,
                       const float* __restrict__ sg_table,
                       const int* __restrict__ space_group,
                       const float* __restrict__ hw1, const float* __restrict__ hb1,
                       const float* __restrict__ ew2, const float* __restrict__ eb2,
                       const float* __restrict__ sw2, const float* __restrict__ sb2,
                       const float* __restrict__ cw2, const float* __restrict__ cb2,
                       const float* __restrict__ mw2, const float* __restrict__ mb2,
                       float* __restrict__ out, int B) {
    __shared__ float comb[256];
    __shared__ float zred[2][128];
    __shared__ float zsh[128];
    int b = blockIdx.x >> 2, i = blockIdx.x & 3;
    int t = threadIdx.x;
    comb[t] = (t < 128) ? pooled[b * HID + t] : sg_table[space_group[b] * HID + (t - 128)];
    __syncthreads();
    int half = t >> 7, tt = t & 127;
    const float* W = hw1 + ((size_t)i * 256 + half * 128) * HID;
    const float* cb = &comb[half * 128];
    float z = 0.f;
#pragma unroll 8
    for (int k = 0; k < 128; ++k) z += cb[k] * W[k * HID + tt];
    zred[half][tt] = z;
    __syncthreads();
    if (t < 128) zsh[t] = fmaxf(zred[0][t] + zred[1][t] + hb1[i * HID + t], 0.f);
    __syncthreads();
    const int od[4] = {1, 3, 7, 3};
    const int base[4] = {0, 64, 256, 704};
    const float* w2 = (i == 0) ? ew2 : (i == 1) ? sw2 : (i == 2) ? cw2 : mw2;
    const float* b2 = (i == 0) ? eb2 : (i == 1) ? sb2 : (i == 2) ? cb2 : mb2;
    int odi = od[i];
    if (t < odi) {
        float o = b2[t];
        for (int c = 0; c < HID; ++c) o += zsh[c] * w2[c * odi + t];
        out[base[i] + b * odi + t] = o;
    }
}

// ---------------------------------------------------------------- launch
extern "C" void kernel_launch(void* const* d_in, const int* in_sizes, int n_in,
                              void* d_out, int out_size, void* d_ws, size_t ws_size,
                              hipStream_t stream) {
    const float* x          = (const float*)d_in[0];
    const int*   edge_index = (const int*)d_in[1];
    const float* edge_attr  = (const float*)d_in[2];
    const int*   batch      = (const int*)d_in[3];
    const int*   space_group= (const int*)d_in[4];
    const float* node_w     = (const float*)d_in[5];
    const float* node_b     = (const float*)d_in[6];
    const float* sg_table   = (const float*)d_in[7];
    const float* lin_w      = (const float*)d_in[8];
    const float* lin_b      = (const float*)d_in[9];
    const float* att_w      = (const float*)d_in[10];
    const float* att_b      = (const float*)d_in[11];
    const float* fk_w       = (const float*)d_in[12];
    const float* fk_b       = (const float*)d_in[13];
    const float* bn_g       = (const float*)d_in[14];
    const float* bn_b       = (const float*)d_in[15];
    const float* pool_w     = (const float*)d_in[16];
    const float* pool_b     = (const float*)d_in[17];
    const float* head_w1    = (const float*)d_in[18];
    const float* head_b1    = (const float*)d_in[19];
    const float* ew2 = (const float*)d_in[20]; const float* eb2 = (const float*)d_in[21];
    const float* sw2 = (const float*)d_in[22]; const float* sb2 = (const float*)d_in[23];
    const float* cw2 = (const float*)d_in[24]; const float* cb2 = (const float*)d_in[25];
    const float* mw2 = (const float*)d_in[26]; const float* mb2 = (const float*)d_in[27];
    float* out = (float*)d_out;

    const int N = in_sizes[3];
    const int E = in_sizes[1] / 2;
    const int B = in_sizes[4];
    const int* src = edge_index;
    const int* dst = edge_index + E;

    char* w = (char*)d_ws;
    auto alloc = [&](size_t bytes) { char* p = w; w += (bytes + 255) & ~(size_t)255; return p; };
    float*  h      = (float*)alloc((size_t)N * HID * 4);
    float*  A1     = (float*)alloc((size_t)N * HID * 4);
    float*  A2     = (float*)alloc((size_t)N * HID * 4);
    float*  pf0    = (float*)alloc((size_t)N * HID * 4);  // FK partial 0 (dedicated)
    float*  pf1    = (float*)alloc((size_t)N * HID * 4);  // FK partial 1 (dedicated)
    float*  hconv  = (float*)alloc((size_t)N * HID * 4);  // becomes pre-BN sum in place
    float*  a1     = (float*)alloc((size_t)N * 4);
    float*  a2     = (float*)alloc((size_t)N * 4);
    float*  sbuf   = (float*)alloc((size_t)N * 4);
    int*    deg    = (int*)alloc((size_t)N * 4);
    int*    cursor = (int*)alloc((size_t)N * 4);
    int*    offs   = (int*)alloc((size_t)(N + 1) * 4);
    int*    eord   = (int*)alloc((size_t)E * 4);
    int*    srco   = (int*)alloc((size_t)E * 4);
    float4* ea3o   = (float4*)alloc((size_t)E * 16);
    _Float16* whi  = (_Float16*)alloc((size_t)DEPTH * 1024 * HID * 2);
    _Float16* wlo  = (_Float16*)alloc((size_t)DEPTH * 1024 * HID * 2);
    int*    bsum   = (int*)alloc(256 * 4);
    int*    boffs  = (int*)alloc((size_t)(B + 1) * 4);
    double* stats  = (double*)alloc(256 * 8);
    float*  mzp    = (float*)alloc(SMAXB * 2 * 4);
    float*  part   = (float*)alloc((size_t)B * PSPLIT * HID * 4);
    float*  pooled = (float*)alloc((size_t)B * HID * 4);

    const int nchunk = (N + 255) / 256;
    const int echunk = (E + 255) / 256;
    const int nfkb   = ((N + 31) / 32) * 2;

    // one-time per launch: W split + CSR build
    k_wsplit<<<128, 256, 0, stream>>>(fk_w, whi, wlo);
    hipMemsetAsync(deg, 0, (size_t)N * 4, stream);
    k_hist<<<echunk, 256, 0, stream>>>(dst, deg, E);
    k_scan_a<<<nchunk, 256, 0, stream>>>(deg, bsum, N);
    k_scan_b<<<1, 256, 0, stream>>>(bsum, nchunk);
    k_scan_c<<<nchunk, 256, 0, stream>>>(deg, bsum, offs, cursor, N);
    k_scatter<<<echunk, 256, 0, stream>>>(src, dst, cursor, eord, srco, E);
    k_eaord<<<echunk, 256, 0, stream>>>(eord, edge_attr, ea3o, E);
    k_bstart<<<nchunk, 256, 0, stream>>>(batch, boffs, N, B);

    k_node_embed<<<(N * HID + 255) / 256, 256, 0, stream>>>(x, node_w, node_b, h, N);

    for (int l = 0; l < DEPTH; ++l) {
        const float* linw_l = lin_w + (size_t)l * 259 * HID;
        k_node_lin<<<(N + 7) / 8, 256, 0, stream>>>(
            h, linw_l, lin_b + l * HID, att_w + (size_t)l * 259, att_b + l,
            A1, A2, a1, a2, N);
        k_edge_fk<<<nfkb + N, 256, 0, stream>>>(
            h, whi + (size_t)l * 131072, wlo + (size_t)l * 131072, pf0, pf1,
            A1, A2, a1, a2, srco, ea3o, offs,
            linw_l + 256 * HID, att_w + (size_t)l * 259 + 256,
            hconv, stats, nfkb, N);
        k_bn_stats<<<320, 256, 0, stream>>>(hconv, pf0, pf1, fk_b + l * HID, stats, N);
        k_bn_apply<<<(N * HID + 255) / 256, 256, 0, stream>>>(
            hconv, stats, bn_g + l * HID, bn_b + l * HID, pool_w, pool_b,
            h, sbuf, (l == DEPTH - 1) ? 1 : 0, N);
    }

    k_smax1<<<SMAXB, 256, 0, stream>>>(sbuf, mzp, N);
    k_pool_part<<<B * PSPLIT, 256, 0, stream>>>(h, sbuf, mzp, boffs, part);
    k_pool_sum<<<B, 128, 0, stream>>>(part, mzp, pooled);
    k_head<<<B * 4, 256, 0, stream>>>(pooled, sg_table, space_group, head_w1, head_b1,
                                      ew2, eb2, sw2, sb2, cw2, cb2, mw2, mb2, out, B);
}

// Round 16
// 765.186 us; speedup vs baseline: 1.3071x; 1.0630x over previous
//
#include <hip/hip_runtime.h>
#include <math.h>

#define HID 128
#define DEPTH 4
#define PSPLIT 16
#define SMAXB 40

typedef _Float16 half8 __attribute__((ext_vector_type(8)));
typedef float f4 __attribute__((ext_vector_type(4)));

// ---------------------------------------------------------------- node embed
__global__ void k_node_embed(const float* __restrict__ x, const float* __restrict__ nw,
                             const float* __restrict__ nb, float* __restrict__ h, int N) {
    int idx = blockIdx.x * blockDim.x + threadIdx.x;
    if (idx >= N * HID) return;
    int n = idx >> 7, c = idx & 127;
    float acc = nb[c];
#pragma unroll
    for (int d = 0; d < 4; ++d) acc += x[n * 4 + d] * nw[d * HID + c];
    h[idx] = acc;
}

// ---------------------------------------------------------------- W split+transpose (once per launch)
__global__ void k_wsplit(const float* __restrict__ fkw, _Float16* __restrict__ whi,
                         _Float16* __restrict__ wlo) {
    __shared__ float sh[64][65];
    int bid = blockIdx.x;           // 4 layers * 16 kblk * 2 nblk = 128 blocks
    int l = bid >> 5; int r = bid & 31; int kb = r >> 1; int nbk = r & 1;
    const float* W = fkw + (size_t)l * 131072;
    _Float16* Hl = whi + (size_t)l * 131072;
    _Float16* Ll = wlo + (size_t)l * 131072;
    int k0 = kb * 64, n0 = nbk * 64;
    for (int i = threadIdx.x; i < 4096; i += 256) {
        int kk = i >> 6, nn = i & 63;
        sh[kk][nn] = W[(k0 + kk) * HID + n0 + nn];
    }
    __syncthreads();
    for (int i = threadIdx.x; i < 4096; i += 256) {
        int nn = i >> 6, kk = i & 63;
        float w = sh[kk][nn];
        _Float16 hi = (_Float16)w;
        _Float16 lo = (_Float16)((w - (float)hi) * 2048.f);
        Hl[(n0 + nn) * 1024 + k0 + kk] = hi;
        Ll[(n0 + nn) * 1024 + k0 + kk] = lo;
    }
}

// ---------------------------------------------------------------- CSR build
__global__ void k_hist(const int* __restrict__ dst, int* __restrict__ deg, int E) {
    int e = blockIdx.x * 256 + threadIdx.x;
    if (e < E) atomicAdd(&deg[dst[e]], 1);
}

__global__ void k_scan_a(const int* __restrict__ deg, int* __restrict__ bsum, int N) {
    __shared__ int sh[256];
    int i = blockIdx.x * 256 + threadIdx.x;
    sh[threadIdx.x] = (i < N) ? deg[i] : 0;
    __syncthreads();
    for (int off = 128; off > 0; off >>= 1) {
        if (threadIdx.x < (unsigned)off) sh[threadIdx.x] += sh[threadIdx.x + off];
        __syncthreads();
    }
    if (threadIdx.x == 0) bsum[blockIdx.x] = sh[0];
}

__global__ void k_scan_b(int* __restrict__ bsum, int nb) {
    __shared__ int sh[256];
    int v = (threadIdx.x < (unsigned)nb) ? bsum[threadIdx.x] : 0;
    sh[threadIdx.x] = v;
    __syncthreads();
    for (int off = 1; off < 256; off <<= 1) {
        int add = (threadIdx.x >= (unsigned)off) ? sh[threadIdx.x - off] : 0;
        __syncthreads();
        sh[threadIdx.x] += add;
        __syncthreads();
    }
    if (threadIdx.x < (unsigned)nb) bsum[threadIdx.x] = sh[threadIdx.x] - v;
}

__global__ void k_scan_c(const int* __restrict__ deg, const int* __restrict__ bsum,
                         int* __restrict__ offs, int* __restrict__ cursor, int N) {
    __shared__ int sh[256];
    int i = blockIdx.x * 256 + threadIdx.x;
    int v = (i < N) ? deg[i] : 0;
    sh[threadIdx.x] = v;
    __syncthreads();
    for (int off = 1; off < 256; off <<= 1) {
        int add = (threadIdx.x >= (unsigned)off) ? sh[threadIdx.x - off] : 0;
        __syncthreads();
        sh[threadIdx.x] += add;
        __syncthreads();
    }
    int ex = bsum[blockIdx.x] + sh[threadIdx.x] - v;
    if (i < N) { offs[i] = ex; cursor[i] = ex; }
    if (i == N - 1) offs[N] = ex + v;
}

// scatter edges into CSR order; writes srco AND edge_attr (float4) directly
__global__ void k_scatter(const int* __restrict__ src, const int* __restrict__ dst,
                          const float* __restrict__ ea, int* cursor,
                          int* __restrict__ srco, float4* __restrict__ ea3o, int E) {
    int e = blockIdx.x * 256 + threadIdx.x;
    if (e < E) {
        int d = dst[e];
        int p = atomicAdd(&cursor[d], 1);
        srco[p] = src[e];
        float4 q;
        q.x = ea[e * 3 + 0]; q.y = ea[e * 3 + 1]; q.z = ea[e * 3 + 2]; q.w = 0.f;
        ea3o[p] = q;
    }
}

__global__ void k_bstart(const int* __restrict__ batch, int* __restrict__ boffs, int N, int B) {
    int n = blockIdx.x * 256 + threadIdx.x;
    if (n >= N) return;
    int b1 = batch[n];
    if (n == 0) for (int b = 0; b <= b1; ++b) boffs[b] = 0;
    int b2 = (n + 1 < N) ? batch[n + 1] : B;
    for (int b = b1 + 1; b <= b2; ++b) boffs[b] = n + 1;
}

// ---------------------------------------------------------------- per-node linear + attention dots (fused, fp32)
__global__ __launch_bounds__(256) void k_node_lin(const float* __restrict__ h,
                           const float* __restrict__ linw, const float* __restrict__ linb,
                           const float* __restrict__ attw, const float* __restrict__ attb,
                           float* __restrict__ A1, float* __restrict__ A2,
                           float* __restrict__ a1, float* __restrict__ a2, int N) {
    __shared__ float hT[HID][12];
    int nb = blockIdx.x * 8;
    int tid = threadIdx.x;
    for (int i = tid; i < 8 * HID; i += 256) {
        int n = i >> 7, c = i & 127;
        int gn = nb + n;
        hT[c][n] = (gn < N) ? h[gn * HID + c] : 0.f;
    }
    __syncthreads();
    {
        int node = tid >> 5, lane32 = tid & 31;
        float p1 = 0.f, p2 = 0.f;
#pragma unroll
        for (int j = 0; j < 4; ++j) {
            int k = lane32 * 4 + j;
            float hv = hT[k][node];
            p1 += hv * attw[k];
            p2 += hv * attw[128 + k];
        }
        for (int off = 16; off > 0; off >>= 1) {
            p1 += __shfl_down(p1, off, 32);
            p2 += __shfl_down(p2, off, 32);
        }
        int gn = nb + node;
        if (lane32 == 0 && gn < N) {
            a1[gn] = p1 + attb[0];
            a2[gn] = p2;
        }
    }
    int c = tid & 127, r = tid >> 7;
    const float* Wd = linw;
    const float* Ws = linw + 128 * HID;
    float acc1[4] = {0, 0, 0, 0}, acc2[4] = {0, 0, 0, 0};
#pragma unroll 4
    for (int k = 0; k < HID; ++k) {
        float wd = Wd[k * HID + c];
        float ws = Ws[k * HID + c];
        float4 hv = *(const float4*)&hT[k][r * 4];
        acc1[0] += hv.x * wd; acc2[0] += hv.x * ws;
        acc1[1] += hv.y * wd; acc2[1] += hv.y * ws;
        acc1[2] += hv.z * wd; acc2[2] += hv.z * ws;
        acc1[3] += hv.w * wd; acc2[3] += hv.w * ws;
    }
#pragma unroll
    for (int j = 0; j < 4; ++j) {
        int gn = nb + r * 4 + j;
        if (gn < N) {
            A1[gn * HID + c] = acc1[j] + linb[c];
            A2[gn * HID + c] = acc2[j];
        }
    }
}

// ---------------------------------------------------------------- edge conv (CSR, 8 slots, float4, alpha fused)
// also zeroes the bn stats buffer (block 0)
__global__ __launch_bounds__(256) void k_edge(const float* __restrict__ A1,
        const float* __restrict__ A2, const float* __restrict__ a1,
        const float* __restrict__ a2, const int* __restrict__ srco,
        const float4* __restrict__ ea3o, const int* __restrict__ offs,
        const float* __restrict__ linw3, const float* __restrict__ attw3,
        float* __restrict__ hconv, double* __restrict__ stats, int N) {
    __shared__ float w3s[3 * HID];
    __shared__ float aw3s[3];
    __shared__ float part[8][HID];
    int n = blockIdx.x;
    int tid = threadIdx.x;
    if (n == 0) stats[tid] = 0.0;
    int lane32 = tid & 31, slot = tid >> 5;
    int c4 = lane32 * 4;
    for (int i = tid; i < 3 * HID; i += 256) w3s[i] = linw3[i];
    if (tid < 3) aw3s[tid] = attw3[tid];
    __syncthreads();
    float4 w0v = *(const float4*)&w3s[c4];
    float4 w1v = *(const float4*)&w3s[HID + c4];
    float4 w2v = *(const float4*)&w3s[2 * HID + c4];
    float aw0 = aw3s[0], aw1 = aw3s[1], aw2 = aw3s[2];
    float a1n = a1[n];
    float4 A1v = *(const float4*)&A1[(size_t)n * HID + c4];
    float4 acc; acc.x = acc.y = acc.z = acc.w = 0.f;
    int s0 = offs[n], s1 = offs[n + 1];
    for (int idx = s0 + slot; idx < s1; idx += 8) {
        int s = srco[idx];
        float4 q = ea3o[idx];
        float logit = a1n + a2[s] + q.x * aw0 + q.y * aw1 + q.z * aw2;
        float al = 1.f / (1.f + __expf(-logit));
        float4 a2v = *(const float4*)&A2[(size_t)s * HID + c4];
        float4 pre;
        pre.x = A1v.x + a2v.x + q.x * w0v.x + q.y * w1v.x + q.z * w2v.x;
        pre.y = A1v.y + a2v.y + q.x * w0v.y + q.y * w1v.y + q.z * w2v.y;
        pre.z = A1v.z + a2v.z + q.x * w0v.z + q.y * w1v.z + q.z * w2v.z;
        pre.w = A1v.w + a2v.w + q.x * w0v.w + q.y * w1v.w + q.z * w2v.w;
        acc.x += al * pre.x; acc.y += al * pre.y;
        acc.z += al * pre.z; acc.w += al * pre.w;
    }
    *(float4*)&part[slot][c4] = acc;
    __syncthreads();
    for (int st = 4; st >= 1; st >>= 1) {
        if (slot < st) {
            float4 p = *(const float4*)&part[slot][c4];
            float4 r = *(const float4*)&part[slot + st][c4];
            p.x += r.x; p.y += r.y; p.z += r.z; p.w += r.w;
            *(float4*)&part[slot][c4] = p;
        }
        __syncthreads();
    }
    if (slot == 0) *(float4*)&hconv[(size_t)n * HID + c4] = *(const float4*)&part[0][c4];
}

// ---------------------------------------------------------------- Fourier-Kolmogorov GEMM (split-f16 MFMA)
// R11 structure: K-split 4; trig threads read own h spans from global; padded
// LDS A-planes; ONE barrier then barrier-free ds_read + global-B + MFMA stream.
#define FK_AST  264        // f16 per staged-A row (256 + 8 pad) = 528 B
__global__ __launch_bounds__(256) void k_fk(const float* __restrict__ h,
        const _Float16* __restrict__ whi, const _Float16* __restrict__ wlo,
        float* __restrict__ p0, float* __restrict__ p1,
        float* __restrict__ p2, float* __restrict__ p3, int N) {
    __shared__ _Float16 ahi[32 * FK_AST];
    __shared__ _Float16 alo[32 * FK_AST];
    int tid = threadIdx.x;
    int bx = blockIdx.x;
    int nb = (bx >> 2) * 32;
    int ks = bx & 3;
    int kbase = ks * 256;
    int fr0 = kbase >> 7;
    {
        int row = tid >> 3;
        int o8 = tid & 7;
        int gn = nb + row;
        int rc = (gn < N) ? gn : (N - 1);
        const float* hp = h + (size_t)rc * HID + o8 * 8;
        float hv[2][8];
        *(float4*)&hv[0][0] = *(const float4*)hp;
        *(float4*)&hv[0][4] = *(const float4*)(hp + 4);
        *(float4*)&hv[1][0] = *(const float4*)(hp + 64);
        *(float4*)&hv[1][4] = *(const float4*)(hp + 68);
#pragma unroll
        for (int g = 0; g < 2; ++g) {
            float freqf = 6.2831853f * (float)(fr0 + g + 1);
#pragma unroll
            for (int s = 0; s < 2; ++s) {
                half8 vh, vl;
#pragma unroll
                for (int j = 0; j < 8; ++j) {
                    float ang = freqf * hv[s][j] + 0.78539816f;
                    float a = 1.41421356f * __sinf(ang);
                    _Float16 hi = (_Float16)a;
                    vh[j] = hi;
                    vl[j] = (_Float16)((a - (float)hi) * 2048.f);
                }
                int oct = g * 16 + s * 8 + o8;
                *(half8*)&ahi[row * FK_AST + oct * 8] = vh;
                *(half8*)&alo[row * FK_AST + oct * 8] = vl;
            }
        }
    }
    __syncthreads();
    int lane = tid & 63, wv = tid >> 6;
    int quad = lane >> 4, l16 = lane & 15;
    int n0w = wv * 32;
    f4 acc0[2][2], accL[2][2];
#pragma unroll
    for (int mi = 0; mi < 2; ++mi)
#pragma unroll
        for (int ni = 0; ni < 2; ++ni) { acc0[mi][ni] = (f4)(0.f); accL[mi][ni] = (f4)(0.f); }
    const _Float16* bhp0 = whi + (size_t)(n0w + l16) * 1024 + kbase + quad * 8;
    const _Float16* bhp1 = whi + (size_t)(n0w + 16 + l16) * 1024 + kbase + quad * 8;
    const _Float16* blp0 = wlo + (size_t)(n0w + l16) * 1024 + kbase + quad * 8;
    const _Float16* blp1 = wlo + (size_t)(n0w + 16 + l16) * 1024 + kbase + quad * 8;
#pragma unroll 2
    for (int step = 0; step < 8; ++step) {
        int ka = step * 32 + quad * 8;
        half8 ah0 = *(const half8*)&ahi[l16 * FK_AST + ka];
        half8 ah1 = *(const half8*)&ahi[(l16 + 16) * FK_AST + ka];
        half8 al0 = *(const half8*)&alo[l16 * FK_AST + ka];
        half8 al1 = *(const half8*)&alo[(l16 + 16) * FK_AST + ka];
        int ko = step * 32;
        half8 bh0 = *(const half8*)(bhp0 + ko);
        half8 bh1 = *(const half8*)(bhp1 + ko);
        half8 bl0 = *(const half8*)(blp0 + ko);
        half8 bl1 = *(const half8*)(blp1 + ko);
        acc0[0][0] = __builtin_amdgcn_mfma_f32_16x16x32_f16(ah0, bh0, acc0[0][0], 0, 0, 0);
        acc0[0][1] = __builtin_amdgcn_mfma_f32_16x16x32_f16(ah0, bh1, acc0[0][1], 0, 0, 0);
        acc0[1][0] = __builtin_amdgcn_mfma_f32_16x16x32_f16(ah1, bh0, acc0[1][0], 0, 0, 0);
        acc0[1][1] = __builtin_amdgcn_mfma_f32_16x16x32_f16(ah1, bh1, acc0[1][1], 0, 0, 0);
        accL[0][0] = __builtin_amdgcn_mfma_f32_16x16x32_f16(ah0, bl0, accL[0][0], 0, 0, 0);
        accL[0][1] = __builtin_amdgcn_mfma_f32_16x16x32_f16(ah0, bl1, accL[0][1], 0, 0, 0);
        accL[1][0] = __builtin_amdgcn_mfma_f32_16x16x32_f16(ah1, bl0, accL[1][0], 0, 0, 0);
        accL[1][1] = __builtin_amdgcn_mfma_f32_16x16x32_f16(ah1, bl1, accL[1][1], 0, 0, 0);
        accL[0][0] = __builtin_amdgcn_mfma_f32_16x16x32_f16(al0, bh0, accL[0][0], 0, 0, 0);
        accL[0][1] = __builtin_amdgcn_mfma_f32_16x16x32_f16(al0, bh1, accL[0][1], 0, 0, 0);
        accL[1][0] = __builtin_amdgcn_mfma_f32_16x16x32_f16(al1, bh0, accL[1][0], 0, 0, 0);
        accL[1][1] = __builtin_amdgcn_mfma_f32_16x16x32_f16(al1, bh1, accL[1][1], 0, 0, 0);
    }
    float* p = (ks == 0) ? p0 : (ks == 1) ? p1 : (ks == 2) ? p2 : p3;
    const float inv = 1.0f / 2048.0f;
#pragma unroll
    for (int mi = 0; mi < 2; ++mi)
#pragma unroll
        for (int ni = 0; ni < 2; ++ni)
#pragma unroll
            for (int r = 0; r < 4; ++r) {
                int gn = nb + mi * 16 + quad * 4 + r;
                if (gn < N)
                    p[gn * HID + n0w + ni * 16 + l16] = acc0[mi][ni][r] + accL[mi][ni][r] * inv;
            }
}

// ---------------------------------------------------------------- batchnorm stats (5 streams)
__global__ void k_bn_stats(float* __restrict__ hconv,
                           const float* __restrict__ p0, const float* __restrict__ p1,
                           const float* __restrict__ p2, const float* __restrict__ p3,
                           const float* __restrict__ fkb,
                           double* __restrict__ stats, int N) {
    int c = threadIdx.x & 127, half = threadIdx.x >> 7;
    float bias = fkb[c];
    float s = 0.f, s2 = 0.f;
    for (int n = blockIdx.x * 2 + half; n < N; n += gridDim.x * 2) {
        int idx = n * HID + c;
        float v = hconv[idx] + p0[idx] + p1[idx] + p2[idx] + p3[idx] + bias;
        hconv[idx] = v;
        s += v; s2 += v * v;
    }
    __shared__ float sh[256], sh2[256];
    sh[threadIdx.x] = s; sh2[threadIdx.x] = s2;
    __syncthreads();
    if (half == 0) {
        s = sh[c] + sh[128 + c];
        s2 = sh2[c] + sh2[128 + c];
        atomicAdd(&stats[c], (double)s);
        atomicAdd(&stats[128 + c], (double)s2);
    }
}

// bn_final folded in; optionally computes pool scores (last layer)
__global__ void k_bn_apply(const float* __restrict__ hsum, const double* __restrict__ stats,
                           const float* __restrict__ g, const float* __restrict__ b,
                           const float* __restrict__ pw, const float* __restrict__ pb,
                           float* __restrict__ h, float* __restrict__ s,
                           int do_score, int N) {
    __shared__ float red[4];
    int idx = blockIdx.x * 256 + threadIdx.x;
    int valid = idx < N * HID;
    int c = idx & 127;
    double invN = 1.0 / (double)N;
    float mu = (float)(stats[c] * invN);
    float var = (float)(stats[128 + c] * invN) - mu * mu;
    float inv = 1.f / sqrtf(var + 1e-5f);
    float sc = g[c] * inv;
    float sh = b[c] - mu * sc;
    float o = 0.f;
    if (valid) {
        o = fmaxf(hsum[idx] * sc + sh, 0.f);
        h[idx] = o;
    }
    if (do_score) {
        float p = valid ? o * pw[c] : 0.f;
        for (int off = 32; off > 0; off >>= 1) p += __shfl_down(p, off);
        int wid = threadIdx.x >> 6;
        if ((threadIdx.x & 63) == 0) red[wid] = p;
        __syncthreads();
        int row = idx >> 7;
        int half = threadIdx.x >> 7;
        if ((threadIdx.x & 127) == 0 && row < N)
            s[row] = red[half * 2] + red[half * 2 + 1] + pb[0];
    }
}

// ---------------------------------------------------------------- softmax partials
__global__ void k_smax1(const float* __restrict__ s, float* __restrict__ mzp, int N) {
    __shared__ float red[256];
    float m = -INFINITY;
    for (int n = blockIdx.x * 256 + threadIdx.x; n < N; n += SMAXB * 256)
        m = fmaxf(m, s[n]);
    red[threadIdx.x] = m;
    __syncthreads();
    for (int off = 128; off > 0; off >>= 1) {
        if (threadIdx.x < (unsigned)off)
            red[threadIdx.x] = fmaxf(red[threadIdx.x], red[threadIdx.x + off]);
        __syncthreads();
    }
    m = red[0];
    __syncthreads();
    float z = 0.f;
    for (int n = blockIdx.x * 256 + threadIdx.x; n < N; n += SMAXB * 256)
        z += __expf(s[n] - m);
    red[threadIdx.x] = z;
    __syncthreads();
    for (int off = 128; off > 0; off >>= 1) {
        if (threadIdx.x < (unsigned)off) red[threadIdx.x] += red[threadIdx.x + off];
        __syncthreads();
    }
    if (threadIdx.x == 0) { mzp[blockIdx.x * 2] = m; mzp[blockIdx.x * 2 + 1] = red[0]; }
}

__device__ __forceinline__ void combine_mz(const float* mzp, float& m, float& Z) {
    m = -INFINITY;
#pragma unroll 8
    for (int i = 0; i < SMAXB; ++i) m = fmaxf(m, mzp[i * 2]);
    Z = 0.f;
#pragma unroll 8
    for (int i = 0; i < SMAXB; ++i) Z += mzp[i * 2 + 1] * __expf(mzp[i * 2] - m);
}

// ---------------------------------------------------------------- attention pool (split)
__global__ void k_pool_part(const float* __restrict__ h, const float* __restrict__ s,
                            const float* __restrict__ mzp, const int* __restrict__ boffs,
                            float* __restrict__ part) {
    int b = blockIdx.x >> 4, split = blockIdx.x & (PSPLIT - 1);
    int c = threadIdx.x & 127, half = threadIdx.x >> 7;
    float m, Z;
    combine_mz(mzp, m, Z);
    (void)Z;
    int n0 = boffs[b], n1 = boffs[b + 1];
    float acc = 0.f;
    for (int n = n0 + split * 2 + half; n < n1; n += PSPLIT * 2)
        acc += __expf(s[n] - m) * h[n * HID + c];
    __shared__ float prt[2][HID];
    prt[half][c] = acc;
    __syncthreads();
    if (half == 0) part[(size_t)(b * PSPLIT + split) * HID + c] = prt[0][c] + prt[1][c];
}

__global__ void k_pool_sum(const float* __restrict__ part, const float* __restrict__ mzp,
                           float* __restrict__ pooled) {
    int b = blockIdx.x, c = threadIdx.x;
    float m, Z;
    combine_mz(mzp, m, Z);
    float acc = 0.f;
#pragma unroll
    for (int i = 0; i < PSPLIT; ++i) acc += part[(size_t)(b * PSPLIT + i) * HID + c];
    pooled[b * HID + c] = acc / Z;
}

// ---------------------------------------------------------------- heads (grid = B*4)
__global__ __launch_bounds__(256) void k_head(const float* __restrict__ pooled,
                       const float* __restrict__ sg_table,
                       const int* __restrict__ space_group,
                       const float* __restrict__ hw1, const float* __restrict__ hb1,
                       const float* __restrict__ ew2, const float* __restrict__ eb2,
                       const float* __restrict__ sw2, const float* __restrict__ sb2,
                       const float* __restrict__ cw2, const float* __restrict__ cb2,
                       const float* __restrict__ mw2, const float* __restrict__ mb2,
                       float* __restrict__ out, int B) {
    __shared__ float comb[256];
    __shared__ float zred[2][128];
    __shared__ float zsh[128];
    int b = blockIdx.x >> 2, i = blockIdx.x & 3;
    int t = threadIdx.x;
    comb[t] = (t < 128) ? pooled[b * HID + t] : sg_table[space_group[b] * HID + (t - 128)];
    __syncthreads();
    int half = t >> 7, tt = t & 127;
    const float* W = hw1 + ((size_t)i * 256 + half * 128) * HID;
    const float* cb = &comb[half * 128];
    float z = 0.f;
#pragma unroll 8
    for (int k = 0; k < 128; ++k) z += cb[k] * W[k * HID + tt];
    zred[half][tt] = z;
    __syncthreads();
    if (t < 128) zsh[t] = fmaxf(zred[0][t] + zred[1][t] + hb1[i * HID + t], 0.f);
    __syncthreads();
    const int od[4] = {1, 3, 7, 3};
    const int base[4] = {0, 64, 256, 704};
    const float* w2 = (i == 0) ? ew2 : (i == 1) ? sw2 : (i == 2) ? cw2 : mw2;
    const float* b2 = (i == 0) ? eb2 : (i == 1) ? sb2 : (i == 2) ? cb2 : mb2;
    int odi = od[i];
    if (t < odi) {
        float o = b2[t];
        for (int c = 0; c < HID; ++c) o += zsh[c] * w2[c * odi + t];
        out[base[i] + b * odi + t] = o;
    }
}

// ---------------------------------------------------------------- launch
extern "C" void kernel_launch(void* const* d_in, const int* in_sizes, int n_in,
                              void* d_out, int out_size, void* d_ws, size_t ws_size,
                              hipStream_t stream) {
    const float* x          = (const float*)d_in[0];
    const int*   edge_index = (const int*)d_in[1];
    const float* edge_attr  = (const float*)d_in[2];
    const int*   batch      = (const int*)d_in[3];
    const int*   space_group= (const int*)d_in[4];
    const float* node_w     = (const float*)d_in[5];
    const float* node_b     = (const float*)d_in[6];
    const float* sg_table   = (const float*)d_in[7];
    const float* lin_w      = (const float*)d_in[8];
    const float* lin_b      = (const float*)d_in[9];
    const float* att_w      = (const float*)d_in[10];
    const float* att_b      = (const float*)d_in[11];
    const float* fk_w       = (const float*)d_in[12];
    const float* fk_b       = (const float*)d_in[13];
    const float* bn_g       = (const float*)d_in[14];
    const float* bn_b       = (const float*)d_in[15];
    const float* pool_w     = (const float*)d_in[16];
    const float* pool_b     = (const float*)d_in[17];
    const float* head_w1    = (const float*)d_in[18];
    const float* head_b1    = (const float*)d_in[19];
    const float* ew2 = (const float*)d_in[20]; const float* eb2 = (const float*)d_in[21];
    const float* sw2 = (const float*)d_in[22]; const float* sb2 = (const float*)d_in[23];
    const float* cw2 = (const float*)d_in[24]; const float* cb2 = (const float*)d_in[25];
    const float* mw2 = (const float*)d_in[26]; const float* mb2 = (const float*)d_in[27];
    float* out = (float*)d_out;

    const int N = in_sizes[3];
    const int E = in_sizes[1] / 2;
    const int B = in_sizes[4];
    const int* src = edge_index;
    const int* dst = edge_index + E;

    char* w = (char*)d_ws;
    auto alloc = [&](size_t bytes) { char* p = w; w += (bytes + 255) & ~(size_t)255; return p; };
    float*  h      = (float*)alloc((size_t)N * HID * 4);
    float*  A1     = (float*)alloc((size_t)N * HID * 4);  // reused as FK partial 0
    float*  A2     = (float*)alloc((size_t)N * HID * 4);  // reused as FK partial 1
    float*  p2     = (float*)alloc((size_t)N * HID * 4);  // FK partial 2
    float*  p3     = (float*)alloc((size_t)N * HID * 4);  // FK partial 3
    float*  hconv  = (float*)alloc((size_t)N * HID * 4);  // becomes pre-BN sum in place
    float*  a1     = (float*)alloc((size_t)N * 4);
    float*  a2     = (float*)alloc((size_t)N * 4);
    float*  sbuf   = (float*)alloc((size_t)N * 4);
    int*    deg    = (int*)alloc((size_t)N * 4);
    int*    cursor = (int*)alloc((size_t)N * 4);
    int*    offs   = (int*)alloc((size_t)(N + 1) * 4);
    int*    srco   = (int*)alloc((size_t)E * 4);
    float4* ea3o   = (float4*)alloc((size_t)E * 16);
    _Float16* whi  = (_Float16*)alloc((size_t)DEPTH * 1024 * HID * 2);
    _Float16* wlo  = (_Float16*)alloc((size_t)DEPTH * 1024 * HID * 2);
    int*    bsum   = (int*)alloc(256 * 4);
    int*    boffs  = (int*)alloc((size_t)(B + 1) * 4);
    double* stats  = (double*)alloc(256 * 8);
    float*  mzp    = (float*)alloc(SMAXB * 2 * 4);
    float*  part   = (float*)alloc((size_t)B * PSPLIT * HID * 4);
    float*  pooled = (float*)alloc((size_t)B * HID * 4);

    const int nchunk = (N + 255) / 256;
    const int echunk = (E + 255) / 256;

    // one-time per launch: W split + CSR build
    k_wsplit<<<128, 256, 0, stream>>>(fk_w, whi, wlo);
    hipMemsetAsync(deg, 0, (size_t)N * 4, stream);
    k_hist<<<echunk, 256, 0, stream>>>(dst, deg, E);
    k_scan_a<<<nchunk, 256, 0, stream>>>(deg, bsum, N);
    k_scan_b<<<1, 256, 0, stream>>>(bsum, nchunk);
    k_scan_c<<<nchunk, 256, 0, stream>>>(deg, bsum, offs, cursor, N);
    k_scatter<<<echunk, 256, 0, stream>>>(src, dst, edge_attr, cursor, srco, ea3o, E);
    k_bstart<<<nchunk, 256, 0, stream>>>(batch, boffs, N, B);

    k_node_embed<<<(N * HID + 255) / 256, 256, 0, stream>>>(x, node_w, node_b, h, N);

    for (int l = 0; l < DEPTH; ++l) {
        const float* linw_l = lin_w + (size_t)l * 259 * HID;
        k_node_lin<<<(N + 7) / 8, 256, 0, stream>>>(
            h, linw_l, lin_b + l * HID, att_w + (size_t)l * 259, att_b + l,
            A1, A2, a1, a2, N);
        k_edge<<<N, 256, 0, stream>>>(A1, A2, a1, a2, srco, ea3o, offs,
                                      linw_l + 256 * HID, att_w + (size_t)l * 259 + 256,
                                      hconv, stats, N);
        k_fk<<<((N + 31) / 32) * 4, 256, 0, stream>>>(
            h, whi + (size_t)l * 131072, wlo + (size_t)l * 131072, A1, A2, p2, p3, N);
        k_bn_stats<<<320, 256, 0, stream>>>(hconv, A1, A2, p2, p3, fk_b + l * HID, stats, N);
        k_bn_apply<<<(N * HID + 255) / 256, 256, 0, stream>>>(
            hconv, stats, bn_g + l * HID, bn_b + l * HID, pool_w, pool_b,
            h, sbuf, (l == DEPTH - 1) ? 1 : 0, N);
    }

    k_smax1<<<SMAXB, 256, 0, stream>>>(sbuf, mzp, N);
    k_pool_part<<<B * PSPLIT, 256, 0, stream>>>(h, sbuf, mzp, boffs, part);
    k_pool_sum<<<B, 128, 0, stream>>>(part, mzp, pooled);
    k_head<<<B * 4, 256, 0, stream>>>(pooled, sg_table, space_group, head_w1, head_b1,
                                      ew2, eb2, sw2, sb2, cw2, cb2, mw2, mb2, out, B);
}

// Round 17
// 744.267 us; speedup vs baseline: 1.3439x; 1.0281x over previous
//
#include <hip/hip_runtime.h>
#include <math.h>

#define HID 128
#define DEPTH 4
#define PSPLIT 16
#define SMAXB 40

typedef _Float16 half8 __attribute__((ext_vector_type(8)));
typedef float f4 __attribute__((ext_vector_type(4)));

// ---------------------------------------------------------------- node embed
__global__ void k_node_embed(const float* __restrict__ x, const float* __restrict__ nw,
                             const float* __restrict__ nb, float* __restrict__ h, int N) {
    int idx = blockIdx.x * blockDim.x + threadIdx.x;
    if (idx >= N * HID) return;
    int n = idx >> 7, c = idx & 127;
    float acc = nb[c];
#pragma unroll
    for (int d = 0; d < 4; ++d) acc += x[n * 4 + d] * nw[d * HID + c];
    h[idx] = acc;
}

// ---------------------------------------------------------------- W split+transpose (once per launch)
__global__ void k_wsplit(const float* __restrict__ fkw, _Float16* __restrict__ whi,
                         _Float16* __restrict__ wlo) {
    __shared__ float sh[64][65];
    int bid = blockIdx.x;           // 4 layers * 16 kblk * 2 nblk = 128 blocks
    int l = bid >> 5; int r = bid & 31; int kb = r >> 1; int nbk = r & 1;
    const float* W = fkw + (size_t)l * 131072;
    _Float16* Hl = whi + (size_t)l * 131072;
    _Float16* Ll = wlo + (size_t)l * 131072;
    int k0 = kb * 64, n0 = nbk * 64;
    for (int i = threadIdx.x; i < 4096; i += 256) {
        int kk = i >> 6, nn = i & 63;
        sh[kk][nn] = W[(k0 + kk) * HID + n0 + nn];
    }
    __syncthreads();
    for (int i = threadIdx.x; i < 4096; i += 256) {
        int nn = i >> 6, kk = i & 63;
        float w = sh[kk][nn];
        _Float16 hi = (_Float16)w;
        _Float16 lo = (_Float16)((w - (float)hi) * 2048.f);
        Hl[(n0 + nn) * 1024 + k0 + kk] = hi;
        Ll[(n0 + nn) * 1024 + k0 + kk] = lo;
    }
}

// ---------------------------------------------------------------- CSR build
__global__ void k_hist(const int* __restrict__ dst, int* __restrict__ deg, int E) {
    int e = blockIdx.x * 256 + threadIdx.x;
    if (e < E) atomicAdd(&deg[dst[e]], 1);
}

__global__ void k_scan_a(const int* __restrict__ deg, int* __restrict__ bsum, int N) {
    __shared__ int sh[256];
    int i = blockIdx.x * 256 + threadIdx.x;
    sh[threadIdx.x] = (i < N) ? deg[i] : 0;
    __syncthreads();
    for (int off = 128; off > 0; off >>= 1) {
        if (threadIdx.x < (unsigned)off) sh[threadIdx.x] += sh[threadIdx.x + off];
        __syncthreads();
    }
    if (threadIdx.x == 0) bsum[blockIdx.x] = sh[0];
}

__global__ void k_scan_b(int* __restrict__ bsum, int nb) {
    __shared__ int sh[256];
    int v = (threadIdx.x < (unsigned)nb) ? bsum[threadIdx.x] : 0;
    sh[threadIdx.x] = v;
    __syncthreads();
    for (int off = 1; off < 256; off <<= 1) {
        int add = (threadIdx.x >= (unsigned)off) ? sh[threadIdx.x - off] : 0;
        __syncthreads();
        sh[threadIdx.x] += add;
        __syncthreads();
    }
    if (threadIdx.x < (unsigned)nb) bsum[threadIdx.x] = sh[threadIdx.x] - v;
}

__global__ void k_scan_c(const int* __restrict__ deg, const int* __restrict__ bsum,
                         int* __restrict__ offs, int* __restrict__ cursor, int N) {
    __shared__ int sh[256];
    int i = blockIdx.x * 256 + threadIdx.x;
    int v = (i < N) ? deg[i] : 0;
    sh[threadIdx.x] = v;
    __syncthreads();
    for (int off = 1; off < 256; off <<= 1) {
        int add = (threadIdx.x >= (unsigned)off) ? sh[threadIdx.x - off] : 0;
        __syncthreads();
        sh[threadIdx.x] += add;
        __syncthreads();
    }
    int ex = bsum[blockIdx.x] + sh[threadIdx.x] - v;
    if (i < N) { offs[i] = ex; cursor[i] = ex; }
    if (i == N - 1) offs[N] = ex + v;
}

// scatter edges into CSR order; writes srco AND edge_attr (float4) directly
__global__ void k_scatter(const int* __restrict__ src, const int* __restrict__ dst,
                          const float* __restrict__ ea, int* cursor,
                          int* __restrict__ srco, float4* __restrict__ ea3o, int E) {
    int e = blockIdx.x * 256 + threadIdx.x;
    if (e < E) {
        int d = dst[e];
        int p = atomicAdd(&cursor[d], 1);
        srco[p] = src[e];
        float4 q;
        q.x = ea[e * 3 + 0]; q.y = ea[e * 3 + 1]; q.z = ea[e * 3 + 2]; q.w = 0.f;
        ea3o[p] = q;
    }
}

__global__ void k_bstart(const int* __restrict__ batch, int* __restrict__ boffs, int N, int B) {
    int n = blockIdx.x * 256 + threadIdx.x;
    if (n >= N) return;
    int b1 = batch[n];
    if (n == 0) for (int b = 0; b <= b1; ++b) boffs[b] = 0;
    int b2 = (n + 1 < N) ? batch[n + 1] : B;
    for (int b = b1 + 1; b <= b2; ++b) boffs[b] = n + 1;
}

// ---------------------------------------------------------------- per-node linear + attention dots (fused, fp32)
__global__ __launch_bounds__(256) void k_node_lin(const float* __restrict__ h,
                           const float* __restrict__ linw, const float* __restrict__ linb,
                           const float* __restrict__ attw, const float* __restrict__ attb,
                           float* __restrict__ A1, float* __restrict__ A2,
                           float* __restrict__ a1, float* __restrict__ a2, int N) {
    __shared__ float hT[HID][12];
    int nb = blockIdx.x * 8;
    int tid = threadIdx.x;
    for (int i = tid; i < 8 * HID; i += 256) {
        int n = i >> 7, c = i & 127;
        int gn = nb + n;
        hT[c][n] = (gn < N) ? h[gn * HID + c] : 0.f;
    }
    __syncthreads();
    {
        int node = tid >> 5, lane32 = tid & 31;
        float p1 = 0.f, p2 = 0.f;
#pragma unroll
        for (int j = 0; j < 4; ++j) {
            int k = lane32 * 4 + j;
            float hv = hT[k][node];
            p1 += hv * attw[k];
            p2 += hv * attw[128 + k];
        }
        for (int off = 16; off > 0; off >>= 1) {
            p1 += __shfl_down(p1, off, 32);
            p2 += __shfl_down(p2, off, 32);
        }
        int gn = nb + node;
        if (lane32 == 0 && gn < N) {
            a1[gn] = p1 + attb[0];
            a2[gn] = p2;
        }
    }
    int c = tid & 127, r = tid >> 7;
    const float* Wd = linw;
    const float* Ws = linw + 128 * HID;
    float acc1[4] = {0, 0, 0, 0}, acc2[4] = {0, 0, 0, 0};
#pragma unroll 4
    for (int k = 0; k < HID; ++k) {
        float wd = Wd[k * HID + c];
        float ws = Ws[k * HID + c];
        float4 hv = *(const float4*)&hT[k][r * 4];
        acc1[0] += hv.x * wd; acc2[0] += hv.x * ws;
        acc1[1] += hv.y * wd; acc2[1] += hv.y * ws;
        acc1[2] += hv.z * wd; acc2[2] += hv.z * ws;
        acc1[3] += hv.w * wd; acc2[3] += hv.w * ws;
    }
#pragma unroll
    for (int j = 0; j < 4; ++j) {
        int gn = nb + r * 4 + j;
        if (gn < N) {
            A1[gn * HID + c] = acc1[j] + linb[c];
            A2[gn * HID + c] = acc2[j];
        }
    }
}

// ---------------------------------------------------------------- edge conv (CSR, 8 slots, float4, alpha fused)
// direct weight loads (no LDS staging barrier), single-barrier reduction,
// padded partials; also zeroes the bn stats buffer (block 0)
__global__ __launch_bounds__(256) void k_edge(const float* __restrict__ A1,
        const float* __restrict__ A2, const float* __restrict__ a1,
        const float* __restrict__ a2, const int* __restrict__ srco,
        const float4* __restrict__ ea3o, const int* __restrict__ offs,
        const float* __restrict__ linw3, const float* __restrict__ attw3,
        float* __restrict__ hconv, double* __restrict__ stats, int N) {
    __shared__ float part[8][HID + 4];
    int n = blockIdx.x;
    int tid = threadIdx.x;
    if (n == 0) stats[tid] = 0.0;
    int lane32 = tid & 31, slot = tid >> 5;
    int c4 = lane32 * 4;
    float4 w0v = *(const float4*)&linw3[c4];
    float4 w1v = *(const float4*)&linw3[HID + c4];
    float4 w2v = *(const float4*)&linw3[2 * HID + c4];
    float aw0 = attw3[0], aw1 = attw3[1], aw2 = attw3[2];
    float a1n = a1[n];
    float4 A1v = *(const float4*)&A1[(size_t)n * HID + c4];
    float4 acc; acc.x = acc.y = acc.z = acc.w = 0.f;
    int s0 = offs[n], s1 = offs[n + 1];
    for (int idx = s0 + slot; idx < s1; idx += 8) {
        int s = srco[idx];
        float4 q = ea3o[idx];
        float logit = a1n + a2[s] + q.x * aw0 + q.y * aw1 + q.z * aw2;
        float al = 1.f / (1.f + __expf(-logit));
        float4 a2v = *(const float4*)&A2[(size_t)s * HID + c4];
        float4 pre;
        pre.x = A1v.x + a2v.x + q.x * w0v.x + q.y * w1v.x + q.z * w2v.x;
        pre.y = A1v.y + a2v.y + q.x * w0v.y + q.y * w1v.y + q.z * w2v.y;
        pre.z = A1v.z + a2v.z + q.x * w0v.z + q.y * w1v.z + q.z * w2v.z;
        pre.w = A1v.w + a2v.w + q.x * w0v.w + q.y * w1v.w + q.z * w2v.w;
        acc.x += al * pre.x; acc.y += al * pre.y;
        acc.z += al * pre.z; acc.w += al * pre.w;
    }
    *(float4*)&part[slot][c4] = acc;
    __syncthreads();
    if (slot == 0) {
        float4 p = *(const float4*)&part[0][c4];
#pragma unroll
        for (int s = 1; s < 8; ++s) {
            float4 r = *(const float4*)&part[s][c4];
            p.x += r.x; p.y += r.y; p.z += r.z; p.w += r.w;
        }
        *(float4*)&hconv[(size_t)n * HID + c4] = p;
    }
}

// ---------------------------------------------------------------- Fourier-Kolmogorov GEMM (split-f16 MFMA)
// R11 structure: K-split 4; trig threads read own h spans from global; padded
// LDS A-planes; ONE barrier then barrier-free ds_read + global-B + MFMA stream.
#define FK_AST  264        // f16 per staged-A row (256 + 8 pad) = 528 B
__global__ __launch_bounds__(256) void k_fk(const float* __restrict__ h,
        const _Float16* __restrict__ whi, const _Float16* __restrict__ wlo,
        float* __restrict__ p0, float* __restrict__ p1,
        float* __restrict__ p2, float* __restrict__ p3, int N) {
    __shared__ _Float16 ahi[32 * FK_AST];
    __shared__ _Float16 alo[32 * FK_AST];
    int tid = threadIdx.x;
    int bx = blockIdx.x;
    int nb = (bx >> 2) * 32;
    int ks = bx & 3;
    int kbase = ks * 256;
    int fr0 = kbase >> 7;
    {
        int row = tid >> 3;
        int o8 = tid & 7;
        int gn = nb + row;
        int rc = (gn < N) ? gn : (N - 1);
        const float* hp = h + (size_t)rc * HID + o8 * 8;
        float hv[2][8];
        *(float4*)&hv[0][0] = *(const float4*)hp;
        *(float4*)&hv[0][4] = *(const float4*)(hp + 4);
        *(float4*)&hv[1][0] = *(const float4*)(hp + 64);
        *(float4*)&hv[1][4] = *(const float4*)(hp + 68);
#pragma unroll
        for (int g = 0; g < 2; ++g) {
            float freqf = 6.2831853f * (float)(fr0 + g + 1);
#pragma unroll
            for (int s = 0; s < 2; ++s) {
                half8 vh, vl;
#pragma unroll
                for (int j = 0; j < 8; ++j) {
                    float ang = freqf * hv[s][j] + 0.78539816f;
                    float a = 1.41421356f * __sinf(ang);
                    _Float16 hi = (_Float16)a;
                    vh[j] = hi;
                    vl[j] = (_Float16)((a - (float)hi) * 2048.f);
                }
                int oct = g * 16 + s * 8 + o8;
                *(half8*)&ahi[row * FK_AST + oct * 8] = vh;
                *(half8*)&alo[row * FK_AST + oct * 8] = vl;
            }
        }
    }
    __syncthreads();
    int lane = tid & 63, wv = tid >> 6;
    int quad = lane >> 4, l16 = lane & 15;
    int n0w = wv * 32;
    f4 acc0[2][2], accL[2][2];
#pragma unroll
    for (int mi = 0; mi < 2; ++mi)
#pragma unroll
        for (int ni = 0; ni < 2; ++ni) { acc0[mi][ni] = (f4)(0.f); accL[mi][ni] = (f4)(0.f); }
    const _Float16* bhp0 = whi + (size_t)(n0w + l16) * 1024 + kbase + quad * 8;
    const _Float16* bhp1 = whi + (size_t)(n0w + 16 + l16) * 1024 + kbase + quad * 8;
    const _Float16* blp0 = wlo + (size_t)(n0w + l16) * 1024 + kbase + quad * 8;
    const _Float16* blp1 = wlo + (size_t)(n0w + 16 + l16) * 1024 + kbase + quad * 8;
#pragma unroll 2
    for (int step = 0; step < 8; ++step) {
        int ka = step * 32 + quad * 8;
        half8 ah0 = *(const half8*)&ahi[l16 * FK_AST + ka];
        half8 ah1 = *(const half8*)&ahi[(l16 + 16) * FK_AST + ka];
        half8 al0 = *(const half8*)&alo[l16 * FK_AST + ka];
        half8 al1 = *(const half8*)&alo[(l16 + 16) * FK_AST + ka];
        int ko = step * 32;
        half8 bh0 = *(const half8*)(bhp0 + ko);
        half8 bh1 = *(const half8*)(bhp1 + ko);
        half8 bl0 = *(const half8*)(blp0 + ko);
        half8 bl1 = *(const half8*)(blp1 + ko);
        acc0[0][0] = __builtin_amdgcn_mfma_f32_16x16x32_f16(ah0, bh0, acc0[0][0], 0, 0, 0);
        acc0[0][1] = __builtin_amdgcn_mfma_f32_16x16x32_f16(ah0, bh1, acc0[0][1], 0, 0, 0);
        acc0[1][0] = __builtin_amdgcn_mfma_f32_16x16x32_f16(ah1, bh0, acc0[1][0], 0, 0, 0);
        acc0[1][1] = __builtin_amdgcn_mfma_f32_16x16x32_f16(ah1, bh1, acc0[1][1], 0, 0, 0);
        accL[0][0] = __builtin_amdgcn_mfma_f32_16x16x32_f16(ah0, bl0, accL[0][0], 0, 0, 0);
        accL[0][1] = __builtin_amdgcn_mfma_f32_16x16x32_f16(ah0, bl1, accL[0][1], 0, 0, 0);
        accL[1][0] = __builtin_amdgcn_mfma_f32_16x16x32_f16(ah1, bl0, accL[1][0], 0, 0, 0);
        accL[1][1] = __builtin_amdgcn_mfma_f32_16x16x32_f16(ah1, bl1, accL[1][1], 0, 0, 0);
        accL[0][0] = __builtin_amdgcn_mfma_f32_16x16x32_f16(al0, bh0, accL[0][0], 0, 0, 0);
        accL[0][1] = __builtin_amdgcn_mfma_f32_16x16x32_f16(al0, bh1, accL[0][1], 0, 0, 0);
        accL[1][0] = __builtin_amdgcn_mfma_f32_16x16x32_f16(al1, bh0, accL[1][0], 0, 0, 0);
        accL[1][1] = __builtin_amdgcn_mfma_f32_16x16x32_f16(al1, bh1, accL[1][1], 0, 0, 0);
    }
    float* p = (ks == 0) ? p0 : (ks == 1) ? p1 : (ks == 2) ? p2 : p3;
    const float inv = 1.0f / 2048.0f;
#pragma unroll
    for (int mi = 0; mi < 2; ++mi)
#pragma unroll
        for (int ni = 0; ni < 2; ++ni)
#pragma unroll
            for (int r = 0; r < 4; ++r) {
                int gn = nb + mi * 16 + quad * 4 + r;
                if (gn < N)
                    p[gn * HID + n0w + ni * 16 + l16] = acc0[mi][ni][r] + accL[mi][ni][r] * inv;
            }
}

// ---------------------------------------------------------------- batchnorm stats (5 streams)
__global__ void k_bn_stats(float* __restrict__ hconv,
                           const float* __restrict__ p0, const float* __restrict__ p1,
                           const float* __restrict__ p2, const float* __restrict__ p3,
                           const float* __restrict__ fkb,
                           double* __restrict__ stats, int N) {
    int c = threadIdx.x & 127, half = threadIdx.x >> 7;
    float bias = fkb[c];
    float s = 0.f, s2 = 0.f;
    for (int n = blockIdx.x * 2 + half; n < N; n += gridDim.x * 2) {
        int idx = n * HID + c;
        float v = hconv[idx] + p0[idx] + p1[idx] + p2[idx] + p3[idx] + bias;
        hconv[idx] = v;
        s += v; s2 += v * v;
    }
    __shared__ float sh[256], sh2[256];
    sh[threadIdx.x] = s; sh2[threadIdx.x] = s2;
    __syncthreads();
    if (half == 0) {
        s = sh[c] + sh[128 + c];
        s2 = sh2[c] + sh2[128 + c];
        atomicAdd(&stats[c], (double)s);
        atomicAdd(&stats[128 + c], (double)s2);
    }
}

// bn_final folded in; float4 per thread; optional pool scores (last layer)
__global__ void k_bn_apply(const float* __restrict__ hsum, const double* __restrict__ stats,
                           const float* __restrict__ g, const float* __restrict__ b,
                           const float* __restrict__ pw, const float* __restrict__ pb,
                           float* __restrict__ h, float* __restrict__ s,
                           int do_score, int N) {
    int idx = blockIdx.x * 256 + threadIdx.x;   // one thread per 4 channels
    int row = idx >> 5, cq = idx & 31;
    int c4 = cq * 4;
    int valid = row < N;
    double invN = 1.0 / (double)N;
    float p = 0.f;
    if (valid) {
        float4 hv = *(const float4*)&hsum[(size_t)row * HID + c4];
        float vin[4] = {hv.x, hv.y, hv.z, hv.w};
        float4 ov;
        float* po = &ov.x;
#pragma unroll
        for (int j = 0; j < 4; ++j) {
            int c = c4 + j;
            float mu = (float)(stats[c] * invN);
            float var = (float)(stats[128 + c] * invN) - mu * mu;
            float inv = 1.f / sqrtf(var + 1e-5f);
            float sc = g[c] * inv;
            float sh = b[c] - mu * sc;
            float oo = fmaxf(vin[j] * sc + sh, 0.f);
            po[j] = oo;
            if (do_score) p += oo * pw[c];
        }
        *(float4*)&h[(size_t)row * HID + c4] = ov;
    }
    if (do_score) {
        for (int off = 16; off > 0; off >>= 1) p += __shfl_down(p, off, 32);
        if ((threadIdx.x & 31) == 0 && valid) s[row] = p + pb[0];
    }
}

// ---------------------------------------------------------------- softmax partials
__global__ void k_smax1(const float* __restrict__ s, float* __restrict__ mzp, int N) {
    __shared__ float red[256];
    float m = -INFINITY;
    for (int n = blockIdx.x * 256 + threadIdx.x; n < N; n += SMAXB * 256)
        m = fmaxf(m, s[n]);
    red[threadIdx.x] = m;
    __syncthreads();
    for (int off = 128; off > 0; off >>= 1) {
        if (threadIdx.x < (unsigned)off)
            red[threadIdx.x] = fmaxf(red[threadIdx.x], red[threadIdx.x + off]);
        __syncthreads();
    }
    m = red[0];
    __syncthreads();
    float z = 0.f;
    for (int n = blockIdx.x * 256 + threadIdx.x; n < N; n += SMAXB * 256)
        z += __expf(s[n] - m);
    red[threadIdx.x] = z;
    __syncthreads();
    for (int off = 128; off > 0; off >>= 1) {
        if (threadIdx.x < (unsigned)off) red[threadIdx.x] += red[threadIdx.x + off];
        __syncthreads();
    }
    if (threadIdx.x == 0) { mzp[blockIdx.x * 2] = m; mzp[blockIdx.x * 2 + 1] = red[0]; }
}

__device__ __forceinline__ void combine_mz(const float* mzp, float& m, float& Z) {
    m = -INFINITY;
#pragma unroll 8
    for (int i = 0; i < SMAXB; ++i) m = fmaxf(m, mzp[i * 2]);
    Z = 0.f;
#pragma unroll 8
    for (int i = 0; i < SMAXB; ++i) Z += mzp[i * 2 + 1] * __expf(mzp[i * 2] - m);
}

// ---------------------------------------------------------------- attention pool (split)
__global__ void k_pool_part(const float* __restrict__ h, const float* __restrict__ s,
                            const float* __restrict__ mzp, const int* __restrict__ boffs,
                            float* __restrict__ part) {
    int b = blockIdx.x >> 4, split = blockIdx.x & (PSPLIT - 1);
    int c = threadIdx.x & 127, half = threadIdx.x >> 7;
    float m, Z;
    combine_mz(mzp, m, Z);
    (void)Z;
    int n0 = boffs[b], n1 = boffs[b + 1];
    float acc = 0.f;
    for (int n = n0 + split * 2 + half; n < n1; n += PSPLIT * 2)
        acc += __expf(s[n] - m) * h[n * HID + c];
    __shared__ float prt[2][HID];
    prt[half][c] = acc;
    __syncthreads();
    if (half == 0) part[(size_t)(b * PSPLIT + split) * HID + c] = prt[0][c] + prt[1][c];
}

__global__ void k_pool_sum(const float* __restrict__ part, const float* __restrict__ mzp,
                           float* __restrict__ pooled) {
    int b = blockIdx.x, c = threadIdx.x;
    float m, Z;
    combine_mz(mzp, m, Z);
    float acc = 0.f;
#pragma unroll
    for (int i = 0; i < PSPLIT; ++i) acc += part[(size_t)(b * PSPLIT + i) * HID + c];
    pooled[b * HID + c] = acc / Z;
}

// ---------------------------------------------------------------- heads (grid = B*4)
__global__ __launch_bounds__(256) void k_head(const float* __restrict__ pooled,
                       const float* __restrict__ sg_table,
                       const int* __restrict__ space_group,
                       const float* __restrict__ hw1, const float* __restrict__ hb1,
                       const float* __restrict__ ew2, const float* __restrict__ eb2,
                       const float* __restrict__ sw2, const float* __restrict__ sb2,
                       const float* __restrict__ cw2, const float* __restrict__ cb2,
                       const float* __restrict__ mw2, const float* __restrict__ mb2,
                       float* __restrict__ out, int B) {
    __shared__ float comb[256];
    __shared__ float zred[2][128];
    __shared__ float zsh[128];
    int b = blockIdx.x >> 2, i = blockIdx.x & 3;
    int t = threadIdx.x;
    comb[t] = (t < 128) ? pooled[b * HID + t] : sg_table[space_group[b] * HID + (t - 128)];
    __syncthreads();
    int half = t >> 7, tt = t & 127;
    const float* W = hw1 + ((size_t)i * 256 + half * 128) * HID;
    const float* cb = &comb[half * 128];
    float z = 0.f;
#pragma unroll 8
    for (int k = 0; k < 128; ++k) z += cb[k] * W[k * HID + tt];
    zred[half][tt] = z;
    __syncthreads();
    if (t < 128) zsh[t] = fmaxf(zred[0][t] + zred[1][t] + hb1[i * HID + t], 0.f);
    __syncthreads();
    const int od[4] = {1, 3, 7, 3};
    const int base[4] = {0, 64, 256, 704};
    const float* w2 = (i == 0) ? ew2 : (i == 1) ? sw2 : (i == 2) ? cw2 : mw2;
    const float* b2 = (i == 0) ? eb2 : (i == 1) ? sb2 : (i == 2) ? cb2 : mb2;
    int odi = od[i];
    if (t < odi) {
        float o = b2[t];
        for (int c = 0; c < HID; ++c) o += zsh[c] * w2[c * odi + t];
        out[base[i] + b * odi + t] = o;
    }
}

// ---------------------------------------------------------------- launch
extern "C" void kernel_launch(void* const* d_in, const int* in_sizes, int n_in,
                              void* d_out, int out_size, void* d_ws, size_t ws_size,
                              hipStream_t stream) {
    const float* x          = (const float*)d_in[0];
    const int*   edge_index = (const int*)d_in[1];
    const float* edge_attr  = (const float*)d_in[2];
    const int*   batch      = (const int*)d_in[3];
    const int*   space_group= (const int*)d_in[4];
    const float* node_w     = (const float*)d_in[5];
    const float* node_b     = (const float*)d_in[6];
    const float* sg_table   = (const float*)d_in[7];
    const float* lin_w      = (const float*)d_in[8];
    const float* lin_b      = (const float*)d_in[9];
    const float* att_w      = (const float*)d_in[10];
    const float* att_b      = (const float*)d_in[11];
    const float* fk_w       = (const float*)d_in[12];
    const float* fk_b       = (const float*)d_in[13];
    const float* bn_g       = (const float*)d_in[14];
    const float* bn_b       = (const float*)d_in[15];
    const float* pool_w     = (const float*)d_in[16];
    const float* pool_b     = (const float*)d_in[17];
    const float* head_w1    = (const float*)d_in[18];
    const float* head_b1    = (const float*)d_in[19];
    const float* ew2 = (const float*)d_in[20]; const float* eb2 = (const float*)d_in[21];
    const float* sw2 = (const float*)d_in[22]; const float* sb2 = (const float*)d_in[23];
    const float* cw2 = (const float*)d_in[24]; const float* cb2 = (const float*)d_in[25];
    const float* mw2 = (const float*)d_in[26]; const float* mb2 = (const float*)d_in[27];
    float* out = (float*)d_out;

    const int N = in_sizes[3];
    const int E = in_sizes[1] / 2;
    const int B = in_sizes[4];
    const int* src = edge_index;
    const int* dst = edge_index + E;

    char* w = (char*)d_ws;
    auto alloc = [&](size_t bytes) { char* p = w; w += (bytes + 255) & ~(size_t)255; return p; };
    float*  h      = (float*)alloc((size_t)N * HID * 4);
    float*  A1     = (float*)alloc((size_t)N * HID * 4);  // reused as FK partial 0
    float*  A2     = (float*)alloc((size_t)N * HID * 4);  // reused as FK partial 1
    float*  p2     = (float*)alloc((size_t)N * HID * 4);  // FK partial 2
    float*  p3     = (float*)alloc((size_t)N * HID * 4);  // FK partial 3
    float*  hconv  = (float*)alloc((size_t)N * HID * 4);  // becomes pre-BN sum in place
    float*  a1     = (float*)alloc((size_t)N * 4);
    float*  a2     = (float*)alloc((size_t)N * 4);
    float*  sbuf   = (float*)alloc((size_t)N * 4);
    int*    deg    = (int*)alloc((size_t)N * 4);
    int*    cursor = (int*)alloc((size_t)N * 4);
    int*    offs   = (int*)alloc((size_t)(N + 1) * 4);
    int*    srco   = (int*)alloc((size_t)E * 4);
    float4* ea3o   = (float4*)alloc((size_t)E * 16);
    _Float16* whi  = (_Float16*)alloc((size_t)DEPTH * 1024 * HID * 2);
    _Float16* wlo  = (_Float16*)alloc((size_t)DEPTH * 1024 * HID * 2);
    int*    bsum   = (int*)alloc(256 * 4);
    int*    boffs  = (int*)alloc((size_t)(B + 1) * 4);
    double* stats  = (double*)alloc(256 * 8);
    float*  mzp    = (float*)alloc(SMAXB * 2 * 4);
    float*  part   = (float*)alloc((size_t)B * PSPLIT * HID * 4);
    float*  pooled = (float*)alloc((size_t)B * HID * 4);

    const int nchunk = (N + 255) / 256;
    const int echunk = (E + 255) / 256;

    // one-time per launch: W split + CSR build
    k_wsplit<<<128, 256, 0, stream>>>(fk_w, whi, wlo);
    hipMemsetAsync(deg, 0, (size_t)N * 4, stream);
    k_hist<<<echunk, 256, 0, stream>>>(dst, deg, E);
    k_scan_a<<<nchunk, 256, 0, stream>>>(deg, bsum, N);
    k_scan_b<<<1, 256, 0, stream>>>(bsum, nchunk);
    k_scan_c<<<nchunk, 256, 0, stream>>>(deg, bsum, offs, cursor, N);
    k_scatter<<<echunk, 256, 0, stream>>>(src, dst, edge_attr, cursor, srco, ea3o, E);
    k_bstart<<<nchunk, 256, 0, stream>>>(batch, boffs, N, B);

    k_node_embed<<<(N * HID + 255) / 256, 256, 0, stream>>>(x, node_w, node_b, h, N);

    for (int l = 0; l < DEPTH; ++l) {
        const float* linw_l = lin_w + (size_t)l * 259 * HID;
        k_node_lin<<<(N + 7) / 8, 256, 0, stream>>>(
            h, linw_l, lin_b + l * HID, att_w + (size_t)l * 259, att_b + l,
            A1, A2, a1, a2, N);
        k_edge<<<N, 256, 0, stream>>>(A1, A2, a1, a2, srco, ea3o, offs,
                                      linw_l + 256 * HID, att_w + (size_t)l * 259 + 256,
                                      hconv, stats, N);
        k_fk<<<((N + 31) / 32) * 4, 256, 0, stream>>>(
            h, whi + (size_t)l * 131072, wlo + (size_t)l * 131072, A1, A2, p2, p3, N);
        k_bn_stats<<<320, 256, 0, stream>>>(hconv, A1, A2, p2, p3, fk_b + l * HID, stats, N);
        k_bn_apply<<<(N * 32 + 255) / 256, 256, 0, stream>>>(
            hconv, stats, bn_g + l * HID, bn_b + l * HID, pool_w, pool_b,
            h, sbuf, (l == DEPTH - 1) ? 1 : 0, N);
    }

    k_smax1<<<SMAXB, 256, 0, stream>>>(sbuf, mzp, N);
    k_pool_part<<<B * PSPLIT, 256, 0, stream>>>(h, sbuf, mzp, boffs, part);
    k_pool_sum<<<B, 128, 0, stream>>>(part, mzp, pooled);
    k_head<<<B * 4, 256, 0, stream>>>(pooled, sg_table, space_group, head_w1, head_b1,
                                      ew2, eb2, sw2, sb2, cw2, cb2, mw2, mb2, out, B);
}

// Round 18
// 729.273 us; speedup vs baseline: 1.3715x; 1.0206x over previous
//
#include <hip/hip_runtime.h>
#include <math.h>

#define HID 128
#define DEPTH 4
#define PSPLIT 16
#define SMAXB 40

typedef _Float16 half8 __attribute__((ext_vector_type(8)));
typedef float f4 __attribute__((ext_vector_type(4)));

// ---------------------------------------------------------------- node embed
__global__ void k_node_embed(const float* __restrict__ x, const float* __restrict__ nw,
                             const float* __restrict__ nb, float* __restrict__ h, int N) {
    int idx = blockIdx.x * blockDim.x + threadIdx.x;
    if (idx >= N * HID) return;
    int n = idx >> 7, c = idx & 127;
    float acc = nb[c];
#pragma unroll
    for (int d = 0; d < 4; ++d) acc += x[n * 4 + d] * nw[d * HID + c];
    h[idx] = acc;
}

// ---------------------------------------------------------------- W split+transpose (once per launch)
__global__ void k_wsplit(const float* __restrict__ fkw, _Float16* __restrict__ whi,
                         _Float16* __restrict__ wlo) {
    __shared__ float sh[64][65];
    int bid = blockIdx.x;           // 4 layers * 16 kblk * 2 nblk = 128 blocks
    int l = bid >> 5; int r = bid & 31; int kb = r >> 1; int nbk = r & 1;
    const float* W = fkw + (size_t)l * 131072;
    _Float16* Hl = whi + (size_t)l * 131072;
    _Float16* Ll = wlo + (size_t)l * 131072;
    int k0 = kb * 64, n0 = nbk * 64;
    for (int i = threadIdx.x; i < 4096; i += 256) {
        int kk = i >> 6, nn = i & 63;
        sh[kk][nn] = W[(k0 + kk) * HID + n0 + nn];
    }
    __syncthreads();
    for (int i = threadIdx.x; i < 4096; i += 256) {
        int nn = i >> 6, kk = i & 63;
        float w = sh[kk][nn];
        _Float16 hi = (_Float16)w;
        _Float16 lo = (_Float16)((w - (float)hi) * 2048.f);
        Hl[(n0 + nn) * 1024 + k0 + kk] = hi;
        Ll[(n0 + nn) * 1024 + k0 + kk] = lo;
    }
}

// ---------------------------------------------------------------- CSR build
__global__ void k_hist(const int* __restrict__ dst, int* __restrict__ deg, int E) {
    int e = blockIdx.x * 256 + threadIdx.x;
    if (e < E) atomicAdd(&deg[dst[e]], 1);
}

__global__ void k_scan_a(const int* __restrict__ deg, int* __restrict__ bsum, int N) {
    __shared__ int sh[256];
    int i = blockIdx.x * 256 + threadIdx.x;
    sh[threadIdx.x] = (i < N) ? deg[i] : 0;
    __syncthreads();
    for (int off = 128; off > 0; off >>= 1) {
        if (threadIdx.x < (unsigned)off) sh[threadIdx.x] += sh[threadIdx.x + off];
        __syncthreads();
    }
    if (threadIdx.x == 0) bsum[blockIdx.x] = sh[0];
}

__global__ void k_scan_b(int* __restrict__ bsum, int nb) {
    __shared__ int sh[256];
    int v = (threadIdx.x < (unsigned)nb) ? bsum[threadIdx.x] : 0;
    sh[threadIdx.x] = v;
    __syncthreads();
    for (int off = 1; off < 256; off <<= 1) {
        int add = (threadIdx.x >= (unsigned)off) ? sh[threadIdx.x - off] : 0;
        __syncthreads();
        sh[threadIdx.x] += add;
        __syncthreads();
    }
    if (threadIdx.x < (unsigned)nb) bsum[threadIdx.x] = sh[threadIdx.x] - v;
}

__global__ void k_scan_c(const int* __restrict__ deg, const int* __restrict__ bsum,
                         int* __restrict__ offs, int* __restrict__ cursor, int N) {
    __shared__ int sh[256];
    int i = blockIdx.x * 256 + threadIdx.x;
    int v = (i < N) ? deg[i] : 0;
    sh[threadIdx.x] = v;
    __syncthreads();
    for (int off = 1; off < 256; off <<= 1) {
        int add = (threadIdx.x >= (unsigned)off) ? sh[threadIdx.x - off] : 0;
        __syncthreads();
        sh[threadIdx.x] += add;
        __syncthreads();
    }
    int ex = bsum[blockIdx.x] + sh[threadIdx.x] - v;
    if (i < N) { offs[i] = ex; cursor[i] = ex; }
    if (i == N - 1) offs[N] = ex + v;
}

// scatter edges into CSR order; writes srco AND edge_attr (float4) directly
__global__ void k_scatter(const int* __restrict__ src, const int* __restrict__ dst,
                          const float* __restrict__ ea, int* cursor,
                          int* __restrict__ srco, float4* __restrict__ ea3o, int E) {
    int e = blockIdx.x * 256 + threadIdx.x;
    if (e < E) {
        int d = dst[e];
        int p = atomicAdd(&cursor[d], 1);
        srco[p] = src[e];
        float4 q;
        q.x = ea[e * 3 + 0]; q.y = ea[e * 3 + 1]; q.z = ea[e * 3 + 2]; q.w = 0.f;
        ea3o[p] = q;
    }
}

__global__ void k_bstart(const int* __restrict__ batch, int* __restrict__ boffs, int N, int B) {
    int n = blockIdx.x * 256 + threadIdx.x;
    if (n >= N) return;
    int b1 = batch[n];
    if (n == 0) for (int b = 0; b <= b1; ++b) boffs[b] = 0;
    int b2 = (n + 1 < N) ? batch[n + 1] : B;
    for (int b = b1 + 1; b <= b2; ++b) boffs[b] = n + 1;
}

// ---------------------------------------------------------------- per-node linear + attention dots (fused, fp32)
__global__ __launch_bounds__(256) void k_node_lin(const float* __restrict__ h,
                           const float* __restrict__ linw, const float* __restrict__ linb,
                           const float* __restrict__ attw, const float* __restrict__ attb,
                           float* __restrict__ A1, float* __restrict__ A2,
                           float* __restrict__ a1, float* __restrict__ a2, int N) {
    __shared__ float hT[HID][12];
    int nb = blockIdx.x * 8;
    int tid = threadIdx.x;
    for (int i = tid; i < 8 * HID; i += 256) {
        int n = i >> 7, c = i & 127;
        int gn = nb + n;
        hT[c][n] = (gn < N) ? h[gn * HID + c] : 0.f;
    }
    __syncthreads();
    {
        int node = tid >> 5, lane32 = tid & 31;
        float p1 = 0.f, p2 = 0.f;
#pragma unroll
        for (int j = 0; j < 4; ++j) {
            int k = lane32 * 4 + j;
            float hv = hT[k][node];
            p1 += hv * attw[k];
            p2 += hv * attw[128 + k];
        }
        for (int off = 16; off > 0; off >>= 1) {
            p1 += __shfl_down(p1, off, 32);
            p2 += __shfl_down(p2, off, 32);
        }
        int gn = nb + node;
        if (lane32 == 0 && gn < N) {
            a1[gn] = p1 + attb[0];
            a2[gn] = p2;
        }
    }
    int c = tid & 127, r = tid >> 7;
    const float* Wd = linw;
    const float* Ws = linw + 128 * HID;
    float acc1[4] = {0, 0, 0, 0}, acc2[4] = {0, 0, 0, 0};
#pragma unroll 4
    for (int k = 0; k < HID; ++k) {
        float wd = Wd[k * HID + c];
        float ws = Ws[k * HID + c];
        float4 hv = *(const float4*)&hT[k][r * 4];
        acc1[0] += hv.x * wd; acc2[0] += hv.x * ws;
        acc1[1] += hv.y * wd; acc2[1] += hv.y * ws;
        acc1[2] += hv.z * wd; acc2[2] += hv.z * ws;
        acc1[3] += hv.w * wd; acc2[3] += hv.w * ws;
    }
#pragma unroll
    for (int j = 0; j < 4; ++j) {
        int gn = nb + r * 4 + j;
        if (gn < N) {
            A1[gn * HID + c] = acc1[j] + linb[c];
            A2[gn * HID + c] = acc2[j];
        }
    }
}

// ---------------------------------------------------------------- edge conv (CSR, 8 slots, float4, alpha fused)
// direct weight loads, single-barrier reduction, padded partials;
// also zeroes the bn stats buffer (block 0)
__global__ __launch_bounds__(256) void k_edge(const float* __restrict__ A1,
        const float* __restrict__ A2, const float* __restrict__ a1,
        const float* __restrict__ a2, const int* __restrict__ srco,
        const float4* __restrict__ ea3o, const int* __restrict__ offs,
        const float* __restrict__ linw3, const float* __restrict__ attw3,
        float* __restrict__ hconv, double* __restrict__ stats, int N) {
    __shared__ float part[8][HID + 4];
    int n = blockIdx.x;
    int tid = threadIdx.x;
    if (n == 0) stats[tid] = 0.0;
    int lane32 = tid & 31, slot = tid >> 5;
    int c4 = lane32 * 4;
    float4 w0v = *(const float4*)&linw3[c4];
    float4 w1v = *(const float4*)&linw3[HID + c4];
    float4 w2v = *(const float4*)&linw3[2 * HID + c4];
    float aw0 = attw3[0], aw1 = attw3[1], aw2 = attw3[2];
    float a1n = a1[n];
    float4 A1v = *(const float4*)&A1[(size_t)n * HID + c4];
    float4 acc; acc.x = acc.y = acc.z = acc.w = 0.f;
    int s0 = offs[n], s1 = offs[n + 1];
    for (int idx = s0 + slot; idx < s1; idx += 8) {
        int s = srco[idx];
        float4 q = ea3o[idx];
        float logit = a1n + a2[s] + q.x * aw0 + q.y * aw1 + q.z * aw2;
        float al = 1.f / (1.f + __expf(-logit));
        float4 a2v = *(const float4*)&A2[(size_t)s * HID + c4];
        float4 pre;
        pre.x = A1v.x + a2v.x + q.x * w0v.x + q.y * w1v.x + q.z * w2v.x;
        pre.y = A1v.y + a2v.y + q.x * w0v.y + q.y * w1v.y + q.z * w2v.y;
        pre.z = A1v.z + a2v.z + q.x * w0v.z + q.y * w1v.z + q.z * w2v.z;
        pre.w = A1v.w + a2v.w + q.x * w0v.w + q.y * w1v.w + q.z * w2v.w;
        acc.x += al * pre.x; acc.y += al * pre.y;
        acc.z += al * pre.z; acc.w += al * pre.w;
    }
    *(float4*)&part[slot][c4] = acc;
    __syncthreads();
    if (slot == 0) {
        float4 p = *(const float4*)&part[0][c4];
#pragma unroll
        for (int s = 1; s < 8; ++s) {
            float4 r = *(const float4*)&part[s][c4];
            p.x += r.x; p.y += r.y; p.z += r.z; p.w += r.w;
        }
        *(float4*)&hconv[(size_t)n * HID + c4] = p;
    }
}

// ---------------------------------------------------------------- Fourier-Kolmogorov GEMM (split-f16 MFMA)
// R11 structure: K-split 4; trig threads read own h spans from global; padded
// LDS A-planes; ONE barrier then barrier-free ds_read + global-B + MFMA stream.
#define FK_AST  264        // f16 per staged-A row (256 + 8 pad) = 528 B
__global__ __launch_bounds__(256) void k_fk(const float* __restrict__ h,
        const _Float16* __restrict__ whi, const _Float16* __restrict__ wlo,
        float* __restrict__ p0, float* __restrict__ p1,
        float* __restrict__ p2, float* __restrict__ p3, int N) {
    __shared__ _Float16 ahi[32 * FK_AST];
    __shared__ _Float16 alo[32 * FK_AST];
    int tid = threadIdx.x;
    int bx = blockIdx.x;
    int nb = (bx >> 2) * 32;
    int ks = bx & 3;
    int kbase = ks * 256;
    int fr0 = kbase >> 7;
    {
        int row = tid >> 3;
        int o8 = tid & 7;
        int gn = nb + row;
        int rc = (gn < N) ? gn : (N - 1);
        const float* hp = h + (size_t)rc * HID + o8 * 8;
        float hv[2][8];
        *(float4*)&hv[0][0] = *(const float4*)hp;
        *(float4*)&hv[0][4] = *(const float4*)(hp + 4);
        *(float4*)&hv[1][0] = *(const float4*)(hp + 64);
        *(float4*)&hv[1][4] = *(const float4*)(hp + 68);
#pragma unroll
        for (int g = 0; g < 2; ++g) {
            float freqf = 6.2831853f * (float)(fr0 + g + 1);
#pragma unroll
            for (int s = 0; s < 2; ++s) {
                half8 vh, vl;
#pragma unroll
                for (int j = 0; j < 8; ++j) {
                    float ang = freqf * hv[s][j] + 0.78539816f;
                    float a = 1.41421356f * __sinf(ang);
                    _Float16 hi = (_Float16)a;
                    vh[j] = hi;
                    vl[j] = (_Float16)((a - (float)hi) * 2048.f);
                }
                int oct = g * 16 + s * 8 + o8;
                *(half8*)&ahi[row * FK_AST + oct * 8] = vh;
                *(half8*)&alo[row * FK_AST + oct * 8] = vl;
            }
        }
    }
    __syncthreads();
    int lane = tid & 63, wv = tid >> 6;
    int quad = lane >> 4, l16 = lane & 15;
    int n0w = wv * 32;
    f4 acc0[2][2], accL[2][2];
#pragma unroll
    for (int mi = 0; mi < 2; ++mi)
#pragma unroll
        for (int ni = 0; ni < 2; ++ni) { acc0[mi][ni] = (f4)(0.f); accL[mi][ni] = (f4)(0.f); }
    const _Float16* bhp0 = whi + (size_t)(n0w + l16) * 1024 + kbase + quad * 8;
    const _Float16* bhp1 = whi + (size_t)(n0w + 16 + l16) * 1024 + kbase + quad * 8;
    const _Float16* blp0 = wlo + (size_t)(n0w + l16) * 1024 + kbase + quad * 8;
    const _Float16* blp1 = wlo + (size_t)(n0w + 16 + l16) * 1024 + kbase + quad * 8;
#pragma unroll 2
    for (int step = 0; step < 8; ++step) {
        int ka = step * 32 + quad * 8;
        half8 ah0 = *(const half8*)&ahi[l16 * FK_AST + ka];
        half8 ah1 = *(const half8*)&ahi[(l16 + 16) * FK_AST + ka];
        half8 al0 = *(const half8*)&alo[l16 * FK_AST + ka];
        half8 al1 = *(const half8*)&alo[(l16 + 16) * FK_AST + ka];
        int ko = step * 32;
        half8 bh0 = *(const half8*)(bhp0 + ko);
        half8 bh1 = *(const half8*)(bhp1 + ko);
        half8 bl0 = *(const half8*)(blp0 + ko);
        half8 bl1 = *(const half8*)(blp1 + ko);
        acc0[0][0] = __builtin_amdgcn_mfma_f32_16x16x32_f16(ah0, bh0, acc0[0][0], 0, 0, 0);
        acc0[0][1] = __builtin_amdgcn_mfma_f32_16x16x32_f16(ah0, bh1, acc0[0][1], 0, 0, 0);
        acc0[1][0] = __builtin_amdgcn_mfma_f32_16x16x32_f16(ah1, bh0, acc0[1][0], 0, 0, 0);
        acc0[1][1] = __builtin_amdgcn_mfma_f32_16x16x32_f16(ah1, bh1, acc0[1][1], 0, 0, 0);
        accL[0][0] = __builtin_amdgcn_mfma_f32_16x16x32_f16(ah0, bl0, accL[0][0], 0, 0, 0);
        accL[0][1] = __builtin_amdgcn_mfma_f32_16x16x32_f16(ah0, bl1, accL[0][1], 0, 0, 0);
        accL[1][0] = __builtin_amdgcn_mfma_f32_16x16x32_f16(ah1, bl0, accL[1][0], 0, 0, 0);
        accL[1][1] = __builtin_amdgcn_mfma_f32_16x16x32_f16(ah1, bl1, accL[1][1], 0, 0, 0);
        accL[0][0] = __builtin_amdgcn_mfma_f32_16x16x32_f16(al0, bh0, accL[0][0], 0, 0, 0);
        accL[0][1] = __builtin_amdgcn_mfma_f32_16x16x32_f16(al0, bh1, accL[0][1], 0, 0, 0);
        accL[1][0] = __builtin_amdgcn_mfma_f32_16x16x32_f16(al1, bh0, accL[1][0], 0, 0, 0);
        accL[1][1] = __builtin_amdgcn_mfma_f32_16x16x32_f16(al1, bh1, accL[1][1], 0, 0, 0);
    }
    float* p = (ks == 0) ? p0 : (ks == 1) ? p1 : (ks == 2) ? p2 : p3;
    const float inv = 1.0f / 2048.0f;
#pragma unroll
    for (int mi = 0; mi < 2; ++mi)
#pragma unroll
        for (int ni = 0; ni < 2; ++ni)
#pragma unroll
            for (int r = 0; r < 4; ++r) {
                int gn = nb + mi * 16 + quad * 4 + r;
                if (gn < N)
                    p[gn * HID + n0w + ni * 16 + l16] = acc0[mi][ni][r] + accL[mi][ni][r] * inv;
            }
}

// ---------------------------------------------------------------- batchnorm stats (float4 per thread, 5 streams)
__global__ __launch_bounds__(256) void k_bn_stats(float* __restrict__ hconv,
                           const float* __restrict__ p0, const float* __restrict__ p1,
                           const float* __restrict__ p2, const float* __restrict__ p3,
                           const float* __restrict__ fkb,
                           double* __restrict__ stats, int N) {
    int tid = threadIdx.x;
    int cq = tid & 31, rg = tid >> 5;          // 8 row slots x 32 channel-quads
    int c4 = cq * 4;
    float4 bias = *(const float4*)&fkb[c4];
    float s1[4] = {0, 0, 0, 0}, s2[4] = {0, 0, 0, 0};
    for (int n = blockIdx.x * 8 + rg; n < N; n += gridDim.x * 8) {
        size_t idx = (size_t)n * HID + c4;
        float4 a  = *(const float4*)&hconv[idx];
        float4 b0 = *(const float4*)&p0[idx];
        float4 b1 = *(const float4*)&p1[idx];
        float4 b2 = *(const float4*)&p2[idx];
        float4 b3 = *(const float4*)&p3[idx];
        float4 v;
        v.x = a.x + b0.x + b1.x + b2.x + b3.x + bias.x;
        v.y = a.y + b0.y + b1.y + b2.y + b3.y + bias.y;
        v.z = a.z + b0.z + b1.z + b2.z + b3.z + bias.z;
        v.w = a.w + b0.w + b1.w + b2.w + b3.w + bias.w;
        *(float4*)&hconv[idx] = v;
        s1[0] += v.x; s2[0] += v.x * v.x;
        s1[1] += v.y; s2[1] += v.y * v.y;
        s1[2] += v.z; s2[2] += v.z * v.z;
        s1[3] += v.w; s2[3] += v.w * v.w;
    }
    // lanes l and l+32 share the same cq: fold within wave
#pragma unroll
    for (int j = 0; j < 4; ++j) {
        s1[j] += __shfl_down(s1[j], 32);
        s2[j] += __shfl_down(s2[j], 32);
    }
    __shared__ float sh1[4][32][4], sh2[4][32][4];
    int wv = tid >> 6, lane = tid & 63;
    if (lane < 32) {
#pragma unroll
        for (int j = 0; j < 4; ++j) { sh1[wv][lane][j] = s1[j]; sh2[wv][lane][j] = s2[j]; }
    }
    __syncthreads();
    if (tid < 128) {   // tid -> (cq = tid>>2, j = tid&3)
        int cq2 = tid >> 2, j2 = tid & 3;
        float t1 = sh1[0][cq2][j2] + sh1[1][cq2][j2] + sh1[2][cq2][j2] + sh1[3][cq2][j2];
        float t2 = sh2[0][cq2][j2] + sh2[1][cq2][j2] + sh2[2][cq2][j2] + sh2[3][cq2][j2];
        int c = cq2 * 4 + j2;
        atomicAdd(&stats[c], (double)t1);
        atomicAdd(&stats[128 + c], (double)t2);
    }
}

// bn_final folded in; float4 per thread; optional pool scores (last layer)
__global__ void k_bn_apply(const float* __restrict__ hsum, const double* __restrict__ stats,
                           const float* __restrict__ g, const float* __restrict__ b,
                           const float* __restrict__ pw, const float* __restrict__ pb,
                           float* __restrict__ h, float* __restrict__ s,
                           int do_score, int N) {
    int idx = blockIdx.x * 256 + threadIdx.x;   // one thread per 4 channels
    int row = idx >> 5, cq = idx & 31;
    int c4 = cq * 4;
    int valid = row < N;
    double invN = 1.0 / (double)N;
    float p = 0.f;
    if (valid) {
        float4 hv = *(const float4*)&hsum[(size_t)row * HID + c4];
        float vin[4] = {hv.x, hv.y, hv.z, hv.w};
        float4 ov;
        float* po = &ov.x;
#pragma unroll
        for (int j = 0; j < 4; ++j) {
            int c = c4 + j;
            float mu = (float)(stats[c] * invN);
            float var = (float)(stats[128 + c] * invN) - mu * mu;
            float inv = 1.f / sqrtf(var + 1e-5f);
            float sc = g[c] * inv;
            float sh = b[c] - mu * sc;
            float oo = fmaxf(vin[j] * sc + sh, 0.f);
            po[j] = oo;
            if (do_score) p += oo * pw[c];
        }
        *(float4*)&h[(size_t)row * HID + c4] = ov;
    }
    if (do_score) {
        for (int off = 16; off > 0; off >>= 1) p += __shfl_down(p, off, 32);
        if ((threadIdx.x & 31) == 0 && valid) s[row] = p + pb[0];
    }
}

// ---------------------------------------------------------------- softmax partials
__global__ void k_smax1(const float* __restrict__ s, float* __restrict__ mzp, int N) {
    __shared__ float red[256];
    float m = -INFINITY;
    for (int n = blockIdx.x * 256 + threadIdx.x; n < N; n += SMAXB * 256)
        m = fmaxf(m, s[n]);
    red[threadIdx.x] = m;
    __syncthreads();
    for (int off = 128; off > 0; off >>= 1) {
        if (threadIdx.x < (unsigned)off)
            red[threadIdx.x] = fmaxf(red[threadIdx.x], red[threadIdx.x + off]);
        __syncthreads();
    }
    m = red[0];
    __syncthreads();
    float z = 0.f;
    for (int n = blockIdx.x * 256 + threadIdx.x; n < N; n += SMAXB * 256)
        z += __expf(s[n] - m);
    red[threadIdx.x] = z;
    __syncthreads();
    for (int off = 128; off > 0; off >>= 1) {
        if (threadIdx.x < (unsigned)off) red[threadIdx.x] += red[threadIdx.x + off];
        __syncthreads();
    }
    if (threadIdx.x == 0) { mzp[blockIdx.x * 2] = m; mzp[blockIdx.x * 2 + 1] = red[0]; }
}

__device__ __forceinline__ void combine_mz(const float* mzp, float& m, float& Z) {
    m = -INFINITY;
#pragma unroll 8
    for (int i = 0; i < SMAXB; ++i) m = fmaxf(m, mzp[i * 2]);
    Z = 0.f;
#pragma unroll 8
    for (int i = 0; i < SMAXB; ++i) Z += mzp[i * 2 + 1] * __expf(mzp[i * 2] - m);
}

// ---------------------------------------------------------------- attention pool (split)
__global__ void k_pool_part(const float* __restrict__ h, const float* __restrict__ s,
                            const float* __restrict__ mzp, const int* __restrict__ boffs,
                            float* __restrict__ part) {
    int b = blockIdx.x >> 4, split = blockIdx.x & (PSPLIT - 1);
    int c = threadIdx.x & 127, half = threadIdx.x >> 7;
    float m, Z;
    combine_mz(mzp, m, Z);
    (void)Z;
    int n0 = boffs[b], n1 = boffs[b + 1];
    float acc = 0.f;
    for (int n = n0 + split * 2 + half; n < n1; n += PSPLIT * 2)
        acc += __expf(s[n] - m) * h[n * HID + c];
    __shared__ float prt[2][HID];
    prt[half][c] = acc;
    __syncthreads();
    if (half == 0) part[(size_t)(b * PSPLIT + split) * HID + c] = prt[0][c] + prt[1][c];
}

__global__ void k_pool_sum(const float* __restrict__ part, const float* __restrict__ mzp,
                           float* __restrict__ pooled) {
    int b = blockIdx.x, c = threadIdx.x;
    float m, Z;
    combine_mz(mzp, m, Z);
    float acc = 0.f;
#pragma unroll
    for (int i = 0; i < PSPLIT; ++i) acc += part[(size_t)(b * PSPLIT + i) * HID + c];
    pooled[b * HID + c] = acc / Z;
}

// ---------------------------------------------------------------- heads (grid = B*4)
__global__ __launch_bounds__(256) void k_head(const float* __restrict__ pooled,
                       const float* __restrict__ sg_table,
                       const int* __restrict__ space_group,
                       const float* __restrict__ hw1, const float* __restrict__ hb1,
                       const float* __restrict__ ew2, const float* __restrict__ eb2,
                       const float* __restrict__ sw2, const float* __restrict__ sb2,
                       const float* __restrict__ cw2, const float* __restrict__ cb2,
                       const float* __restrict__ mw2, const float* __restrict__ mb2,
                       float* __restrict__ out, int B) {
    __shared__ float comb[256];
    __shared__ float zred[2][128];
    __shared__ float zsh[128];
    int b = blockIdx.x >> 2, i = blockIdx.x & 3;
    int t = threadIdx.x;
    comb[t] = (t < 128) ? pooled[b * HID + t] : sg_table[space_group[b] * HID + (t - 128)];
    __syncthreads();
    int half = t >> 7, tt = t & 127;
    const float* W = hw1 + ((size_t)i * 256 + half * 128) * HID;
    const float* cb = &comb[half * 128];
    float z = 0.f;
#pragma unroll 8
    for (int k = 0; k < 128; ++k) z += cb[k] * W[k * HID + tt];
    zred[half][tt] = z;
    __syncthreads();
    if (t < 128) zsh[t] = fmaxf(zred[0][t] + zred[1][t] + hb1[i * HID + t], 0.f);
    __syncthreads();
    const int od[4] = {1, 3, 7, 3};
    const int base[4] = {0, 64, 256, 704};
    const float* w2 = (i == 0) ? ew2 : (i == 1) ? sw2 : (i == 2) ? cw2 : mw2;
    const float* b2 = (i == 0) ? eb2 : (i == 1) ? sb2 : (i == 2) ? cb2 : mb2;
    int odi = od[i];
    if (t < odi) {
        float o = b2[t];
        for (int c = 0; c < HID; ++c) o += zsh[c] * w2[c * odi + t];
        out[base[i] + b * odi + t] = o;
    }
}

// ---------------------------------------------------------------- launch
extern "C" void kernel_launch(void* const* d_in, const int* in_sizes, int n_in,
                              void* d_out, int out_size, void* d_ws, size_t ws_size,
                              hipStream_t stream) {
    const float* x          = (const float*)d_in[0];
    const int*   edge_index = (const int*)d_in[1];
    const float* edge_attr  = (const float*)d_in[2];
    const int*   batch      = (const int*)d_in[3];
    const int*   space_group= (const int*)d_in[4];
    const float* node_w     = (const float*)d_in[5];
    const float* node_b     = (const float*)d_in[6];
    const float* sg_table   = (const float*)d_in[7];
    const float* lin_w      = (const float*)d_in[8];
    const float* lin_b      = (const float*)d_in[9];
    const float* att_w      = (const float*)d_in[10];
    const float* att_b      = (const float*)d_in[11];
    const float* fk_w       = (const float*)d_in[12];
    const float* fk_b       = (const float*)d_in[13];
    const float* bn_g       = (const float*)d_in[14];
    const float* bn_b       = (const float*)d_in[15];
    const float* pool_w     = (const float*)d_in[16];
    const float* pool_b     = (const float*)d_in[17];
    const float* head_w1    = (const float*)d_in[18];
    const float* head_b1    = (const float*)d_in[19];
    const float* ew2 = (const float*)d_in[20]; const float* eb2 = (const float*)d_in[21];
    const float* sw2 = (const float*)d_in[22]; const float* sb2 = (const float*)d_in[23];
    const float* cw2 = (const float*)d_in[24]; const float* cb2 = (const float*)d_in[25];
    const float* mw2 = (const float*)d_in[26]; const float* mb2 = (const float*)d_in[27];
    float* out = (float*)d_out;

    const int N = in_sizes[3];
    const int E = in_sizes[1] / 2;
    const int B = in_sizes[4];
    const int* src = edge_index;
    const int* dst = edge_index + E;

    char* w = (char*)d_ws;
    auto alloc = [&](size_t bytes) { char* p = w; w += (bytes + 255) & ~(size_t)255; return p; };
    float*  h      = (float*)alloc((size_t)N * HID * 4);
    float*  A1     = (float*)alloc((size_t)N * HID * 4);  // reused as FK partial 0
    float*  A2     = (float*)alloc((size_t)N * HID * 4);  // reused as FK partial 1
    float*  p2     = (float*)alloc((size_t)N * HID * 4);  // FK partial 2
    float*  p3     = (float*)alloc((size_t)N * HID * 4);  // FK partial 3
    float*  hconv  = (float*)alloc((size_t)N * HID * 4);  // becomes pre-BN sum in place
    float*  a1     = (float*)alloc((size_t)N * 4);
    float*  a2     = (float*)alloc((size_t)N * 4);
    float*  sbuf   = (float*)alloc((size_t)N * 4);
    int*    deg    = (int*)alloc((size_t)N * 4);
    int*    cursor = (int*)alloc((size_t)N * 4);
    int*    offs   = (int*)alloc((size_t)(N + 1) * 4);
    int*    srco   = (int*)alloc((size_t)E * 4);
    float4* ea3o   = (float4*)alloc((size_t)E * 16);
    _Float16* whi  = (_Float16*)alloc((size_t)DEPTH * 1024 * HID * 2);
    _Float16* wlo  = (_Float16*)alloc((size_t)DEPTH * 1024 * HID * 2);
    int*    bsum   = (int*)alloc(256 * 4);
    int*    boffs  = (int*)alloc((size_t)(B + 1) * 4);
    double* stats  = (double*)alloc(256 * 8);
    float*  mzp    = (float*)alloc(SMAXB * 2 * 4);
    float*  part   = (float*)alloc((size_t)B * PSPLIT * HID * 4);
    float*  pooled = (float*)alloc((size_t)B * HID * 4);

    const int nchunk = (N + 255) / 256;
    const int echunk = (E + 255) / 256;

    // one-time per launch: W split + CSR build
    k_wsplit<<<128, 256, 0, stream>>>(fk_w, whi, wlo);
    hipMemsetAsync(deg, 0, (size_t)N * 4, stream);
    k_hist<<<echunk, 256, 0, stream>>>(dst, deg, E);
    k_scan_a<<<nchunk, 256, 0, stream>>>(deg, bsum, N);
    k_scan_b<<<1, 256, 0, stream>>>(bsum, nchunk);
    k_scan_c<<<nchunk, 256, 0, stream>>>(deg, bsum, offs, cursor, N);
    k_scatter<<<echunk, 256, 0, stream>>>(src, dst, edge_attr, cursor, srco, ea3o, E);
    k_bstart<<<nchunk, 256, 0, stream>>>(batch, boffs, N, B);

    k_node_embed<<<(N * HID + 255) / 256, 256, 0, stream>>>(x, node_w, node_b, h, N);

    for (int l = 0; l < DEPTH; ++l) {
        const float* linw_l = lin_w + (size_t)l * 259 * HID;
        k_node_lin<<<(N + 7) / 8, 256, 0, stream>>>(
            h, linw_l, lin_b + l * HID, att_w + (size_t)l * 259, att_b + l,
            A1, A2, a1, a2, N);
        k_edge<<<N, 256, 0, stream>>>(A1, A2, a1, a2, srco, ea3o, offs,
                                      linw_l + 256 * HID, att_w + (size_t)l * 259 + 256,
                                      hconv, stats, N);
        k_fk<<<((N + 31) / 32) * 4, 256, 0, stream>>>(
            h, whi + (size_t)l * 131072, wlo + (size_t)l * 131072, A1, A2, p2, p3, N);
        k_bn_stats<<<320, 256, 0, stream>>>(hconv, A1, A2, p2, p3, fk_b + l * HID, stats, N);
        k_bn_apply<<<(N * 32 + 255) / 256, 256, 0, stream>>>(
            hconv, stats, bn_g + l * HID, bn_b + l * HID, pool_w, pool_b,
            h, sbuf, (l == DEPTH - 1) ? 1 : 0, N);
    }

    k_smax1<<<SMAXB, 256, 0, stream>>>(sbuf, mzp, N);
    k_pool_part<<<B * PSPLIT, 256, 0, stream>>>(h, sbuf, mzp, boffs, part);
    k_pool_sum<<<B, 128, 0, stream>>>(part, mzp, pooled);
    k_head<<<B * 4, 256, 0, stream>>>(pooled, sg_table, space_group, head_w1, head_b1,
                                      ew2, eb2, sw2, sb2, cw2, cb2, mw2, mb2, out, B);
}

// Round 19
// 710.966 us; speedup vs baseline: 1.4068x; 1.0257x over previous
//
#include <hip/hip_runtime.h>
#include <math.h>

#define HID 128
#define DEPTH 4
#define PSPLIT 16
#define SMAXB 40

typedef _Float16 half8 __attribute__((ext_vector_type(8)));
typedef float f4 __attribute__((ext_vector_type(4)));

// ---------------------------------------------------------------- node embed
__global__ void k_node_embed(const float* __restrict__ x, const float* __restrict__ nw,
                             const float* __restrict__ nb, float* __restrict__ h, int N) {
    int idx = blockIdx.x * blockDim.x + threadIdx.x;
    if (idx >= N * HID) return;
    int n = idx >> 7, c = idx & 127;
    float acc = nb[c];
#pragma unroll
    for (int d = 0; d < 4; ++d) acc += x[n * 4 + d] * nw[d * HID + c];
    h[idx] = acc;
}

// ---------------------------------------------------------------- W split+transpose (once per launch)
__global__ void k_wsplit(const float* __restrict__ fkw, _Float16* __restrict__ whi,
                         _Float16* __restrict__ wlo) {
    __shared__ float sh[64][65];
    int bid = blockIdx.x;           // 4 layers * 16 kblk * 2 nblk = 128 blocks
    int l = bid >> 5; int r = bid & 31; int kb = r >> 1; int nbk = r & 1;
    const float* W = fkw + (size_t)l * 131072;
    _Float16* Hl = whi + (size_t)l * 131072;
    _Float16* Ll = wlo + (size_t)l * 131072;
    int k0 = kb * 64, n0 = nbk * 64;
    for (int i = threadIdx.x; i < 4096; i += 256) {
        int kk = i >> 6, nn = i & 63;
        sh[kk][nn] = W[(k0 + kk) * HID + n0 + nn];
    }
    __syncthreads();
    for (int i = threadIdx.x; i < 4096; i += 256) {
        int nn = i >> 6, kk = i & 63;
        float w = sh[kk][nn];
        _Float16 hi = (_Float16)w;
        _Float16 lo = (_Float16)((w - (float)hi) * 2048.f);
        Hl[(n0 + nn) * 1024 + k0 + kk] = hi;
        Ll[(n0 + nn) * 1024 + k0 + kk] = lo;
    }
}

// ---------------------------------------------------------------- CSR build
__global__ void k_hist(const int* __restrict__ dst, int* __restrict__ deg, int E) {
    int e = blockIdx.x * 256 + threadIdx.x;
    if (e < E) atomicAdd(&deg[dst[e]], 1);
}

__global__ void k_scan_a(const int* __restrict__ deg, int* __restrict__ bsum, int N) {
    __shared__ int sh[256];
    int i = blockIdx.x * 256 + threadIdx.x;
    sh[threadIdx.x] = (i < N) ? deg[i] : 0;
    __syncthreads();
    for (int off = 128; off > 0; off >>= 1) {
        if (threadIdx.x < (unsigned)off) sh[threadIdx.x] += sh[threadIdx.x + off];
        __syncthreads();
    }
    if (threadIdx.x == 0) bsum[blockIdx.x] = sh[0];
}

__global__ void k_scan_b(int* __restrict__ bsum, int nb) {
    __shared__ int sh[256];
    int v = (threadIdx.x < (unsigned)nb) ? bsum[threadIdx.x] : 0;
    sh[threadIdx.x] = v;
    __syncthreads();
    for (int off = 1; off < 256; off <<= 1) {
        int add = (threadIdx.x >= (unsigned)off) ? sh[threadIdx.x - off] : 0;
        __syncthreads();
        sh[threadIdx.x] += add;
        __syncthreads();
    }
    if (threadIdx.x < (unsigned)nb) bsum[threadIdx.x] = sh[threadIdx.x] - v;
}

__global__ void k_scan_c(const int* __restrict__ deg, const int* __restrict__ bsum,
                         int* __restrict__ offs, int* __restrict__ cursor, int N) {
    __shared__ int sh[256];
    int i = blockIdx.x * 256 + threadIdx.x;
    int v = (i < N) ? deg[i] : 0;
    sh[threadIdx.x] = v;
    __syncthreads();
    for (int off = 1; off < 256; off <<= 1) {
        int add = (threadIdx.x >= (unsigned)off) ? sh[threadIdx.x - off] : 0;
        __syncthreads();
        sh[threadIdx.x] += add;
        __syncthreads();
    }
    int ex = bsum[blockIdx.x] + sh[threadIdx.x] - v;
    if (i < N) { offs[i] = ex; cursor[i] = ex; }
    if (i == N - 1) offs[N] = ex + v;
}

// scatter edges into CSR order; writes srco AND edge_attr (float4) directly
__global__ void k_scatter(const int* __restrict__ src, const int* __restrict__ dst,
                          const float* __restrict__ ea, int* cursor,
                          int* __restrict__ srco, float4* __restrict__ ea3o, int E) {
    int e = blockIdx.x * 256 + threadIdx.x;
    if (e < E) {
        int d = dst[e];
        int p = atomicAdd(&cursor[d], 1);
        srco[p] = src[e];
        float4 q;
        q.x = ea[e * 3 + 0]; q.y = ea[e * 3 + 1]; q.z = ea[e * 3 + 2]; q.w = 0.f;
        ea3o[p] = q;
    }
}

__global__ void k_bstart(const int* __restrict__ batch, int* __restrict__ boffs, int N, int B) {
    int n = blockIdx.x * 256 + threadIdx.x;
    if (n >= N) return;
    int b1 = batch[n];
    if (n == 0) for (int b = 0; b <= b1; ++b) boffs[b] = 0;
    int b2 = (n + 1 < N) ? batch[n + 1] : B;
    for (int b = b1 + 1; b <= b2; ++b) boffs[b] = n + 1;
}

// ---------------------------------------------------------------- per-node linear + attention dots (fused, fp32)
// 16-node tiles: halves per-layer weight re-streaming (320 -> 160 MB), 16:4
// FMA:load inner loop. Outputs bit-identical to the 8-node version.
__global__ __launch_bounds__(256) void k_node_lin(const float* __restrict__ h,
                           const float* __restrict__ linw, const float* __restrict__ linb,
                           const float* __restrict__ attw, const float* __restrict__ attb,
                           float* __restrict__ A1, float* __restrict__ A2,
                           float* __restrict__ a1, float* __restrict__ a2, int N) {
    __shared__ float hT[HID][20];   // 16 nodes + 4 pad (16B-aligned rows)
    int nb = blockIdx.x * 16;
    int tid = threadIdx.x;
    for (int i = tid; i < 16 * HID; i += 256) {
        int n = i >> 7, c = i & 127;
        int gn = nb + n;
        hT[c][n] = (gn < N) ? h[gn * HID + c] : 0.f;
    }
    __syncthreads();
    {   // attention dots: 16 nodes x 16 lanes, 8 channels each
        int node = tid >> 4, lane16 = tid & 15;
        float p1 = 0.f, p2 = 0.f;
#pragma unroll
        for (int j = 0; j < 8; ++j) {
            int k = lane16 * 8 + j;
            float hv = hT[k][node];
            p1 += hv * attw[k];
            p2 += hv * attw[128 + k];
        }
        for (int off = 8; off > 0; off >>= 1) {
            p1 += __shfl_down(p1, off, 16);
            p2 += __shfl_down(p2, off, 16);
        }
        int gn = nb + node;
        if (lane16 == 0 && gn < N) {
            a1[gn] = p1 + attb[0];
            a2[gn] = p2;
        }
    }
    int c = tid & 127, r = tid >> 7;   // r in {0,1}: nodes r*8 .. r*8+7
    const float* Wd = linw;
    const float* Ws = linw + 128 * HID;
    float acc1[8] = {0, 0, 0, 0, 0, 0, 0, 0}, acc2[8] = {0, 0, 0, 0, 0, 0, 0, 0};
#pragma unroll 4
    for (int k = 0; k < HID; ++k) {
        float wd = Wd[k * HID + c];
        float ws = Ws[k * HID + c];
        float4 h0 = *(const float4*)&hT[k][r * 8];
        float4 h1 = *(const float4*)&hT[k][r * 8 + 4];
        acc1[0] += h0.x * wd; acc2[0] += h0.x * ws;
        acc1[1] += h0.y * wd; acc2[1] += h0.y * ws;
        acc1[2] += h0.z * wd; acc2[2] += h0.z * ws;
        acc1[3] += h0.w * wd; acc2[3] += h0.w * ws;
        acc1[4] += h1.x * wd; acc2[4] += h1.x * ws;
        acc1[5] += h1.y * wd; acc2[5] += h1.y * ws;
        acc1[6] += h1.z * wd; acc2[6] += h1.z * ws;
        acc1[7] += h1.w * wd; acc2[7] += h1.w * ws;
    }
    float lb = linb[c];
#pragma unroll
    for (int j = 0; j < 8; ++j) {
        int gn = nb + r * 8 + j;
        if (gn < N) {
            A1[(size_t)gn * HID + c] = acc1[j] + lb;
            A2[(size_t)gn * HID + c] = acc2[j];
        }
    }
}

// ---------------------------------------------------------------- edge conv (CSR, 8 slots, float4, alpha fused)
// direct weight loads, single-barrier reduction, padded partials;
// also zeroes the bn stats buffer (block 0)
__global__ __launch_bounds__(256) void k_edge(const float* __restrict__ A1,
        const float* __restrict__ A2, const float* __restrict__ a1,
        const float* __restrict__ a2, const int* __restrict__ srco,
        const float4* __restrict__ ea3o, const int* __restrict__ offs,
        const float* __restrict__ linw3, const float* __restrict__ attw3,
        float* __restrict__ hconv, double* __restrict__ stats, int N) {
    __shared__ float part[8][HID + 4];
    int n = blockIdx.x;
    int tid = threadIdx.x;
    if (n == 0) stats[tid] = 0.0;
    int lane32 = tid & 31, slot = tid >> 5;
    int c4 = lane32 * 4;
    float4 w0v = *(const float4*)&linw3[c4];
    float4 w1v = *(const float4*)&linw3[HID + c4];
    float4 w2v = *(const float4*)&linw3[2 * HID + c4];
    float aw0 = attw3[0], aw1 = attw3[1], aw2 = attw3[2];
    float a1n = a1[n];
    float4 A1v = *(const float4*)&A1[(size_t)n * HID + c4];
    float4 acc; acc.x = acc.y = acc.z = acc.w = 0.f;
    int s0 = offs[n], s1 = offs[n + 1];
    for (int idx = s0 + slot; idx < s1; idx += 8) {
        int s = srco[idx];
        float4 q = ea3o[idx];
        float logit = a1n + a2[s] + q.x * aw0 + q.y * aw1 + q.z * aw2;
        float al = 1.f / (1.f + __expf(-logit));
        float4 a2v = *(const float4*)&A2[(size_t)s * HID + c4];
        float4 pre;
        pre.x = A1v.x + a2v.x + q.x * w0v.x + q.y * w1v.x + q.z * w2v.x;
        pre.y = A1v.y + a2v.y + q.x * w0v.y + q.y * w1v.y + q.z * w2v.y;
        pre.z = A1v.z + a2v.z + q.x * w0v.z + q.y * w1v.z + q.z * w2v.z;
        pre.w = A1v.w + a2v.w + q.x * w0v.w + q.y * w1v.w + q.z * w2v.w;
        acc.x += al * pre.x; acc.y += al * pre.y;
        acc.z += al * pre.z; acc.w += al * pre.w;
    }
    *(float4*)&part[slot][c4] = acc;
    __syncthreads();
    if (slot == 0) {
        float4 p = *(const float4*)&part[0][c4];
#pragma unroll
        for (int s = 1; s < 8; ++s) {
            float4 r = *(const float4*)&part[s][c4];
            p.x += r.x; p.y += r.y; p.z += r.z; p.w += r.w;
        }
        *(float4*)&hconv[(size_t)n * HID + c4] = p;
    }
}

// ---------------------------------------------------------------- Fourier-Kolmogorov GEMM (split-f16 MFMA)
// R11 structure: K-split 4; trig threads read own h spans from global; padded
// LDS A-planes; ONE barrier then barrier-free ds_read + global-B + MFMA stream.
#define FK_AST  264        // f16 per staged-A row (256 + 8 pad) = 528 B
__global__ __launch_bounds__(256) void k_fk(const float* __restrict__ h,
        const _Float16* __restrict__ whi, const _Float16* __restrict__ wlo,
        float* __restrict__ p0, float* __restrict__ p1,
        float* __restrict__ p2, float* __restrict__ p3, int N) {
    __shared__ _Float16 ahi[32 * FK_AST];
    __shared__ _Float16 alo[32 * FK_AST];
    int tid = threadIdx.x;
    int bx = blockIdx.x;
    int nb = (bx >> 2) * 32;
    int ks = bx & 3;
    int kbase = ks * 256;
    int fr0 = kbase >> 7;
    {
        int row = tid >> 3;
        int o8 = tid & 7;
        int gn = nb + row;
        int rc = (gn < N) ? gn : (N - 1);
        const float* hp = h + (size_t)rc * HID + o8 * 8;
        float hv[2][8];
        *(float4*)&hv[0][0] = *(const float4*)hp;
        *(float4*)&hv[0][4] = *(const float4*)(hp + 4);
        *(float4*)&hv[1][0] = *(const float4*)(hp + 64);
        *(float4*)&hv[1][4] = *(const float4*)(hp + 68);
#pragma unroll
        for (int g = 0; g < 2; ++g) {
            float freqf = 6.2831853f * (float)(fr0 + g + 1);
#pragma unroll
            for (int s = 0; s < 2; ++s) {
                half8 vh, vl;
#pragma unroll
                for (int j = 0; j < 8; ++j) {
                    float ang = freqf * hv[s][j] + 0.78539816f;
                    float a = 1.41421356f * __sinf(ang);
                    _Float16 hi = (_Float16)a;
                    vh[j] = hi;
                    vl[j] = (_Float16)((a - (float)hi) * 2048.f);
                }
                int oct = g * 16 + s * 8 + o8;
                *(half8*)&ahi[row * FK_AST + oct * 8] = vh;
                *(half8*)&alo[row * FK_AST + oct * 8] = vl;
            }
        }
    }
    __syncthreads();
    int lane = tid & 63, wv = tid >> 6;
    int quad = lane >> 4, l16 = lane & 15;
    int n0w = wv * 32;
    f4 acc0[2][2], accL[2][2];
#pragma unroll
    for (int mi = 0; mi < 2; ++mi)
#pragma unroll
        for (int ni = 0; ni < 2; ++ni) { acc0[mi][ni] = (f4)(0.f); accL[mi][ni] = (f4)(0.f); }
    const _Float16* bhp0 = whi + (size_t)(n0w + l16) * 1024 + kbase + quad * 8;
    const _Float16* bhp1 = whi + (size_t)(n0w + 16 + l16) * 1024 + kbase + quad * 8;
    const _Float16* blp0 = wlo + (size_t)(n0w + l16) * 1024 + kbase + quad * 8;
    const _Float16* blp1 = wlo + (size_t)(n0w + 16 + l16) * 1024 + kbase + quad * 8;
#pragma unroll 2
    for (int step = 0; step < 8; ++step) {
        int ka = step * 32 + quad * 8;
        half8 ah0 = *(const half8*)&ahi[l16 * FK_AST + ka];
        half8 ah1 = *(const half8*)&ahi[(l16 + 16) * FK_AST + ka];
        half8 al0 = *(const half8*)&alo[l16 * FK_AST + ka];
        half8 al1 = *(const half8*)&alo[(l16 + 16) * FK_AST + ka];
        int ko = step * 32;
        half8 bh0 = *(const half8*)(bhp0 + ko);
        half8 bh1 = *(const half8*)(bhp1 + ko);
        half8 bl0 = *(const half8*)(blp0 + ko);
        half8 bl1 = *(const half8*)(blp1 + ko);
        acc0[0][0] = __builtin_amdgcn_mfma_f32_16x16x32_f16(ah0, bh0, acc0[0][0], 0, 0, 0);
        acc0[0][1] = __builtin_amdgcn_mfma_f32_16x16x32_f16(ah0, bh1, acc0[0][1], 0, 0, 0);
        acc0[1][0] = __builtin_amdgcn_mfma_f32_16x16x32_f16(ah1, bh0, acc0[1][0], 0, 0, 0);
        acc0[1][1] = __builtin_amdgcn_mfma_f32_16x16x32_f16(ah1, bh1, acc0[1][1], 0, 0, 0);
        accL[0][0] = __builtin_amdgcn_mfma_f32_16x16x32_f16(ah0, bl0, accL[0][0], 0, 0, 0);
        accL[0][1] = __builtin_amdgcn_mfma_f32_16x16x32_f16(ah0, bl1, accL[0][1], 0, 0, 0);
        accL[1][0] = __builtin_amdgcn_mfma_f32_16x16x32_f16(ah1, bl0, accL[1][0], 0, 0, 0);
        accL[1][1] = __builtin_amdgcn_mfma_f32_16x16x32_f16(ah1, bl1, accL[1][1], 0, 0, 0);
        accL[0][0] = __builtin_amdgcn_mfma_f32_16x16x32_f16(al0, bh0, accL[0][0], 0, 0, 0);
        accL[0][1] = __builtin_amdgcn_mfma_f32_16x16x32_f16(al0, bh1, accL[0][1], 0, 0, 0);
        accL[1][0] = __builtin_amdgcn_mfma_f32_16x16x32_f16(al1, bh0, accL[1][0], 0, 0, 0);
        accL[1][1] = __builtin_amdgcn_mfma_f32_16x16x32_f16(al1, bh1, accL[1][1], 0, 0, 0);
    }
    float* p = (ks == 0) ? p0 : (ks == 1) ? p1 : (ks == 2) ? p2 : p3;
    const float inv = 1.0f / 2048.0f;
#pragma unroll
    for (int mi = 0; mi < 2; ++mi)
#pragma unroll
        for (int ni = 0; ni < 2; ++ni)
#pragma unroll
            for (int r = 0; r < 4; ++r) {
                int gn = nb + mi * 16 + quad * 4 + r;
                if (gn < N)
                    p[gn * HID + n0w + ni * 16 + l16] = acc0[mi][ni][r] + accL[mi][ni][r] * inv;
            }
}

// ---------------------------------------------------------------- batchnorm stats (float4 per thread, 5 streams)
__global__ __launch_bounds__(256) void k_bn_stats(float* __restrict__ hconv,
                           const float* __restrict__ p0, const float* __restrict__ p1,
                           const float* __restrict__ p2, const float* __restrict__ p3,
                           const float* __restrict__ fkb,
                           double* __restrict__ stats, int N) {
    int tid = threadIdx.x;
    int cq = tid & 31, rg = tid >> 5;          // 8 row slots x 32 channel-quads
    int c4 = cq * 4;
    float4 bias = *(const float4*)&fkb[c4];
    float s1[4] = {0, 0, 0, 0}, s2[4] = {0, 0, 0, 0};
    for (int n = blockIdx.x * 8 + rg; n < N; n += gridDim.x * 8) {
        size_t idx = (size_t)n * HID + c4;
        float4 a  = *(const float4*)&hconv[idx];
        float4 b0 = *(const float4*)&p0[idx];
        float4 b1 = *(const float4*)&p1[idx];
        float4 b2 = *(const float4*)&p2[idx];
        float4 b3 = *(const float4*)&p3[idx];
        float4 v;
        v.x = a.x + b0.x + b1.x + b2.x + b3.x + bias.x;
        v.y = a.y + b0.y + b1.y + b2.y + b3.y + bias.y;
        v.z = a.z + b0.z + b1.z + b2.z + b3.z + bias.z;
        v.w = a.w + b0.w + b1.w + b2.w + b3.w + bias.w;
        *(float4*)&hconv[idx] = v;
        s1[0] += v.x; s2[0] += v.x * v.x;
        s1[1] += v.y; s2[1] += v.y * v.y;
        s1[2] += v.z; s2[2] += v.z * v.z;
        s1[3] += v.w; s2[3] += v.w * v.w;
    }
#pragma unroll
    for (int j = 0; j < 4; ++j) {
        s1[j] += __shfl_down(s1[j], 32);
        s2[j] += __shfl_down(s2[j], 32);
    }
    __shared__ float sh1[4][32][4], sh2[4][32][4];
    int wv = tid >> 6, lane = tid & 63;
    if (lane < 32) {
#pragma unroll
        for (int j = 0; j < 4; ++j) { sh1[wv][lane][j] = s1[j]; sh2[wv][lane][j] = s2[j]; }
    }
    __syncthreads();
    if (tid < 128) {
        int cq2 = tid >> 2, j2 = tid & 3;
        float t1 = sh1[0][cq2][j2] + sh1[1][cq2][j2] + sh1[2][cq2][j2] + sh1[3][cq2][j2];
        float t2 = sh2[0][cq2][j2] + sh2[1][cq2][j2] + sh2[2][cq2][j2] + sh2[3][cq2][j2];
        int c = cq2 * 4 + j2;
        atomicAdd(&stats[c], (double)t1);
        atomicAdd(&stats[128 + c], (double)t2);
    }
}

// bn_final folded in; float4 per thread; optional pool scores (last layer)
__global__ void k_bn_apply(const float* __restrict__ hsum, const double* __restrict__ stats,
                           const float* __restrict__ g, const float* __restrict__ b,
                           const float* __restrict__ pw, const float* __restrict__ pb,
                           float* __restrict__ h, float* __restrict__ s,
                           int do_score, int N) {
    int idx = blockIdx.x * 256 + threadIdx.x;   // one thread per 4 channels
    int row = idx >> 5, cq = idx & 31;
    int c4 = cq * 4;
    int valid = row < N;
    double invN = 1.0 / (double)N;
    float p = 0.f;
    if (valid) {
        float4 hv = *(const float4*)&hsum[(size_t)row * HID + c4];
        float vin[4] = {hv.x, hv.y, hv.z, hv.w};
        float4 ov;
        float* po = &ov.x;
#pragma unroll
        for (int j = 0; j < 4; ++j) {
            int c = c4 + j;
            float mu = (float)(stats[c] * invN);
            float var = (float)(stats[128 + c] * invN) - mu * mu;
            float inv = 1.f / sqrtf(var + 1e-5f);
            float sc = g[c] * inv;
            float sh = b[c] - mu * sc;
            float oo = fmaxf(vin[j] * sc + sh, 0.f);
            po[j] = oo;
            if (do_score) p += oo * pw[c];
        }
        *(float4*)&h[(size_t)row * HID + c4] = ov;
    }
    if (do_score) {
        for (int off = 16; off > 0; off >>= 1) p += __shfl_down(p, off, 32);
        if ((threadIdx.x & 31) == 0 && valid) s[row] = p + pb[0];
    }
}

// ---------------------------------------------------------------- softmax partials
__global__ void k_smax1(const float* __restrict__ s, float* __restrict__ mzp, int N) {
    __shared__ float red[256];
    float m = -INFINITY;
    for (int n = blockIdx.x * 256 + threadIdx.x; n < N; n += SMAXB * 256)
        m = fmaxf(m, s[n]);
    red[threadIdx.x] = m;
    __syncthreads();
    for (int off = 128; off > 0; off >>= 1) {
        if (threadIdx.x < (unsigned)off)
            red[threadIdx.x] = fmaxf(red[threadIdx.x], red[threadIdx.x + off]);
        __syncthreads();
    }
    m = red[0];
    __syncthreads();
    float z = 0.f;
    for (int n = blockIdx.x * 256 + threadIdx.x; n < N; n += SMAXB * 256)
        z += __expf(s[n] - m);
    red[threadIdx.x] = z;
    __syncthreads();
    for (int off = 128; off > 0; off >>= 1) {
        if (threadIdx.x < (unsigned)off) red[threadIdx.x] += red[threadIdx.x + off];
        __syncthreads();
    }
    if (threadIdx.x == 0) { mzp[blockIdx.x * 2] = m; mzp[blockIdx.x * 2 + 1] = red[0]; }
}

__device__ __forceinline__ void combine_mz(const float* mzp, float& m, float& Z) {
    m = -INFINITY;
#pragma unroll 8
    for (int i = 0; i < SMAXB; ++i) m = fmaxf(m, mzp[i * 2]);
    Z = 0.f;
#pragma unroll 8
    for (int i = 0; i < SMAXB; ++i) Z += mzp[i * 2 + 1] * __expf(mzp[i * 2] - m);
}

// ---------------------------------------------------------------- attention pool (split)
__global__ void k_pool_part(const float* __restrict__ h, const float* __restrict__ s,
                            const float* __restrict__ mzp, const int* __restrict__ boffs,
                            float* __restrict__ part) {
    int b = blockIdx.x >> 4, split = blockIdx.x & (PSPLIT - 1);
    int c = threadIdx.x & 127, half = threadIdx.x >> 7;
    float m, Z;
    combine_mz(mzp, m, Z);
    (void)Z;
    int n0 = boffs[b], n1 = boffs[b + 1];
    float acc = 0.f;
    for (int n = n0 + split * 2 + half; n < n1; n += PSPLIT * 2)
        acc += __expf(s[n] - m) * h[n * HID + c];
    __shared__ float prt[2][HID];
    prt[half][c] = acc;
    __syncthreads();
    if (half == 0) part[(size_t)(b * PSPLIT + split) * HID + c] = prt[0][c] + prt[1][c];
}

__global__ void k_pool_sum(const float* __restrict__ part, const float* __restrict__ mzp,
                           float* __restrict__ pooled) {
    int b = blockIdx.x, c = threadIdx.x;
    float m, Z;
    combine_mz(mzp, m, Z);
    float acc = 0.f;
#pragma unroll
    for (int i = 0; i < PSPLIT; ++i) acc += part[(size_t)(b * PSPLIT + i) * HID + c];
    pooled[b * HID + c] = acc / Z;
}

// ---------------------------------------------------------------- heads (grid = B*4)
__global__ __launch_bounds__(256) void k_head(const float* __restrict__ pooled,
                       const float* __restrict__ sg_table,
                       const int* __restrict__ space_group,
                       const float* __restrict__ hw1, const float* __restrict__ hb1,
                       const float* __restrict__ ew2, const float* __restrict__ eb2,
                       const float* __restrict__ sw2, const float* __restrict__ sb2,
                       const float* __restrict__ cw2, const float* __restrict__ cb2,
                       const float* __restrict__ mw2, const float* __restrict__ mb2,
                       float* __restrict__ out, int B) {
    __shared__ float comb[256];
    __shared__ float zred[2][128];
    __shared__ float zsh[128];
    int b = blockIdx.x >> 2, i = blockIdx.x & 3;
    int t = threadIdx.x;
    comb[t] = (t < 128) ? pooled[b * HID + t] : sg_table[space_group[b] * HID + (t - 128)];
    __syncthreads();
    int half = t >> 7, tt = t & 127;
    const float* W = hw1 + ((size_t)i * 256 + half * 128) * HID;
    const float* cb = &comb[half * 128];
    float z = 0.f;
#pragma unroll 8
    for (int k = 0; k < 128; ++k) z += cb[k] * W[k * HID + tt];
    zred[half][tt] = z;
    __syncthreads();
    if (t < 128) zsh[t] = fmaxf(zred[0][t] + zred[1][t] + hb1[i * HID + t], 0.f);
    __syncthreads();
    const int od[4] = {1, 3, 7, 3};
    const int base[4] = {0, 64, 256, 704};
    const float* w2 = (i == 0) ? ew2 : (i == 1) ? sw2 : (i == 2) ? cw2 : mw2;
    const float* b2 = (i == 0) ? eb2 : (i == 1) ? sb2 : (i == 2) ? cb2 : mb2;
    int odi = od[i];
    if (t < odi) {
        float o = b2[t];
        for (int c = 0; c < HID; ++c) o += zsh[c] * w2[c * odi + t];
        out[base[i] + b * odi + t] = o;
    }
}

// ---------------------------------------------------------------- launch
extern "C" void kernel_launch(void* const* d_in, const int* in_sizes, int n_in,
                              void* d_out, int out_size, void* d_ws, size_t ws_size,
                              hipStream_t stream) {
    const float* x          = (const float*)d_in[0];
    const int*   edge_index = (const int*)d_in[1];
    const float* edge_attr  = (const float*)d_in[2];
    const int*   batch      = (const int*)d_in[3];
    const int*   space_group= (const int*)d_in[4];
    const float* node_w     = (const float*)d_in[5];
    const float* node_b     = (const float*)d_in[6];
    const float* sg_table   = (const float*)d_in[7];
    const float* lin_w      = (const float*)d_in[8];
    const float* lin_b      = (const float*)d_in[9];
    const float* att_w      = (const float*)d_in[10];
    const float* att_b      = (const float*)d_in[11];
    const float* fk_w       = (const float*)d_in[12];
    const float* fk_b       = (const float*)d_in[13];
    const float* bn_g       = (const float*)d_in[14];
    const float* bn_b       = (const float*)d_in[15];
    const float* pool_w     = (const float*)d_in[16];
    const float* pool_b     = (const float*)d_in[17];
    const float* head_w1    = (const float*)d_in[18];
    const float* head_b1    = (const float*)d_in[19];
    const float* ew2 = (const float*)d_in[20]; const float* eb2 = (const float*)d_in[21];
    const float* sw2 = (const float*)d_in[22]; const float* sb2 = (const float*)d_in[23];
    const float* cw2 = (const float*)d_in[24]; const float* cb2 = (const float*)d_in[25];
    const float* mw2 = (const float*)d_in[26]; const float* mb2 = (const float*)d_in[27];
    float* out = (float*)d_out;

    const int N = in_sizes[3];
    const int E = in_sizes[1] / 2;
    const int B = in_sizes[4];
    const int* src = edge_index;
    const int* dst = edge_index + E;

    char* w = (char*)d_ws;
    auto alloc = [&](size_t bytes) { char* p = w; w += (bytes + 255) & ~(size_t)255; return p; };
    float*  h      = (float*)alloc((size_t)N * HID * 4);
    float*  A1     = (float*)alloc((size_t)N * HID * 4);  // reused as FK partial 0
    float*  A2     = (float*)alloc((size_t)N * HID * 4);  // reused as FK partial 1
    float*  p2     = (float*)alloc((size_t)N * HID * 4);  // FK partial 2
    float*  p3     = (float*)alloc((size_t)N * HID * 4);  // FK partial 3
    float*  hconv  = (float*)alloc((size_t)N * HID * 4);  // becomes pre-BN sum in place
    float*  a1     = (float*)alloc((size_t)N * 4);
    float*  a2     = (float*)alloc((size_t)N * 4);
    float*  sbuf   = (float*)alloc((size_t)N * 4);
    int*    deg    = (int*)alloc((size_t)N * 4);
    int*    cursor = (int*)alloc((size_t)N * 4);
    int*    offs   = (int*)alloc((size_t)(N + 1) * 4);
    int*    srco   = (int*)alloc((size_t)E * 4);
    float4* ea3o   = (float4*)alloc((size_t)E * 16);
    _Float16* whi  = (_Float16*)alloc((size_t)DEPTH * 1024 * HID * 2);
    _Float16* wlo  = (_Float16*)alloc((size_t)DEPTH * 1024 * HID * 2);
    int*    bsum   = (int*)alloc(256 * 4);
    int*    boffs  = (int*)alloc((size_t)(B + 1) * 4);
    double* stats  = (double*)alloc(256 * 8);
    float*  mzp    = (float*)alloc(SMAXB * 2 * 4);
    float*  part   = (float*)alloc((size_t)B * PSPLIT * HID * 4);
    float*  pooled = (float*)alloc((size_t)B * HID * 4);

    const int nchunk = (N + 255) / 256;
    const int echunk = (E + 255) / 256;

    // one-time per launch: W split + CSR build
    k_wsplit<<<128, 256, 0, stream>>>(fk_w, whi, wlo);
    hipMemsetAsync(deg, 0, (size_t)N * 4, stream);
    k_hist<<<echunk, 256, 0, stream>>>(dst, deg, E);
    k_scan_a<<<nchunk, 256, 0, stream>>>(deg, bsum, N);
    k_scan_b<<<1, 256, 0, stream>>>(bsum, nchunk);
    k_scan_c<<<nchunk, 256, 0, stream>>>(deg, bsum, offs, cursor, N);
    k_scatter<<<echunk, 256, 0, stream>>>(src, dst, edge_attr, cursor, srco, ea3o, E);
    k_bstart<<<nchunk, 256, 0, stream>>>(batch, boffs, N, B);

    k_node_embed<<<(N * HID + 255) / 256, 256, 0, stream>>>(x, node_w, node_b, h, N);

    for (int l = 0; l < DEPTH; ++l) {
        const float* linw_l = lin_w + (size_t)l * 259 * HID;
        k_node_lin<<<(N + 15) / 16, 256, 0, stream>>>(
            h, linw_l, lin_b + l * HID, att_w + (size_t)l * 259, att_b + l,
            A1, A2, a1, a2, N);
        k_edge<<<N, 256, 0, stream>>>(A1, A2, a1, a2, srco, ea3o, offs,
                                      linw_l + 256 * HID, att_w + (size_t)l * 259 + 256,
                                      hconv, stats, N);
        k_fk<<<((N + 31) / 32) * 4, 256, 0, stream>>>(
            h, whi + (size_t)l * 131072, wlo + (size_t)l * 131072, A1, A2, p2, p3, N);
        k_bn_stats<<<320, 256, 0, stream>>>(hconv, A1, A2, p2, p3, fk_b + l * HID, stats, N);
        k_bn_apply<<<(N * 32 + 255) / 256, 256, 0, stream>>>(
            hconv, stats, bn_g + l * HID, bn_b + l * HID, pool_w, pool_b,
            h, sbuf, (l == DEPTH - 1) ? 1 : 0, N);
    }

    k_smax1<<<SMAXB, 256, 0, stream>>>(sbuf, mzp, N);
    k_pool_part<<<B * PSPLIT, 256, 0, stream>>>(h, sbuf, mzp, boffs, part);
    k_pool_sum<<<B, 128, 0, stream>>>(part, mzp, pooled);
    k_head<<<B * 4, 256, 0, stream>>>(pooled, sg_table, space_group, head_w1, head_b1,
                                      ew2, eb2, sw2, sb2, cw2, cb2, mw2, mb2, out, B);
}